// Round 1
// baseline (3747.843 us; speedup 1.0000x reference)
//
#include <hip/hip_runtime.h>
#include <math.h>

#define B_ 2
#define S_ 512
#define P_ 64
#define T_ 576          // P_+S_
#define D_ 1024
#define L_ 4
#define DI_ 2048
#define DS_ 16
#define DC_ 4
#define DR_ 64
#define PCD_ 768
#define M_ (B_*T_)      // 1152

__device__ __forceinline__ float silu_f(float v) { return v / (1.f + __expf(-v)); }
__device__ __forceinline__ float softplus_f(float v) {
    return fmaxf(v, 0.f) + log1pf(__expf(-fabsf(v)));
}

// ---------------------------------------------------------------------------
// Generic tiled fp32 GEMM.
//  NT=true :  C[m,n] = sum_k A[m*lda+k] * W[n*ldw+k]
//  NT=false:  C[m,n] = sum_k A[m*lda+k] * W[k*ldw+n]
// EPI: 0 plain store, 1 silu, 2 softplus(v + bias[n]), 3 add into C
// Requires: M % 64 == 0, K % 16 == 0, N % 4 == 0 (N<64 allowed, guarded).
// ---------------------------------------------------------------------------
template<int EPI, bool NT>
__global__ __launch_bounds__(256) void gemm_kernel(
    const float* __restrict__ A, const float* __restrict__ W,
    float* __restrict__ C, const float* __restrict__ bias,
    int M, int N, int K, int lda, int ldw, int ldc)
{
    __shared__ __align__(16) float As[16][68];
    __shared__ __align__(16) float Ws[16][68];
    const int m0 = blockIdx.y * 64;
    const int n0 = blockIdx.x * 64;
    const int tid = threadIdx.x;
    const int ty = tid >> 4;        // 0..15
    const int tx = tid & 15;        // 0..15
    float acc[4][4] = {};

    const int lr = tid >> 2;        // 0..63 (row within tile for NT loads)
    const int lk = (tid & 3) * 4;   // k quad
    const int kk = tid >> 4;        // 0..15 (for NN W load)
    const int nq = (tid & 15) * 4;  // 0..60

    for (int k0 = 0; k0 < K; k0 += 16) {
        // A tile: As[k][m]
        {
            const float4 v = *(const float4*)(A + (size_t)(m0 + lr) * lda + k0 + lk);
            As[lk + 0][lr] = v.x; As[lk + 1][lr] = v.y;
            As[lk + 2][lr] = v.z; As[lk + 3][lr] = v.w;
        }
        // W tile: Ws[k][n]
        if (NT) {
            const int n = n0 + lr;
            float4 v = make_float4(0.f, 0.f, 0.f, 0.f);
            if (n < N) v = *(const float4*)(W + (size_t)n * ldw + k0 + lk);
            Ws[lk + 0][lr] = v.x; Ws[lk + 1][lr] = v.y;
            Ws[lk + 2][lr] = v.z; Ws[lk + 3][lr] = v.w;
        } else {
            const int n = n0 + nq;
            float4 v = make_float4(0.f, 0.f, 0.f, 0.f);
            if (n < N) v = *(const float4*)(W + (size_t)(k0 + kk) * ldw + n);
            Ws[kk][nq + 0] = v.x; Ws[kk][nq + 1] = v.y;
            Ws[kk][nq + 2] = v.z; Ws[kk][nq + 3] = v.w;
        }
        __syncthreads();
        #pragma unroll
        for (int k = 0; k < 16; ++k) {
            const float4 a = *(const float4*)&As[k][ty * 4];
            const float4 b = *(const float4*)&Ws[k][tx * 4];
            acc[0][0] = fmaf(a.x, b.x, acc[0][0]);
            acc[0][1] = fmaf(a.x, b.y, acc[0][1]);
            acc[0][2] = fmaf(a.x, b.z, acc[0][2]);
            acc[0][3] = fmaf(a.x, b.w, acc[0][3]);
            acc[1][0] = fmaf(a.y, b.x, acc[1][0]);
            acc[1][1] = fmaf(a.y, b.y, acc[1][1]);
            acc[1][2] = fmaf(a.y, b.z, acc[1][2]);
            acc[1][3] = fmaf(a.y, b.w, acc[1][3]);
            acc[2][0] = fmaf(a.z, b.x, acc[2][0]);
            acc[2][1] = fmaf(a.z, b.y, acc[2][1]);
            acc[2][2] = fmaf(a.z, b.z, acc[2][2]);
            acc[2][3] = fmaf(a.z, b.w, acc[2][3]);
            acc[3][0] = fmaf(a.w, b.x, acc[3][0]);
            acc[3][1] = fmaf(a.w, b.y, acc[3][1]);
            acc[3][2] = fmaf(a.w, b.z, acc[3][2]);
            acc[3][3] = fmaf(a.w, b.w, acc[3][3]);
        }
        __syncthreads();
    }
    #pragma unroll
    for (int i = 0; i < 4; ++i) {
        const int m = m0 + ty * 4 + i;
        #pragma unroll
        for (int j = 0; j < 4; ++j) {
            const int n = n0 + tx * 4 + j;
            if (n < N) {
                float v = acc[i][j];
                if (EPI == 1) v = silu_f(v);
                if (EPI == 2) v = softplus_f(v + bias[n]);
                float* p = C + (size_t)m * ldc + n;
                if (EPI == 3) *p += v; else *p = v;
            }
        }
    }
}

// h[b*T+t, :] = (t < P) ? p[b*P+t, :] : x[b*S + (t-P), :]
__global__ __launch_bounds__(256) void assemble_h_kernel(
    const float* __restrict__ p, const float* __restrict__ x, float* __restrict__ h)
{
    const int idx = blockIdx.x * 256 + threadIdx.x;   // over M_*D_/4 float4s
    const int r = idx >> 8;                            // D_/4 = 256
    const int c = idx & 255;
    const int b = r / T_;
    const int t = r - b * T_;
    float4 v;
    if (t < P_) v = ((const float4*)p)[(size_t)(b * P_ + t) * 256 + c];
    else        v = ((const float4*)x)[(size_t)(b * S_ + (t - P_)) * 256 + c];
    ((float4*)h)[idx] = v;
}

// one block per row, 256 threads, D_=1024
__global__ __launch_bounds__(256) void rmsnorm_kernel(
    const float* __restrict__ x, const float* __restrict__ w, float* __restrict__ out)
{
    const int r = blockIdx.x;
    const float4 v = ((const float4*)(x + (size_t)r * D_))[threadIdx.x];
    float ss = v.x * v.x + v.y * v.y + v.z * v.z + v.w * v.w;
    ss += __shfl_xor(ss, 32, 64);
    ss += __shfl_xor(ss, 16, 64);
    ss += __shfl_xor(ss, 8, 64);
    ss += __shfl_xor(ss, 4, 64);
    ss += __shfl_xor(ss, 2, 64);
    ss += __shfl_xor(ss, 1, 64);
    __shared__ float red[4];
    if ((threadIdx.x & 63) == 0) red[threadIdx.x >> 6] = ss;
    __syncthreads();
    const float tot = red[0] + red[1] + red[2] + red[3];
    const float scale = rsqrtf(tot * (1.f / D_) + 1e-5f);
    const float4 wv = ((const float4*)w)[threadIdx.x];
    float4 o;
    o.x = v.x * scale * wv.x; o.y = v.y * scale * wv.y;
    o.z = v.z * scale * wv.z; o.w = v.w * scale * wv.w;
    ((float4*)(out + (size_t)r * D_))[threadIdx.x] = o;
}

// rows r over B*S; reads h[b*T+P+s], writes out[b*S+s]
__global__ __launch_bounds__(256) void final_rmsnorm_kernel(
    const float* __restrict__ h, const float* __restrict__ w, float* __restrict__ out)
{
    const int r = blockIdx.x;               // 0..B*S-1
    const int b = r / S_;
    const int s = r - b * S_;
    const int hr = b * T_ + P_ + s;
    const float4 v = ((const float4*)(h + (size_t)hr * D_))[threadIdx.x];
    float ss = v.x * v.x + v.y * v.y + v.z * v.z + v.w * v.w;
    ss += __shfl_xor(ss, 32, 64);
    ss += __shfl_xor(ss, 16, 64);
    ss += __shfl_xor(ss, 8, 64);
    ss += __shfl_xor(ss, 4, 64);
    ss += __shfl_xor(ss, 2, 64);
    ss += __shfl_xor(ss, 1, 64);
    __shared__ float red[4];
    if ((threadIdx.x & 63) == 0) red[threadIdx.x >> 6] = ss;
    __syncthreads();
    const float tot = red[0] + red[1] + red[2] + red[3];
    const float scale = rsqrtf(tot * (1.f / D_) + 1e-5f);
    const float4 wv = ((const float4*)w)[threadIdx.x];
    float4 o;
    o.x = v.x * scale * wv.x; o.y = v.y * scale * wv.y;
    o.z = v.z * scale * wv.z; o.w = v.w * scale * wv.w;
    ((float4*)(out + (size_t)r * D_))[threadIdx.x] = o;
}

// causal depthwise conv (DC=4) + bias + silu. xz: [M_, 2*DI_], first DI_ cols.
__global__ __launch_bounds__(256) void conv_silu_kernel(
    const float* __restrict__ xz, const float* __restrict__ cw,
    const float* __restrict__ cb, float* __restrict__ xi)
{
    const int idx = blockIdx.x * 256 + threadIdx.x;   // over M_*DI_
    const int e = idx & (DI_ - 1);
    const int r = idx >> 11;
    const int b = r / T_;
    const int t = r - b * T_;
    const float4 w = *(const float4*)(cw + (size_t)e * 4);
    const float x3 = xz[(size_t)r * (2 * DI_) + e];
    const float x2 = (t >= 1) ? xz[(size_t)(r - 1) * (2 * DI_) + e] : 0.f;
    const float x1 = (t >= 2) ? xz[(size_t)(r - 2) * (2 * DI_) + e] : 0.f;
    const float x0 = (t >= 3) ? xz[(size_t)(r - 3) * (2 * DI_) + e] : 0.f;
    float v = cb[e];
    v = fmaf(w.x, x0, v);
    v = fmaf(w.y, x1, v);
    v = fmaf(w.z, x2, v);
    v = fmaf(w.w, x3, v);
    xi[idx] = silu_f(v);
}

// selective scan: one lane per (b, e, s). 16-lane shuffle reduce over s.
// y[r,e] = (sum_s h_state*C + u*Dp[e]) * silu(z)
__global__ __launch_bounds__(256) void scan_kernel(
    const float* __restrict__ dt,    // [M_, DI_]
    const float* __restrict__ xdbl,  // [M_, 96]: [0:64)=dtr, [64:80)=B, [80:96)=C
    const float* __restrict__ xi,    // [M_, DI_]
    const float* __restrict__ xz,    // [M_, 2*DI_] (z at cols DI_..)
    const float* __restrict__ A_log, // [DI_, DS_] layer slice
    const float* __restrict__ Dp,    // [DI_]
    float* __restrict__ y)           // [M_, DI_]
{
    const int g = blockIdx.x * 256 + threadIdx.x;     // 0..B_*DI_*DS_-1
    const int s = g & (DS_ - 1);
    const int e = (g >> 4) & (DI_ - 1);
    const int b = g >> 15;
    const float Aval = -__expf(A_log[(size_t)e * DS_ + s]);
    const float dpe = Dp[e];
    float hstate = 0.f;
    const int row0 = b * T_;
    for (int t = 0; t < T_; ++t) {
        const int r = row0 + t;
        const float dtv = dt[(size_t)r * DI_ + e];
        const float u   = xi[(size_t)r * DI_ + e];
        const float bv  = xdbl[(size_t)r * 96 + DR_ + s];
        const float cv  = xdbl[(size_t)r * 96 + DR_ + DS_ + s];
        const float da  = __expf(dtv * Aval);
        hstate = fmaf(da, hstate, dtv * bv * u);
        float contrib = hstate * cv;
        contrib += __shfl_xor(contrib, 1, 64);
        contrib += __shfl_xor(contrib, 2, 64);
        contrib += __shfl_xor(contrib, 4, 64);
        contrib += __shfl_xor(contrib, 8, 64);
        if (s == 0) {
            const float z = xz[(size_t)r * (2 * DI_) + DI_ + e];
            y[(size_t)r * DI_ + e] = (contrib + u * dpe) * silu_f(z);
        }
    }
}

extern "C" void kernel_launch(void* const* d_in, const int* in_sizes, int n_in,
                              void* d_out, int out_size, void* d_ws, size_t ws_size,
                              hipStream_t stream)
{
    const float* x       = (const float*)d_in[0];
    const float* pc      = (const float*)d_in[1];
    const float* pre_w1  = (const float*)d_in[2];
    const float* pre_w2  = (const float*)d_in[3];
    const float* norm_w  = (const float*)d_in[4];
    const float* ip_w    = (const float*)d_in[5];
    const float* conv_w  = (const float*)d_in[6];
    const float* conv_b  = (const float*)d_in[7];
    const float* xp_w    = (const float*)d_in[8];
    const float* dtp_w   = (const float*)d_in[9];
    const float* dtp_b   = (const float*)d_in[10];
    const float* A_log   = (const float*)d_in[11];
    const float* D_param = (const float*)d_in[12];
    const float* op_w    = (const float*)d_in[13];
    const float* fnw     = (const float*)d_in[14];
    float* out = (float*)d_out;

    float* ws = (float*)d_ws;
    float* h    = ws;  ws += (size_t)M_ * D_;          // 1179648
    float* xn   = ws;  ws += (size_t)M_ * D_;          // 1179648
    float* xz   = ws;  ws += (size_t)M_ * 2 * DI_;     // 4718592
    float* xi   = ws;  ws += (size_t)M_ * DI_;         // 2359296
    float* xdbl = ws;  ws += (size_t)M_ * 96;          // 110592
    float* dtb  = ws;  ws += (size_t)M_ * DI_;         // 2359296
    float* yb   = ws;  ws += (size_t)M_ * DI_;         // 2359296
    // prepend temporaries alias xz (consumed before layer 0 writes xz)
    float* tmp1 = xz;
    float* tmp2 = xz + (size_t)B_ * P_ * D_;

    const dim3 blk(256);

    // prepend embed: tmp1 = silu(pc @ pre_w1); tmp2 = tmp1 @ pre_w2
    gemm_kernel<1, false><<<dim3(D_ / 64, (B_ * P_) / 64), blk, 0, stream>>>(
        pc, pre_w1, tmp1, nullptr, B_ * P_, D_, PCD_, PCD_, D_, D_);
    gemm_kernel<0, false><<<dim3(D_ / 64, (B_ * P_) / 64), blk, 0, stream>>>(
        tmp1, pre_w2, tmp2, nullptr, B_ * P_, D_, D_, D_, D_, D_);
    assemble_h_kernel<<<dim3(M_ * D_ / 4 / 256), blk, 0, stream>>>(tmp2, x, h);

    for (int l = 0; l < L_; ++l) {
        rmsnorm_kernel<<<dim3(M_), blk, 0, stream>>>(h, norm_w + (size_t)l * D_, xn);
        // in_proj: xz = xn @ ip_w^T   [M,4096,K=1024]
        gemm_kernel<0, true><<<dim3(2 * DI_ / 64, M_ / 64), blk, 0, stream>>>(
            xn, ip_w + (size_t)l * 2 * DI_ * D_, xz, nullptr,
            M_, 2 * DI_, D_, D_, D_, 2 * DI_);
        conv_silu_kernel<<<dim3(M_ * DI_ / 256), blk, 0, stream>>>(
            xz, conv_w + (size_t)l * DI_ * DC_, conv_b + (size_t)l * DI_, xi);
        // x_proj: xdbl = xi @ xp_w^T  [M,96,K=2048]
        gemm_kernel<0, true><<<dim3(2, M_ / 64), blk, 0, stream>>>(
            xi, xp_w + (size_t)l * 96 * DI_, xdbl, nullptr,
            M_, 96, DI_, DI_, DI_, 96);
        // dt_proj: dtb = softplus(xdbl[:, :64] @ dtp_w^T + dtp_b)  [M,2048,K=64]
        gemm_kernel<2, true><<<dim3(DI_ / 64, M_ / 64), blk, 0, stream>>>(
            xdbl, dtp_w + (size_t)l * DI_ * DR_, dtb, dtp_b + (size_t)l * DI_,
            M_, DI_, DR_, 96, DR_, DI_);
        scan_kernel<<<dim3(B_ * DI_ * DS_ / 256), blk, 0, stream>>>(
            dtb, xdbl, xi, xz, A_log + (size_t)l * DI_ * DS_,
            D_param + (size_t)l * DI_, yb);
        // out_proj + residual: h += yb @ op_w^T  [M,1024,K=2048]
        gemm_kernel<3, true><<<dim3(D_ / 64, M_ / 64), blk, 0, stream>>>(
            yb, op_w + (size_t)l * D_ * DI_, h, nullptr,
            M_, D_, DI_, DI_, DI_, D_);
    }

    final_rmsnorm_kernel<<<dim3(B_ * S_), blk, 0, stream>>>(h, fnw, out);
}

// Round 2
// 2559.884 us; speedup vs baseline: 1.4641x; 1.4641x over previous
//
#include <hip/hip_runtime.h>
#include <math.h>

#define B_ 2
#define S_ 512
#define P_ 64
#define T_ 576          // P_+S_
#define D_ 1024
#define L_ 4
#define DI_ 2048
#define DS_ 16
#define DC_ 4
#define DR_ 64
#define PCD_ 768
#define M_ (B_*T_)      // 1152
#define CCH 64          // scan chunk length
#define NC (T_/CCH)     // 9 chunks

__device__ __forceinline__ float silu_f(float v) { return v / (1.f + __expf(-v)); }
__device__ __forceinline__ float softplus_f(float v) {
    return fmaxf(v, 0.f) + log1pf(__expf(-fabsf(v)));
}

// ---------------------------------------------------------------------------
// Generic tiled fp32 GEMM.
//  NT=true :  C[m,n] = sum_k A[m*lda+k] * W[n*ldw+k]
//  NT=false:  C[m,n] = sum_k A[m*lda+k] * W[k*ldw+n]
// EPI: 0 plain store, 1 silu, 2 softplus(v + bias[n]), 3 add into C
// ---------------------------------------------------------------------------
template<int EPI, bool NT>
__global__ __launch_bounds__(256) void gemm_kernel(
    const float* __restrict__ A, const float* __restrict__ W,
    float* __restrict__ C, const float* __restrict__ bias,
    int M, int N, int K, int lda, int ldw, int ldc)
{
    __shared__ __align__(16) float As[16][68];
    __shared__ __align__(16) float Ws[16][68];
    const int m0 = blockIdx.y * 64;
    const int n0 = blockIdx.x * 64;
    const int tid = threadIdx.x;
    const int ty = tid >> 4;        // 0..15
    const int tx = tid & 15;        // 0..15
    float acc[4][4] = {};

    const int lr = tid >> 2;        // 0..63 (row within tile for NT loads)
    const int lk = (tid & 3) * 4;   // k quad
    const int kk = tid >> 4;        // 0..15 (for NN W load)
    const int nq = (tid & 15) * 4;  // 0..60

    for (int k0 = 0; k0 < K; k0 += 16) {
        {
            const float4 v = *(const float4*)(A + (size_t)(m0 + lr) * lda + k0 + lk);
            As[lk + 0][lr] = v.x; As[lk + 1][lr] = v.y;
            As[lk + 2][lr] = v.z; As[lk + 3][lr] = v.w;
        }
        if (NT) {
            const int n = n0 + lr;
            float4 v = make_float4(0.f, 0.f, 0.f, 0.f);
            if (n < N) v = *(const float4*)(W + (size_t)n * ldw + k0 + lk);
            Ws[lk + 0][lr] = v.x; Ws[lk + 1][lr] = v.y;
            Ws[lk + 2][lr] = v.z; Ws[lk + 3][lr] = v.w;
        } else {
            const int n = n0 + nq;
            float4 v = make_float4(0.f, 0.f, 0.f, 0.f);
            if (n < N) v = *(const float4*)(W + (size_t)(k0 + kk) * ldw + n);
            Ws[kk][nq + 0] = v.x; Ws[kk][nq + 1] = v.y;
            Ws[kk][nq + 2] = v.z; Ws[kk][nq + 3] = v.w;
        }
        __syncthreads();
        #pragma unroll
        for (int k = 0; k < 16; ++k) {
            const float4 a = *(const float4*)&As[k][ty * 4];
            const float4 b = *(const float4*)&Ws[k][tx * 4];
            acc[0][0] = fmaf(a.x, b.x, acc[0][0]);
            acc[0][1] = fmaf(a.x, b.y, acc[0][1]);
            acc[0][2] = fmaf(a.x, b.z, acc[0][2]);
            acc[0][3] = fmaf(a.x, b.w, acc[0][3]);
            acc[1][0] = fmaf(a.y, b.x, acc[1][0]);
            acc[1][1] = fmaf(a.y, b.y, acc[1][1]);
            acc[1][2] = fmaf(a.y, b.z, acc[1][2]);
            acc[1][3] = fmaf(a.y, b.w, acc[1][3]);
            acc[2][0] = fmaf(a.z, b.x, acc[2][0]);
            acc[2][1] = fmaf(a.z, b.y, acc[2][1]);
            acc[2][2] = fmaf(a.z, b.z, acc[2][2]);
            acc[2][3] = fmaf(a.z, b.w, acc[2][3]);
            acc[3][0] = fmaf(a.w, b.x, acc[3][0]);
            acc[3][1] = fmaf(a.w, b.y, acc[3][1]);
            acc[3][2] = fmaf(a.w, b.z, acc[3][2]);
            acc[3][3] = fmaf(a.w, b.w, acc[3][3]);
        }
        __syncthreads();
    }
    #pragma unroll
    for (int i = 0; i < 4; ++i) {
        const int m = m0 + ty * 4 + i;
        #pragma unroll
        for (int j = 0; j < 4; ++j) {
            const int n = n0 + tx * 4 + j;
            if (n < N) {
                float v = acc[i][j];
                if (EPI == 1) v = silu_f(v);
                if (EPI == 2) v = softplus_f(v + bias[n]);
                float* p = C + (size_t)m * ldc + n;
                if (EPI == 3) *p += v; else *p = v;
            }
        }
    }
}

// h[b*T+t, :] = (t < P) ? p[b*P+t, :] : x[b*S + (t-P), :]
__global__ __launch_bounds__(256) void assemble_h_kernel(
    const float* __restrict__ p, const float* __restrict__ x, float* __restrict__ h)
{
    const int idx = blockIdx.x * 256 + threadIdx.x;   // over M_*D_/4 float4s
    const int r = idx >> 8;                            // D_/4 = 256
    const int c = idx & 255;
    const int b = r / T_;
    const int t = r - b * T_;
    float4 v;
    if (t < P_) v = ((const float4*)p)[(size_t)(b * P_ + t) * 256 + c];
    else        v = ((const float4*)x)[(size_t)(b * S_ + (t - P_)) * 256 + c];
    ((float4*)h)[idx] = v;
}

// one block per row, 256 threads, D_=1024
__global__ __launch_bounds__(256) void rmsnorm_kernel(
    const float* __restrict__ x, const float* __restrict__ w, float* __restrict__ out)
{
    const int r = blockIdx.x;
    const float4 v = ((const float4*)(x + (size_t)r * D_))[threadIdx.x];
    float ss = v.x * v.x + v.y * v.y + v.z * v.z + v.w * v.w;
    ss += __shfl_xor(ss, 32, 64);
    ss += __shfl_xor(ss, 16, 64);
    ss += __shfl_xor(ss, 8, 64);
    ss += __shfl_xor(ss, 4, 64);
    ss += __shfl_xor(ss, 2, 64);
    ss += __shfl_xor(ss, 1, 64);
    __shared__ float red[4];
    if ((threadIdx.x & 63) == 0) red[threadIdx.x >> 6] = ss;
    __syncthreads();
    const float tot = red[0] + red[1] + red[2] + red[3];
    const float scale = rsqrtf(tot * (1.f / D_) + 1e-5f);
    const float4 wv = ((const float4*)w)[threadIdx.x];
    float4 o;
    o.x = v.x * scale * wv.x; o.y = v.y * scale * wv.y;
    o.z = v.z * scale * wv.z; o.w = v.w * scale * wv.w;
    ((float4*)(out + (size_t)r * D_))[threadIdx.x] = o;
}

// rows r over B*S; reads h[b*T+P+s], writes out[b*S+s]
__global__ __launch_bounds__(256) void final_rmsnorm_kernel(
    const float* __restrict__ h, const float* __restrict__ w, float* __restrict__ out)
{
    const int r = blockIdx.x;               // 0..B*S-1
    const int b = r / S_;
    const int s = r - b * S_;
    const int hr = b * T_ + P_ + s;
    const float4 v = ((const float4*)(h + (size_t)hr * D_))[threadIdx.x];
    float ss = v.x * v.x + v.y * v.y + v.z * v.z + v.w * v.w;
    ss += __shfl_xor(ss, 32, 64);
    ss += __shfl_xor(ss, 16, 64);
    ss += __shfl_xor(ss, 8, 64);
    ss += __shfl_xor(ss, 4, 64);
    ss += __shfl_xor(ss, 2, 64);
    ss += __shfl_xor(ss, 1, 64);
    __shared__ float red[4];
    if ((threadIdx.x & 63) == 0) red[threadIdx.x >> 6] = ss;
    __syncthreads();
    const float tot = red[0] + red[1] + red[2] + red[3];
    const float scale = rsqrtf(tot * (1.f / D_) + 1e-5f);
    const float4 wv = ((const float4*)w)[threadIdx.x];
    float4 o;
    o.x = v.x * scale * wv.x; o.y = v.y * scale * wv.y;
    o.z = v.z * scale * wv.z; o.w = v.w * scale * wv.w;
    ((float4*)(out + (size_t)r * D_))[threadIdx.x] = o;
}

// causal depthwise conv (DC=4) + bias + silu. xz: [M_, 2*DI_], first DI_ cols.
__global__ __launch_bounds__(256) void conv_silu_kernel(
    const float* __restrict__ xz, const float* __restrict__ cw,
    const float* __restrict__ cb, float* __restrict__ xi)
{
    const int idx = blockIdx.x * 256 + threadIdx.x;   // over M_*DI_
    const int e = idx & (DI_ - 1);
    const int r = idx >> 11;
    const int b = r / T_;
    const int t = r - b * T_;
    const float4 w = *(const float4*)(cw + (size_t)e * 4);
    const float x3 = xz[(size_t)r * (2 * DI_) + e];
    const float x2 = (t >= 1) ? xz[(size_t)(r - 1) * (2 * DI_) + e] : 0.f;
    const float x1 = (t >= 2) ? xz[(size_t)(r - 2) * (2 * DI_) + e] : 0.f;
    const float x0 = (t >= 3) ? xz[(size_t)(r - 3) * (2 * DI_) + e] : 0.f;
    float v = cb[e];
    v = fmaf(w.x, x0, v);
    v = fmaf(w.y, x1, v);
    v = fmaf(w.z, x2, v);
    v = fmaf(w.w, x3, v);
    xi[idx] = silu_f(v);
}

// ---------------------------------------------------------------------------
// Chunked selective scan. Linear recurrence h_t = da_t*h_{t-1} + dbu_t is
// associative: phase 1 computes per-chunk (prod da, h_partial | h_in=0),
// phase 2 does a tiny sequential prefix over NC=9 chunk summaries, phase 3
// replays each chunk from its known h_in and emits gated outputs.
// Lane mapping (phases 1/3): g -> s=g&15, e=(g>>4)&2047, b=(g>>15)&1, c=g>>16.
// Parallelism: NC*B*DI*DS = 589824 lanes -> full occupancy (vs 65536 before).
// ---------------------------------------------------------------------------
__global__ __launch_bounds__(256) void scan_chunk1_kernel(
    const float* __restrict__ dt,    // [M_, DI_]
    const float* __restrict__ xdbl,  // [M_, 96]
    const float* __restrict__ xi,    // [M_, DI_]
    const float* __restrict__ A_log, // [DI_, DS_] layer slice
    float* __restrict__ Ap,          // [NC, B, DI, DS]
    float* __restrict__ Hp)          // [NC, B, DI, DS]
{
    const int g = blockIdx.x * 256 + threadIdx.x;
    const int s = g & (DS_ - 1);
    const int e = (g >> 4) & (DI_ - 1);
    const int b = (g >> 15) & (B_ - 1);
    const int c = g >> 16;
    const float Aval = -__expf(A_log[(size_t)e * DS_ + s]);
    float ap = 1.f, hp = 0.f;
    const int r0 = b * T_ + c * CCH;
    for (int t = 0; t < CCH; ++t) {
        const int r = r0 + t;
        const float dtv = dt[(size_t)r * DI_ + e];
        const float u   = xi[(size_t)r * DI_ + e];
        const float bv  = xdbl[(size_t)r * 96 + DR_ + s];
        const float da  = __expf(dtv * Aval);
        ap *= da;
        hp = fmaf(da, hp, dtv * bv * u);
    }
    const size_t o = (((size_t)c * B_ + b) * DI_ + e) * DS_ + s;
    Ap[o] = ap; Hp[o] = hp;
}

// prefix over chunks, in place: after this, Hp[c] = h at the START of chunk c.
__global__ __launch_bounds__(256) void scan_chunk2_kernel(
    float* __restrict__ Ap, float* __restrict__ Hp)
{
    const int g = blockIdx.x * 256 + threadIdx.x;     // 0..B_*DI_*DS_-1
    float h = 0.f;
    #pragma unroll
    for (int c = 0; c < NC; ++c) {
        const size_t o = (size_t)c * (B_ * DI_ * DS_) + g;
        const float ap = Ap[o];
        const float hp = Hp[o];
        Hp[o] = h;
        h = fmaf(ap, h, hp);
    }
}

__global__ __launch_bounds__(256) void scan_chunk3_kernel(
    const float* __restrict__ dt,    // [M_, DI_]
    const float* __restrict__ xdbl,  // [M_, 96]
    const float* __restrict__ xi,    // [M_, DI_]
    const float* __restrict__ xz,    // [M_, 2*DI_] (z at cols DI_..)
    const float* __restrict__ A_log, // [DI_, DS_]
    const float* __restrict__ Dp,    // [DI_]
    const float* __restrict__ Hin,   // [NC, B, DI, DS] (phase-2 output)
    float* __restrict__ y)           // [M_, DI_]
{
    const int g = blockIdx.x * 256 + threadIdx.x;
    const int s = g & (DS_ - 1);
    const int e = (g >> 4) & (DI_ - 1);
    const int b = (g >> 15) & (B_ - 1);
    const int c = g >> 16;
    const float Aval = -__expf(A_log[(size_t)e * DS_ + s]);
    const float dpe = Dp[e];
    float h = Hin[(((size_t)c * B_ + b) * DI_ + e) * DS_ + s];
    const int r0 = b * T_ + c * CCH;
    for (int t = 0; t < CCH; ++t) {
        const int r = r0 + t;
        const float dtv = dt[(size_t)r * DI_ + e];
        const float u   = xi[(size_t)r * DI_ + e];
        const float bv  = xdbl[(size_t)r * 96 + DR_ + s];
        const float cv  = xdbl[(size_t)r * 96 + DR_ + DS_ + s];
        const float da  = __expf(dtv * Aval);
        h = fmaf(da, h, dtv * bv * u);
        float contrib = h * cv;
        contrib += __shfl_xor(contrib, 1, 64);
        contrib += __shfl_xor(contrib, 2, 64);
        contrib += __shfl_xor(contrib, 4, 64);
        contrib += __shfl_xor(contrib, 8, 64);
        if (s == 0) {
            const float z = xz[(size_t)r * (2 * DI_) + DI_ + e];
            y[(size_t)r * DI_ + e] = (contrib + u * dpe) * silu_f(z);
        }
    }
}

extern "C" void kernel_launch(void* const* d_in, const int* in_sizes, int n_in,
                              void* d_out, int out_size, void* d_ws, size_t ws_size,
                              hipStream_t stream)
{
    const float* x       = (const float*)d_in[0];
    const float* pc      = (const float*)d_in[1];
    const float* pre_w1  = (const float*)d_in[2];
    const float* pre_w2  = (const float*)d_in[3];
    const float* norm_w  = (const float*)d_in[4];
    const float* ip_w    = (const float*)d_in[5];
    const float* conv_w  = (const float*)d_in[6];
    const float* conv_b  = (const float*)d_in[7];
    const float* xp_w    = (const float*)d_in[8];
    const float* dtp_w   = (const float*)d_in[9];
    const float* dtp_b   = (const float*)d_in[10];
    const float* A_log   = (const float*)d_in[11];
    const float* D_param = (const float*)d_in[12];
    const float* op_w    = (const float*)d_in[13];
    const float* fnw     = (const float*)d_in[14];
    float* out = (float*)d_out;

    float* ws = (float*)d_ws;
    float* h    = ws;  ws += (size_t)M_ * D_;          // 1179648
    float* xn   = ws;  ws += (size_t)M_ * D_;          // 1179648
    float* xz   = ws;  ws += (size_t)M_ * 2 * DI_;     // 4718592
    float* xi   = ws;  ws += (size_t)M_ * DI_;         // 2359296
    float* xdbl = ws;  ws += (size_t)M_ * 96;          // 110592
    float* dtb  = ws;  ws += (size_t)M_ * DI_;         // 2359296
    float* yb   = ws;  ws += (size_t)M_ * DI_;         // 2359296
    // prepend temporaries alias xz (consumed before layer 0 writes xz)
    float* tmp1 = xz;
    float* tmp2 = xz + (size_t)B_ * P_ * D_;
    // chunk-scan summaries alias xn (dead between in_proj and next rmsnorm):
    // Ap+Hp = 2*NC*B*DI*DS = 1179648 floats = exactly M_*D_.
    float* Ap = xn;
    float* Hp = xn + (size_t)NC * B_ * DI_ * DS_;

    const dim3 blk(256);

    // prepend embed: tmp1 = silu(pc @ pre_w1); tmp2 = tmp1 @ pre_w2
    gemm_kernel<1, false><<<dim3(D_ / 64, (B_ * P_) / 64), blk, 0, stream>>>(
        pc, pre_w1, tmp1, nullptr, B_ * P_, D_, PCD_, PCD_, D_, D_);
    gemm_kernel<0, false><<<dim3(D_ / 64, (B_ * P_) / 64), blk, 0, stream>>>(
        tmp1, pre_w2, tmp2, nullptr, B_ * P_, D_, D_, D_, D_, D_);
    assemble_h_kernel<<<dim3(M_ * D_ / 4 / 256), blk, 0, stream>>>(tmp2, x, h);

    for (int l = 0; l < L_; ++l) {
        rmsnorm_kernel<<<dim3(M_), blk, 0, stream>>>(h, norm_w + (size_t)l * D_, xn);
        // in_proj: xz = xn @ ip_w^T   [M,4096,K=1024]
        gemm_kernel<0, true><<<dim3(2 * DI_ / 64, M_ / 64), blk, 0, stream>>>(
            xn, ip_w + (size_t)l * 2 * DI_ * D_, xz, nullptr,
            M_, 2 * DI_, D_, D_, D_, 2 * DI_);
        conv_silu_kernel<<<dim3(M_ * DI_ / 256), blk, 0, stream>>>(
            xz, conv_w + (size_t)l * DI_ * DC_, conv_b + (size_t)l * DI_, xi);
        // x_proj: xdbl = xi @ xp_w^T  [M,96,K=2048]
        gemm_kernel<0, true><<<dim3(2, M_ / 64), blk, 0, stream>>>(
            xi, xp_w + (size_t)l * 96 * DI_, xdbl, nullptr,
            M_, 96, DI_, DI_, DI_, 96);
        // dt_proj: dtb = softplus(xdbl[:, :64] @ dtp_w^T + dtp_b)  [M,2048,K=64]
        gemm_kernel<2, true><<<dim3(DI_ / 64, M_ / 64), blk, 0, stream>>>(
            xdbl, dtp_w + (size_t)l * DI_ * DR_, dtb, dtp_b + (size_t)l * DI_,
            M_, DI_, DR_, 96, DR_, DI_);
        // chunked scan (NOTE: Ap/Hp alias xn — xn is dead here)
        scan_chunk1_kernel<<<dim3(NC * B_ * DI_ * DS_ / 256), blk, 0, stream>>>(
            dtb, xdbl, xi, A_log + (size_t)l * DI_ * DS_, Ap, Hp);
        scan_chunk2_kernel<<<dim3(B_ * DI_ * DS_ / 256), blk, 0, stream>>>(Ap, Hp);
        scan_chunk3_kernel<<<dim3(NC * B_ * DI_ * DS_ / 256), blk, 0, stream>>>(
            dtb, xdbl, xi, xz, A_log + (size_t)l * DI_ * DS_,
            D_param + (size_t)l * DI_, Hp, yb);
        // out_proj + residual: h += yb @ op_w^T  [M,1024,K=2048]
        gemm_kernel<3, true><<<dim3(D_ / 64, M_ / 64), blk, 0, stream>>>(
            yb, op_w + (size_t)l * D_ * DI_, h, nullptr,
            M_, D_, DI_, DI_, DI_, D_);
    }

    final_rmsnorm_kernel<<<dim3(B_ * S_), blk, 0, stream>>>(h, fnw, out);
}

// Round 3
// 1800.661 us; speedup vs baseline: 2.0814x; 1.4216x over previous
//
#include <hip/hip_runtime.h>
#include <math.h>

#define B_ 2
#define S_ 512
#define P_ 64
#define T_ 576          // P_+S_
#define D_ 1024
#define L_ 4
#define DI_ 2048
#define DS_ 16
#define DC_ 4
#define DR_ 64
#define PCD_ 768
#define M_ (B_*T_)      // 1152
#define CCH 64          // scan chunk length
#define NC (T_/CCH)     // 9 chunks

typedef __attribute__((ext_vector_type(8))) short bf16x8;
typedef __attribute__((ext_vector_type(4))) float f32x4;

__device__ __forceinline__ float silu_f(float v) { return v / (1.f + __expf(-v)); }
__device__ __forceinline__ float softplus_f(float v) {
    return fmaxf(v, 0.f) + log1pf(__expf(-fabsf(v)));
}
__device__ __forceinline__ unsigned short bf16_rne(float x) {
    unsigned int b = __float_as_uint(x);
    b += 0x7fffu + ((b >> 16) & 1u);
    return (unsigned short)(b >> 16);
}

typedef const void __attribute__((address_space(1)))* gas_t;
typedef void __attribute__((address_space(3)))* las_t;
__device__ __forceinline__ void async16(const void* g, void* l) {
    // wave-uniform LDS base; HW scatters lane i -> base + i*16 bytes
    __builtin_amdgcn_global_load_lds((gas_t)g, (las_t)l, 16, 0, 0);
}

// ---------------------------------------------------------------------------
// bf16 MFMA GEMM (m97 structure): C[m,n] (+)= sum_k A[m,k]*W[n,k], fp32 out.
// BM=BN=128, BK=32, 256 threads = 4 waves (2x2), each wave 64x64 via 4x4
// mfma_f32_16x16x32_bf16. Requires M%128==0, N%128==0, K%32==0.
// EPI: 0 = store, 3 = accumulate into C (residual).
// ---------------------------------------------------------------------------
template<int EPI>
__global__ __launch_bounds__(256) void gemm_mfma_kernel(
    const unsigned short* __restrict__ A, const unsigned short* __restrict__ W,
    float* __restrict__ C, int M, int N, int K)
{
    __shared__ unsigned short As[128 * 32];
    __shared__ unsigned short Bs[128 * 32];
    const int tid = threadIdx.x;
    const int wave = tid >> 6;
    const int lane = tid & 63;
    const int m0 = blockIdx.y * 128, n0 = blockIdx.x * 128;
    const int wm = (wave >> 1) * 64, wn = (wave & 1) * 64;

    // staging: wave w covers tile rows [w*32, w*32+32) in two 16-row issues
    const int srow = (wave << 5) + (lane >> 2);
    const int selem = (lane & 3) * 8;
    const unsigned short* gA = A + (size_t)(m0 + srow) * K + selem;
    const unsigned short* gB = W + (size_t)(n0 + srow) * K + selem;
    unsigned short* lA = As + (wave << 5) * 32;
    unsigned short* lB = Bs + (wave << 5) * 32;

    f32x4 acc[4][4];
    #pragma unroll
    for (int i = 0; i < 4; ++i)
        #pragma unroll
        for (int j = 0; j < 4; ++j)
            acc[i][j] = (f32x4){0.f, 0.f, 0.f, 0.f};

    const int fr = lane & 15;       // fragment row (m or n within 16)
    const int fq = lane >> 4;       // quad -> k offset fq*8, D-row fq*4
    const int aoff = (wm + fr) * 32 + fq * 8;
    const int boff = (wn + fr) * 32 + fq * 8;

    for (int k0 = 0; k0 < K; k0 += 32) {
        async16(gA, lA);
        async16(gA + (size_t)16 * K, lA + 16 * 32);
        async16(gB, lB);
        async16(gB + (size_t)16 * K, lB + 16 * 32);
        gA += 32; gB += 32;
        __syncthreads();            // drains vmcnt -> LDS visible
        bf16x8 af[4], bf[4];
        #pragma unroll
        for (int i = 0; i < 4; ++i) af[i] = *(const bf16x8*)&As[aoff + i * 512];
        #pragma unroll
        for (int j = 0; j < 4; ++j) bf[j] = *(const bf16x8*)&Bs[boff + j * 512];
        #pragma unroll
        for (int i = 0; i < 4; ++i)
            #pragma unroll
            for (int j = 0; j < 4; ++j)
                acc[i][j] = __builtin_amdgcn_mfma_f32_16x16x32_bf16(
                    af[i], bf[j], acc[i][j], 0, 0, 0);
        __syncthreads();            // LDS reads done before next staging
    }

    // C/D layout (m89-verified): col = lane&15, row = (lane>>4)*4 + reg
    #pragma unroll
    for (int i = 0; i < 4; ++i) {
        const int m = m0 + wm + i * 16 + fq * 4;
        #pragma unroll
        for (int j = 0; j < 4; ++j) {
            const int n = n0 + wn + j * 16 + fr;
            float* p = C + (size_t)m * N + n;
            #pragma unroll
            for (int r = 0; r < 4; ++r) {
                const float v = acc[i][j][r];
                if (EPI == 3) p[(size_t)r * N] += v;
                else          p[(size_t)r * N] = v;
            }
        }
    }
}

// fp32 -> bf16 (RNE), vectorized x4
__global__ __launch_bounds__(256) void cvt_bf16_kernel(
    const float* __restrict__ in, unsigned short* __restrict__ out, int n4)
{
    const int i = blockIdx.x * 256 + threadIdx.x;
    if (i >= n4) return;
    const float4 v = ((const float4*)in)[i];
    ushort4 o;
    o.x = bf16_rne(v.x); o.y = bf16_rne(v.y);
    o.z = bf16_rne(v.z); o.w = bf16_rne(v.w);
    ((ushort4*)out)[i] = o;
}

// ---------------------------------------------------------------------------
// Generic tiled fp32 GEMM (kept for prepend / x_proj / dt_proj).
//  NT=true :  C[m,n] = sum_k A[m*lda+k] * W[n*ldw+k]
//  NT=false:  C[m,n] = sum_k A[m*lda+k] * W[k*ldw+n]
// EPI: 0 plain, 1 silu, 2 softplus(v + bias[n])
// ---------------------------------------------------------------------------
template<int EPI, bool NT>
__global__ __launch_bounds__(256) void gemm_kernel(
    const float* __restrict__ A, const float* __restrict__ W,
    float* __restrict__ C, const float* __restrict__ bias,
    int M, int N, int K, int lda, int ldw, int ldc)
{
    __shared__ __align__(16) float As[16][68];
    __shared__ __align__(16) float Ws[16][68];
    const int m0 = blockIdx.y * 64;
    const int n0 = blockIdx.x * 64;
    const int tid = threadIdx.x;
    const int ty = tid >> 4;
    const int tx = tid & 15;
    float acc[4][4] = {};

    const int lr = tid >> 2;
    const int lk = (tid & 3) * 4;
    const int kk = tid >> 4;
    const int nq = (tid & 15) * 4;

    for (int k0 = 0; k0 < K; k0 += 16) {
        {
            const float4 v = *(const float4*)(A + (size_t)(m0 + lr) * lda + k0 + lk);
            As[lk + 0][lr] = v.x; As[lk + 1][lr] = v.y;
            As[lk + 2][lr] = v.z; As[lk + 3][lr] = v.w;
        }
        if (NT) {
            const int n = n0 + lr;
            float4 v = make_float4(0.f, 0.f, 0.f, 0.f);
            if (n < N) v = *(const float4*)(W + (size_t)n * ldw + k0 + lk);
            Ws[lk + 0][lr] = v.x; Ws[lk + 1][lr] = v.y;
            Ws[lk + 2][lr] = v.z; Ws[lk + 3][lr] = v.w;
        } else {
            const int n = n0 + nq;
            float4 v = make_float4(0.f, 0.f, 0.f, 0.f);
            if (n < N) v = *(const float4*)(W + (size_t)(k0 + kk) * ldw + n);
            Ws[kk][nq + 0] = v.x; Ws[kk][nq + 1] = v.y;
            Ws[kk][nq + 2] = v.z; Ws[kk][nq + 3] = v.w;
        }
        __syncthreads();
        #pragma unroll
        for (int k = 0; k < 16; ++k) {
            const float4 a = *(const float4*)&As[k][ty * 4];
            const float4 b = *(const float4*)&Ws[k][tx * 4];
            acc[0][0] = fmaf(a.x, b.x, acc[0][0]);
            acc[0][1] = fmaf(a.x, b.y, acc[0][1]);
            acc[0][2] = fmaf(a.x, b.z, acc[0][2]);
            acc[0][3] = fmaf(a.x, b.w, acc[0][3]);
            acc[1][0] = fmaf(a.y, b.x, acc[1][0]);
            acc[1][1] = fmaf(a.y, b.y, acc[1][1]);
            acc[1][2] = fmaf(a.y, b.z, acc[1][2]);
            acc[1][3] = fmaf(a.y, b.w, acc[1][3]);
            acc[2][0] = fmaf(a.z, b.x, acc[2][0]);
            acc[2][1] = fmaf(a.z, b.y, acc[2][1]);
            acc[2][2] = fmaf(a.z, b.z, acc[2][2]);
            acc[2][3] = fmaf(a.z, b.w, acc[2][3]);
            acc[3][0] = fmaf(a.w, b.x, acc[3][0]);
            acc[3][1] = fmaf(a.w, b.y, acc[3][1]);
            acc[3][2] = fmaf(a.w, b.z, acc[3][2]);
            acc[3][3] = fmaf(a.w, b.w, acc[3][3]);
        }
        __syncthreads();
    }
    #pragma unroll
    for (int i = 0; i < 4; ++i) {
        const int m = m0 + ty * 4 + i;
        #pragma unroll
        for (int j = 0; j < 4; ++j) {
            const int n = n0 + tx * 4 + j;
            if (n < N) {
                float v = acc[i][j];
                if (EPI == 1) v = silu_f(v);
                if (EPI == 2) v = softplus_f(v + bias[n]);
                C[(size_t)m * ldc + n] = v;
            }
        }
    }
}

// h[b*T+t, :] = (t < P) ? p[b*P+t, :] : x[b*S + (t-P), :]
__global__ __launch_bounds__(256) void assemble_h_kernel(
    const float* __restrict__ p, const float* __restrict__ x, float* __restrict__ h)
{
    const int idx = blockIdx.x * 256 + threadIdx.x;
    const int r = idx >> 8;
    const int c = idx & 255;
    const int b = r / T_;
    const int t = r - b * T_;
    float4 v;
    if (t < P_) v = ((const float4*)p)[(size_t)(b * P_ + t) * 256 + c];
    else        v = ((const float4*)x)[(size_t)(b * S_ + (t - P_)) * 256 + c];
    ((float4*)h)[idx] = v;
}

// rmsnorm -> bf16 output (feeds in_proj MFMA). one block per row.
__global__ __launch_bounds__(256) void rmsnorm_bf16_kernel(
    const float* __restrict__ x, const float* __restrict__ w,
    unsigned short* __restrict__ outb)
{
    const int r = blockIdx.x;
    const float4 v = ((const float4*)(x + (size_t)r * D_))[threadIdx.x];
    float ss = v.x * v.x + v.y * v.y + v.z * v.z + v.w * v.w;
    ss += __shfl_xor(ss, 32, 64);
    ss += __shfl_xor(ss, 16, 64);
    ss += __shfl_xor(ss, 8, 64);
    ss += __shfl_xor(ss, 4, 64);
    ss += __shfl_xor(ss, 2, 64);
    ss += __shfl_xor(ss, 1, 64);
    __shared__ float red[4];
    if ((threadIdx.x & 63) == 0) red[threadIdx.x >> 6] = ss;
    __syncthreads();
    const float tot = red[0] + red[1] + red[2] + red[3];
    const float scale = rsqrtf(tot * (1.f / D_) + 1e-5f);
    const float4 wv = ((const float4*)w)[threadIdx.x];
    ushort4 o;
    o.x = bf16_rne(v.x * scale * wv.x);
    o.y = bf16_rne(v.y * scale * wv.y);
    o.z = bf16_rne(v.z * scale * wv.z);
    o.w = bf16_rne(v.w * scale * wv.w);
    ((ushort4*)(outb + (size_t)r * D_))[threadIdx.x] = o;
}

// final rmsnorm (fp32 out): rows over B*S; reads h[b*T+P+s]
__global__ __launch_bounds__(256) void final_rmsnorm_kernel(
    const float* __restrict__ h, const float* __restrict__ w, float* __restrict__ out)
{
    const int r = blockIdx.x;
    const int b = r / S_;
    const int s = r - b * S_;
    const int hr = b * T_ + P_ + s;
    const float4 v = ((const float4*)(h + (size_t)hr * D_))[threadIdx.x];
    float ss = v.x * v.x + v.y * v.y + v.z * v.z + v.w * v.w;
    ss += __shfl_xor(ss, 32, 64);
    ss += __shfl_xor(ss, 16, 64);
    ss += __shfl_xor(ss, 8, 64);
    ss += __shfl_xor(ss, 4, 64);
    ss += __shfl_xor(ss, 2, 64);
    ss += __shfl_xor(ss, 1, 64);
    __shared__ float red[4];
    if ((threadIdx.x & 63) == 0) red[threadIdx.x >> 6] = ss;
    __syncthreads();
    const float tot = red[0] + red[1] + red[2] + red[3];
    const float scale = rsqrtf(tot * (1.f / D_) + 1e-5f);
    const float4 wv = ((const float4*)w)[threadIdx.x];
    float4 o;
    o.x = v.x * scale * wv.x; o.y = v.y * scale * wv.y;
    o.z = v.z * scale * wv.z; o.w = v.w * scale * wv.w;
    ((float4*)(out + (size_t)r * D_))[threadIdx.x] = o;
}

// causal depthwise conv (DC=4) + bias + silu
__global__ __launch_bounds__(256) void conv_silu_kernel(
    const float* __restrict__ xz, const float* __restrict__ cw,
    const float* __restrict__ cb, float* __restrict__ xi)
{
    const int idx = blockIdx.x * 256 + threadIdx.x;
    const int e = idx & (DI_ - 1);
    const int r = idx >> 11;
    const int b = r / T_;
    const int t = r - b * T_;
    const float4 w = *(const float4*)(cw + (size_t)e * 4);
    const float x3 = xz[(size_t)r * (2 * DI_) + e];
    const float x2 = (t >= 1) ? xz[(size_t)(r - 1) * (2 * DI_) + e] : 0.f;
    const float x1 = (t >= 2) ? xz[(size_t)(r - 2) * (2 * DI_) + e] : 0.f;
    const float x0 = (t >= 3) ? xz[(size_t)(r - 3) * (2 * DI_) + e] : 0.f;
    float v = cb[e];
    v = fmaf(w.x, x0, v);
    v = fmaf(w.y, x1, v);
    v = fmaf(w.z, x2, v);
    v = fmaf(w.w, x3, v);
    xi[idx] = silu_f(v);
}

// ---------------------------------------------------------------------------
// Chunked selective scan (associative rearrangement; see R2 notes).
// ---------------------------------------------------------------------------
__global__ __launch_bounds__(256) void scan_chunk1_kernel(
    const float* __restrict__ dt, const float* __restrict__ xdbl,
    const float* __restrict__ xi, const float* __restrict__ A_log,
    float* __restrict__ Ap, float* __restrict__ Hp)
{
    const int g = blockIdx.x * 256 + threadIdx.x;
    const int s = g & (DS_ - 1);
    const int e = (g >> 4) & (DI_ - 1);
    const int b = (g >> 15) & (B_ - 1);
    const int c = g >> 16;
    const float Aval = -__expf(A_log[(size_t)e * DS_ + s]);
    float ap = 1.f, hp = 0.f;
    const int r0 = b * T_ + c * CCH;
    for (int t = 0; t < CCH; ++t) {
        const int r = r0 + t;
        const float dtv = dt[(size_t)r * DI_ + e];
        const float u   = xi[(size_t)r * DI_ + e];
        const float bv  = xdbl[(size_t)r * 96 + DR_ + s];
        const float da  = __expf(dtv * Aval);
        ap *= da;
        hp = fmaf(da, hp, dtv * bv * u);
    }
    const size_t o = (((size_t)c * B_ + b) * DI_ + e) * DS_ + s;
    Ap[o] = ap; Hp[o] = hp;
}

__global__ __launch_bounds__(256) void scan_chunk2_kernel(
    float* __restrict__ Ap, float* __restrict__ Hp)
{
    const int g = blockIdx.x * 256 + threadIdx.x;
    float h = 0.f;
    #pragma unroll
    for (int c = 0; c < NC; ++c) {
        const size_t o = (size_t)c * (B_ * DI_ * DS_) + g;
        const float ap = Ap[o];
        const float hp = Hp[o];
        Hp[o] = h;
        h = fmaf(ap, h, hp);
    }
}

__global__ __launch_bounds__(256) void scan_chunk3_kernel(
    const float* __restrict__ dt, const float* __restrict__ xdbl,
    const float* __restrict__ xi, const float* __restrict__ xz,
    const float* __restrict__ A_log, const float* __restrict__ Dp,
    const float* __restrict__ Hin, unsigned short* __restrict__ y)
{
    const int g = blockIdx.x * 256 + threadIdx.x;
    const int s = g & (DS_ - 1);
    const int e = (g >> 4) & (DI_ - 1);
    const int b = (g >> 15) & (B_ - 1);
    const int c = g >> 16;
    const float Aval = -__expf(A_log[(size_t)e * DS_ + s]);
    const float dpe = Dp[e];
    float h = Hin[(((size_t)c * B_ + b) * DI_ + e) * DS_ + s];
    const int r0 = b * T_ + c * CCH;
    for (int t = 0; t < CCH; ++t) {
        const int r = r0 + t;
        const float dtv = dt[(size_t)r * DI_ + e];
        const float u   = xi[(size_t)r * DI_ + e];
        const float bv  = xdbl[(size_t)r * 96 + DR_ + s];
        const float cv  = xdbl[(size_t)r * 96 + DR_ + DS_ + s];
        const float da  = __expf(dtv * Aval);
        h = fmaf(da, h, dtv * bv * u);
        float contrib = h * cv;
        contrib += __shfl_xor(contrib, 1, 64);
        contrib += __shfl_xor(contrib, 2, 64);
        contrib += __shfl_xor(contrib, 4, 64);
        contrib += __shfl_xor(contrib, 8, 64);
        if (s == 0) {
            const float z = xz[(size_t)r * (2 * DI_) + DI_ + e];
            y[(size_t)r * DI_ + e] = bf16_rne((contrib + u * dpe) * silu_f(z));
        }
    }
}

extern "C" void kernel_launch(void* const* d_in, const int* in_sizes, int n_in,
                              void* d_out, int out_size, void* d_ws, size_t ws_size,
                              hipStream_t stream)
{
    const float* x       = (const float*)d_in[0];
    const float* pc      = (const float*)d_in[1];
    const float* pre_w1  = (const float*)d_in[2];
    const float* pre_w2  = (const float*)d_in[3];
    const float* norm_w  = (const float*)d_in[4];
    const float* ip_w    = (const float*)d_in[5];
    const float* conv_w  = (const float*)d_in[6];
    const float* conv_b  = (const float*)d_in[7];
    const float* xp_w    = (const float*)d_in[8];
    const float* dtp_w   = (const float*)d_in[9];
    const float* dtp_b   = (const float*)d_in[10];
    const float* A_log   = (const float*)d_in[11];
    const float* D_param = (const float*)d_in[12];
    const float* op_w    = (const float*)d_in[13];
    const float* fnw     = (const float*)d_in[14];
    float* out = (float*)d_out;

    float* ws = (float*)d_ws;
    float* h    = ws;  ws += (size_t)M_ * D_;            // fp32 residual
    float* xz   = ws;  ws += (size_t)M_ * 2 * DI_;       // in_proj out
    float* xi   = ws;  ws += (size_t)M_ * DI_;           // conv out
    float* xdbl = ws;  ws += (size_t)M_ * 96;
    float* dtb  = ws;  ws += (size_t)M_ * DI_;
    float* Ap   = ws;  ws += (size_t)NC * B_ * DI_ * DS_;
    float* Hp   = ws;  ws += (size_t)NC * B_ * DI_ * DS_;
    unsigned short* xn_bf = (unsigned short*)ws;  ws += (size_t)M_ * D_ / 2;
    unsigned short* yb_bf = (unsigned short*)ws;  ws += (size_t)M_ * DI_ / 2;
    unsigned short* wbuf  = (unsigned short*)ws;  ws += (size_t)2 * DI_ * D_ / 2;
    // prepend temporaries alias xz (consumed before layer 0 writes xz)
    float* tmp1 = xz;
    float* tmp2 = xz + (size_t)B_ * P_ * D_;

    const dim3 blk(256);

    // prepend embed: tmp1 = silu(pc @ pre_w1); tmp2 = tmp1 @ pre_w2
    gemm_kernel<1, false><<<dim3(D_ / 64, (B_ * P_) / 64), blk, 0, stream>>>(
        pc, pre_w1, tmp1, nullptr, B_ * P_, D_, PCD_, PCD_, D_, D_);
    gemm_kernel<0, false><<<dim3(D_ / 64, (B_ * P_) / 64), blk, 0, stream>>>(
        tmp1, pre_w2, tmp2, nullptr, B_ * P_, D_, D_, D_, D_, D_);
    assemble_h_kernel<<<dim3(M_ * D_ / 4 / 256), blk, 0, stream>>>(tmp2, x, h);

    for (int l = 0; l < L_; ++l) {
        rmsnorm_bf16_kernel<<<dim3(M_), blk, 0, stream>>>(
            h, norm_w + (size_t)l * D_, xn_bf);
        // convert in_proj weights for this layer -> bf16
        cvt_bf16_kernel<<<dim3(2 * DI_ * D_ / 4 / 256), blk, 0, stream>>>(
            ip_w + (size_t)l * 2 * DI_ * D_, wbuf, 2 * DI_ * D_ / 4);
        // in_proj (MFMA): xz = xn @ ip_w^T   [1152, 4096, K=1024]
        gemm_mfma_kernel<0><<<dim3(2 * DI_ / 128, M_ / 128), blk, 0, stream>>>(
            xn_bf, wbuf, xz, M_, 2 * DI_, D_);
        conv_silu_kernel<<<dim3(M_ * DI_ / 256), blk, 0, stream>>>(
            xz, conv_w + (size_t)l * DI_ * DC_, conv_b + (size_t)l * DI_, xi);
        // x_proj (fp32): xdbl = xi @ xp_w^T  [1152, 96, K=2048]
        gemm_kernel<0, true><<<dim3(2, M_ / 64), blk, 0, stream>>>(
            xi, xp_w + (size_t)l * 96 * DI_, xdbl, nullptr,
            M_, 96, DI_, DI_, DI_, 96);
        // dt_proj (fp32): dtb = softplus(xdbl[:, :64] @ dtp_w^T + dtp_b)
        gemm_kernel<2, true><<<dim3(DI_ / 64, M_ / 64), blk, 0, stream>>>(
            xdbl, dtp_w + (size_t)l * DI_ * DR_, dtb, dtp_b + (size_t)l * DI_,
            M_, DI_, DR_, 96, DR_, DI_);
        // chunked scan
        scan_chunk1_kernel<<<dim3(NC * B_ * DI_ * DS_ / 256), blk, 0, stream>>>(
            dtb, xdbl, xi, A_log + (size_t)l * DI_ * DS_, Ap, Hp);
        scan_chunk2_kernel<<<dim3(B_ * DI_ * DS_ / 256), blk, 0, stream>>>(Ap, Hp);
        scan_chunk3_kernel<<<dim3(NC * B_ * DI_ * DS_ / 256), blk, 0, stream>>>(
            dtb, xdbl, xi, xz, A_log + (size_t)l * DI_ * DS_,
            D_param + (size_t)l * DI_, Hp, yb_bf);
        // convert out_proj weights -> bf16 (reuses wbuf; in_proj GEMM done)
        cvt_bf16_kernel<<<dim3(D_ * DI_ / 4 / 256), blk, 0, stream>>>(
            op_w + (size_t)l * D_ * DI_, wbuf, D_ * DI_ / 4);
        // out_proj + residual (MFMA): h += yb @ op_w^T  [1152, 1024, K=2048]
        gemm_mfma_kernel<3><<<dim3(D_ / 128, M_ / 128), blk, 0, stream>>>(
            yb_bf, wbuf, h, M_, D_, DI_);
    }

    final_rmsnorm_kernel<<<dim3(B_ * S_), blk, 0, stream>>>(h, fnw, out);
}

// Round 4
// 1225.016 us; speedup vs baseline: 3.0594x; 1.4699x over previous
//
#include <hip/hip_runtime.h>
#include <math.h>

#define B_ 2
#define S_ 512
#define P_ 64
#define T_ 576          // P_+S_
#define D_ 1024
#define L_ 4
#define DI_ 2048
#define DS_ 16
#define DC_ 4
#define DR_ 64
#define PCD_ 768
#define M_ (B_*T_)      // 1152
#define CCH 64          // scan chunk length
#define NC (T_/CCH)     // 9 chunks
#define XKS 16          // x_proj K-splits (KC = 2048/16 = 128)

typedef __attribute__((ext_vector_type(8))) short bf16x8;
typedef __attribute__((ext_vector_type(4))) float f32x4;

__device__ __forceinline__ float silu_f(float v) { return v / (1.f + __expf(-v)); }
__device__ __forceinline__ float softplus_f(float v) {
    return fmaxf(v, 0.f) + log1pf(__expf(-fabsf(v)));
}
__device__ __forceinline__ unsigned short bf16_rne(float x) {
    unsigned int b = __float_as_uint(x);
    b += 0x7fffu + ((b >> 16) & 1u);
    return (unsigned short)(b >> 16);
}

typedef const void __attribute__((address_space(1)))* gas_t;
typedef void __attribute__((address_space(3)))* las_t;
__device__ __forceinline__ void async16(const void* g, void* l) {
    // wave-uniform LDS base; HW scatters lane i -> base + i*16 bytes
    __builtin_amdgcn_global_load_lds((gas_t)g, (las_t)l, 16, 0, 0);
}

// ---------------------------------------------------------------------------
// bf16 MFMA GEMM (m97 structure): C[m,n] (+)= sum_k A[m,k]*W[n,k], fp32 out.
// BM=BN=128, BK=32, 256 threads = 4 waves (2x2), each wave 64x64 via 4x4
// mfma_f32_16x16x32_bf16. K-split via blockIdx.z * Kchunk.
// EPI: 0 = store, 2 = softplus(v + bias[n]), 4 = atomicAdd into C.
// ---------------------------------------------------------------------------
template<int EPI>
__global__ __launch_bounds__(256) void gemm_mfma_kernel(
    const unsigned short* __restrict__ A, const unsigned short* __restrict__ W,
    float* __restrict__ C, const float* __restrict__ bias,
    int M, int N, int K, int Kchunk)
{
    __shared__ unsigned short As[128 * 32];
    __shared__ unsigned short Bs[128 * 32];
    const int tid = threadIdx.x;
    const int wave = tid >> 6;
    const int lane = tid & 63;
    const int m0 = blockIdx.y * 128, n0 = blockIdx.x * 128;
    const int kbase = blockIdx.z * Kchunk;
    const int wm = (wave >> 1) * 64, wn = (wave & 1) * 64;

    const int srow = (wave << 5) + (lane >> 2);
    const int selem = (lane & 3) * 8;
    const unsigned short* gA = A + (size_t)(m0 + srow) * K + kbase + selem;
    const unsigned short* gB = W + (size_t)(n0 + srow) * K + kbase + selem;
    unsigned short* lA = As + (wave << 5) * 32;
    unsigned short* lB = Bs + (wave << 5) * 32;

    f32x4 acc[4][4];
    #pragma unroll
    for (int i = 0; i < 4; ++i)
        #pragma unroll
        for (int j = 0; j < 4; ++j)
            acc[i][j] = (f32x4){0.f, 0.f, 0.f, 0.f};

    const int fr = lane & 15;
    const int fq = lane >> 4;
    const int aoff = (wm + fr) * 32 + fq * 8;
    const int boff = (wn + fr) * 32 + fq * 8;

    for (int k0 = 0; k0 < Kchunk; k0 += 32) {
        async16(gA, lA);
        async16(gA + (size_t)16 * K, lA + 16 * 32);
        async16(gB, lB);
        async16(gB + (size_t)16 * K, lB + 16 * 32);
        gA += 32; gB += 32;
        __syncthreads();
        bf16x8 af[4], bf[4];
        #pragma unroll
        for (int i = 0; i < 4; ++i) af[i] = *(const bf16x8*)&As[aoff + i * 512];
        #pragma unroll
        for (int j = 0; j < 4; ++j) bf[j] = *(const bf16x8*)&Bs[boff + j * 512];
        #pragma unroll
        for (int i = 0; i < 4; ++i)
            #pragma unroll
            for (int j = 0; j < 4; ++j)
                acc[i][j] = __builtin_amdgcn_mfma_f32_16x16x32_bf16(
                    af[i], bf[j], acc[i][j], 0, 0, 0);
        __syncthreads();
    }

    // C/D layout (m89-verified): col = lane&15, row = (lane>>4)*4 + reg
    #pragma unroll
    for (int i = 0; i < 4; ++i) {
        const int m = m0 + wm + i * 16 + fq * 4;
        #pragma unroll
        for (int j = 0; j < 4; ++j) {
            const int n = n0 + wn + j * 16 + fr;
            float* p = C + (size_t)m * N + n;
            #pragma unroll
            for (int r = 0; r < 4; ++r) {
                float v = acc[i][j][r];
                if (EPI == 2) v = softplus_f(v + bias[n]);
                if (EPI == 4) atomicAdd(p + (size_t)r * N, v);
                else          p[(size_t)r * N] = v;
            }
        }
    }
}

// ---------------------------------------------------------------------------
// x_proj split-K MFMA: P[ks][m][96] = xi_bf[m, ks*128:(ks+1)*128] @ W[96,...]^T
// BM=128, BN=96 (wave tile 64x48), KC=128. grid (XKS, M/128).
// ---------------------------------------------------------------------------
__global__ __launch_bounds__(256) void xproj_mfma_kernel(
    const unsigned short* __restrict__ A,   // [M, 2048] bf16
    const unsigned short* __restrict__ W,   // [96, 2048] bf16
    float* __restrict__ P)                  // [XKS, M, 96]
{
    __shared__ unsigned short As[128 * 32];
    __shared__ unsigned short Bs[96 * 32];
    const int tid = threadIdx.x;
    const int wave = tid >> 6;
    const int lane = tid & 63;
    const int m0 = blockIdx.y * 128;
    const int kbase = blockIdx.x * (DI_ / XKS);   // 128
    const int wm = (wave >> 1) * 64, wn = (wave & 1) * 48;

    const int srow = (wave << 5) + (lane >> 2);
    const int selem = (lane & 3) * 8;
    const unsigned short* gA = A + (size_t)(m0 + srow) * DI_ + kbase + selem;
    const unsigned short* gB = W + (size_t)srow * DI_ + kbase + selem;
    unsigned short* lA = As + (wave << 5) * 32;
    unsigned short* lB = Bs + (wave << 5) * 32;

    f32x4 acc[4][3];
    #pragma unroll
    for (int i = 0; i < 4; ++i)
        #pragma unroll
        for (int j = 0; j < 3; ++j)
            acc[i][j] = (f32x4){0.f, 0.f, 0.f, 0.f};

    const int fr = lane & 15;
    const int fq = lane >> 4;
    const int aoff = (wm + fr) * 32 + fq * 8;
    const int boff = (wn + fr) * 32 + fq * 8;

    #pragma unroll
    for (int kk = 0; kk < 4; ++kk) {        // 4 x BK=32 = KC 128
        async16(gA, lA);
        async16(gA + (size_t)16 * DI_, lA + 16 * 32);
        if (wave < 3) {                     // B has 96 rows: waves 0..2
            async16(gB, lB);
            async16(gB + (size_t)16 * DI_, lB + 16 * 32);
        }
        gA += 32; gB += 32;
        __syncthreads();
        bf16x8 af[4], bf[3];
        #pragma unroll
        for (int i = 0; i < 4; ++i) af[i] = *(const bf16x8*)&As[aoff + i * 512];
        #pragma unroll
        for (int j = 0; j < 3; ++j) bf[j] = *(const bf16x8*)&Bs[boff + j * 512];
        #pragma unroll
        for (int i = 0; i < 4; ++i)
            #pragma unroll
            for (int j = 0; j < 3; ++j)
                acc[i][j] = __builtin_amdgcn_mfma_f32_16x16x32_bf16(
                    af[i], bf[j], acc[i][j], 0, 0, 0);
        __syncthreads();
    }

    float* Pb = P + ((size_t)blockIdx.x * M_ + m0) * 96;
    #pragma unroll
    for (int i = 0; i < 4; ++i) {
        const int m = wm + i * 16 + fq * 4;
        #pragma unroll
        for (int j = 0; j < 3; ++j) {
            const int n = wn + j * 16 + fr;
            #pragma unroll
            for (int r = 0; r < 4; ++r)
                Pb[(size_t)(m + r) * 96 + n] = acc[i][j][r];
        }
    }
}

// xdbl[m][n] = sum_ks P[ks][m][n]; also dtr_bf[m*64+n] = bf16(xdbl) for n<64
__global__ __launch_bounds__(256) void xproj_reduce_kernel(
    const float* __restrict__ P, float* __restrict__ xdbl,
    unsigned short* __restrict__ dtr_bf)
{
    const int i = blockIdx.x * 256 + threadIdx.x;   // over M_*96
    if (i >= M_ * 96) return;
    float s = 0.f;
    #pragma unroll
    for (int ks = 0; ks < XKS; ++ks) s += P[(size_t)ks * (M_ * 96) + i];
    xdbl[i] = s;
    const int m = i / 96;
    const int n = i - m * 96;
    if (n < DR_) dtr_bf[(size_t)m * DR_ + n] = bf16_rne(s);
}

// fp32 -> bf16 (RNE), vectorized x4
__global__ __launch_bounds__(256) void cvt_bf16_kernel(
    const float* __restrict__ in, unsigned short* __restrict__ out, int n4)
{
    const int i = blockIdx.x * 256 + threadIdx.x;
    if (i >= n4) return;
    const float4 v = ((const float4*)in)[i];
    ushort4 o;
    o.x = bf16_rne(v.x); o.y = bf16_rne(v.y);
    o.z = bf16_rne(v.z); o.w = bf16_rne(v.w);
    ((ushort4*)out)[i] = o;
}

// ---------------------------------------------------------------------------
// Generic tiled fp32 GEMM (prepend path only).
// ---------------------------------------------------------------------------
template<int EPI, bool NT>
__global__ __launch_bounds__(256) void gemm_kernel(
    const float* __restrict__ A, const float* __restrict__ W,
    float* __restrict__ C, const float* __restrict__ bias,
    int M, int N, int K, int lda, int ldw, int ldc)
{
    __shared__ __align__(16) float As[16][68];
    __shared__ __align__(16) float Ws[16][68];
    const int m0 = blockIdx.y * 64;
    const int n0 = blockIdx.x * 64;
    const int tid = threadIdx.x;
    const int ty = tid >> 4;
    const int tx = tid & 15;
    float acc[4][4] = {};

    const int lr = tid >> 2;
    const int lk = (tid & 3) * 4;
    const int kk = tid >> 4;
    const int nq = (tid & 15) * 4;

    for (int k0 = 0; k0 < K; k0 += 16) {
        {
            const float4 v = *(const float4*)(A + (size_t)(m0 + lr) * lda + k0 + lk);
            As[lk + 0][lr] = v.x; As[lk + 1][lr] = v.y;
            As[lk + 2][lr] = v.z; As[lk + 3][lr] = v.w;
        }
        if (NT) {
            const int n = n0 + lr;
            float4 v = make_float4(0.f, 0.f, 0.f, 0.f);
            if (n < N) v = *(const float4*)(W + (size_t)n * ldw + k0 + lk);
            Ws[lk + 0][lr] = v.x; Ws[lk + 1][lr] = v.y;
            Ws[lk + 2][lr] = v.z; Ws[lk + 3][lr] = v.w;
        } else {
            const int n = n0 + nq;
            float4 v = make_float4(0.f, 0.f, 0.f, 0.f);
            if (n < N) v = *(const float4*)(W + (size_t)(k0 + kk) * ldw + n);
            Ws[kk][nq + 0] = v.x; Ws[kk][nq + 1] = v.y;
            Ws[kk][nq + 2] = v.z; Ws[kk][nq + 3] = v.w;
        }
        __syncthreads();
        #pragma unroll
        for (int k = 0; k < 16; ++k) {
            const float4 a = *(const float4*)&As[k][ty * 4];
            const float4 b = *(const float4*)&Ws[k][tx * 4];
            acc[0][0] = fmaf(a.x, b.x, acc[0][0]);
            acc[0][1] = fmaf(a.x, b.y, acc[0][1]);
            acc[0][2] = fmaf(a.x, b.z, acc[0][2]);
            acc[0][3] = fmaf(a.x, b.w, acc[0][3]);
            acc[1][0] = fmaf(a.y, b.x, acc[1][0]);
            acc[1][1] = fmaf(a.y, b.y, acc[1][1]);
            acc[1][2] = fmaf(a.y, b.z, acc[1][2]);
            acc[1][3] = fmaf(a.y, b.w, acc[1][3]);
            acc[2][0] = fmaf(a.z, b.x, acc[2][0]);
            acc[2][1] = fmaf(a.z, b.y, acc[2][1]);
            acc[2][2] = fmaf(a.z, b.z, acc[2][2]);
            acc[2][3] = fmaf(a.z, b.w, acc[2][3]);
            acc[3][0] = fmaf(a.w, b.x, acc[3][0]);
            acc[3][1] = fmaf(a.w, b.y, acc[3][1]);
            acc[3][2] = fmaf(a.w, b.z, acc[3][2]);
            acc[3][3] = fmaf(a.w, b.w, acc[3][3]);
        }
        __syncthreads();
    }
    #pragma unroll
    for (int i = 0; i < 4; ++i) {
        const int m = m0 + ty * 4 + i;
        #pragma unroll
        for (int j = 0; j < 4; ++j) {
            const int n = n0 + tx * 4 + j;
            if (n < N) {
                float v = acc[i][j];
                if (EPI == 1) v = silu_f(v);
                C[(size_t)m * ldc + n] = v;
            }
        }
    }
}

// h[b*T+t, :] = (t < P) ? p[b*P+t, :] : x[b*S + (t-P), :]
__global__ __launch_bounds__(256) void assemble_h_kernel(
    const float* __restrict__ p, const float* __restrict__ x, float* __restrict__ h)
{
    const int idx = blockIdx.x * 256 + threadIdx.x;
    const int r = idx >> 8;
    const int c = idx & 255;
    const int b = r / T_;
    const int t = r - b * T_;
    float4 v;
    if (t < P_) v = ((const float4*)p)[(size_t)(b * P_ + t) * 256 + c];
    else        v = ((const float4*)x)[(size_t)(b * S_ + (t - P_)) * 256 + c];
    ((float4*)h)[idx] = v;
}

// rmsnorm -> bf16 output (feeds in_proj MFMA). one block per row.
__global__ __launch_bounds__(256) void rmsnorm_bf16_kernel(
    const float* __restrict__ x, const float* __restrict__ w,
    unsigned short* __restrict__ outb)
{
    const int r = blockIdx.x;
    const float4 v = ((const float4*)(x + (size_t)r * D_))[threadIdx.x];
    float ss = v.x * v.x + v.y * v.y + v.z * v.z + v.w * v.w;
    ss += __shfl_xor(ss, 32, 64);
    ss += __shfl_xor(ss, 16, 64);
    ss += __shfl_xor(ss, 8, 64);
    ss += __shfl_xor(ss, 4, 64);
    ss += __shfl_xor(ss, 2, 64);
    ss += __shfl_xor(ss, 1, 64);
    __shared__ float red[4];
    if ((threadIdx.x & 63) == 0) red[threadIdx.x >> 6] = ss;
    __syncthreads();
    const float tot = red[0] + red[1] + red[2] + red[3];
    const float scale = rsqrtf(tot * (1.f / D_) + 1e-5f);
    const float4 wv = ((const float4*)w)[threadIdx.x];
    ushort4 o;
    o.x = bf16_rne(v.x * scale * wv.x);
    o.y = bf16_rne(v.y * scale * wv.y);
    o.z = bf16_rne(v.z * scale * wv.z);
    o.w = bf16_rne(v.w * scale * wv.w);
    ((ushort4*)(outb + (size_t)r * D_))[threadIdx.x] = o;
}

// final rmsnorm (fp32 out): rows over B*S; reads h[b*T+P+s]
__global__ __launch_bounds__(256) void final_rmsnorm_kernel(
    const float* __restrict__ h, const float* __restrict__ w, float* __restrict__ out)
{
    const int r = blockIdx.x;
    const int b = r / S_;
    const int s = r - b * S_;
    const int hr = b * T_ + P_ + s;
    const float4 v = ((const float4*)(h + (size_t)hr * D_))[threadIdx.x];
    float ss = v.x * v.x + v.y * v.y + v.z * v.z + v.w * v.w;
    ss += __shfl_xor(ss, 32, 64);
    ss += __shfl_xor(ss, 16, 64);
    ss += __shfl_xor(ss, 8, 64);
    ss += __shfl_xor(ss, 4, 64);
    ss += __shfl_xor(ss, 2, 64);
    ss += __shfl_xor(ss, 1, 64);
    __shared__ float red[4];
    if ((threadIdx.x & 63) == 0) red[threadIdx.x >> 6] = ss;
    __syncthreads();
    const float tot = red[0] + red[1] + red[2] + red[3];
    const float scale = rsqrtf(tot * (1.f / D_) + 1e-5f);
    const float4 wv = ((const float4*)w)[threadIdx.x];
    float4 o;
    o.x = v.x * scale * wv.x; o.y = v.y * scale * wv.y;
    o.z = v.z * scale * wv.z; o.w = v.w * scale * wv.w;
    ((float4*)(out + (size_t)r * D_))[threadIdx.x] = o;
}

// causal depthwise conv (DC=4) + bias + silu; writes fp32 (scan) + bf16 (x_proj)
__global__ __launch_bounds__(256) void conv_silu_kernel(
    const float* __restrict__ xz, const float* __restrict__ cw,
    const float* __restrict__ cb, float* __restrict__ xi,
    unsigned short* __restrict__ xib)
{
    const int idx = blockIdx.x * 256 + threadIdx.x;
    const int e = idx & (DI_ - 1);
    const int r = idx >> 11;
    const int b = r / T_;
    const int t = r - b * T_;
    const float4 w = *(const float4*)(cw + (size_t)e * 4);
    const float x3 = xz[(size_t)r * (2 * DI_) + e];
    const float x2 = (t >= 1) ? xz[(size_t)(r - 1) * (2 * DI_) + e] : 0.f;
    const float x1 = (t >= 2) ? xz[(size_t)(r - 2) * (2 * DI_) + e] : 0.f;
    const float x0 = (t >= 3) ? xz[(size_t)(r - 3) * (2 * DI_) + e] : 0.f;
    float v = cb[e];
    v = fmaf(w.x, x0, v);
    v = fmaf(w.y, x1, v);
    v = fmaf(w.z, x2, v);
    v = fmaf(w.w, x3, v);
    const float o = silu_f(v);
    xi[idx] = o;
    xib[idx] = bf16_rne(o);
}

// ---------------------------------------------------------------------------
// Chunked selective scan (associative rearrangement; see R2 notes).
// ---------------------------------------------------------------------------
__global__ __launch_bounds__(256) void scan_chunk1_kernel(
    const float* __restrict__ dt, const float* __restrict__ xdbl,
    const float* __restrict__ xi, const float* __restrict__ A_log,
    float* __restrict__ Ap, float* __restrict__ Hp)
{
    const int g = blockIdx.x * 256 + threadIdx.x;
    const int s = g & (DS_ - 1);
    const int e = (g >> 4) & (DI_ - 1);
    const int b = (g >> 15) & (B_ - 1);
    const int c = g >> 16;
    const float Aval = -__expf(A_log[(size_t)e * DS_ + s]);
    float ap = 1.f, hp = 0.f;
    const int r0 = b * T_ + c * CCH;
    for (int t = 0; t < CCH; ++t) {
        const int r = r0 + t;
        const float dtv = dt[(size_t)r * DI_ + e];
        const float u   = xi[(size_t)r * DI_ + e];
        const float bv  = xdbl[(size_t)r * 96 + DR_ + s];
        const float da  = __expf(dtv * Aval);
        ap *= da;
        hp = fmaf(da, hp, dtv * bv * u);
    }
    const size_t o = (((size_t)c * B_ + b) * DI_ + e) * DS_ + s;
    Ap[o] = ap; Hp[o] = hp;
}

__global__ __launch_bounds__(256) void scan_chunk2_kernel(
    float* __restrict__ Ap, float* __restrict__ Hp)
{
    const int g = blockIdx.x * 256 + threadIdx.x;
    float h = 0.f;
    #pragma unroll
    for (int c = 0; c < NC; ++c) {
        const size_t o = (size_t)c * (B_ * DI_ * DS_) + g;
        const float ap = Ap[o];
        const float hp = Hp[o];
        Hp[o] = h;
        h = fmaf(ap, h, hp);
    }
}

__global__ __launch_bounds__(256) void scan_chunk3_kernel(
    const float* __restrict__ dt, const float* __restrict__ xdbl,
    const float* __restrict__ xi, const float* __restrict__ xz,
    const float* __restrict__ A_log, const float* __restrict__ Dp,
    const float* __restrict__ Hin, unsigned short* __restrict__ y)
{
    const int g = blockIdx.x * 256 + threadIdx.x;
    const int s = g & (DS_ - 1);
    const int e = (g >> 4) & (DI_ - 1);
    const int b = (g >> 15) & (B_ - 1);
    const int c = g >> 16;
    const float Aval = -__expf(A_log[(size_t)e * DS_ + s]);
    const float dpe = Dp[e];
    float h = Hin[(((size_t)c * B_ + b) * DI_ + e) * DS_ + s];
    const int r0 = b * T_ + c * CCH;
    for (int t = 0; t < CCH; ++t) {
        const int r = r0 + t;
        const float dtv = dt[(size_t)r * DI_ + e];
        const float u   = xi[(size_t)r * DI_ + e];
        const float bv  = xdbl[(size_t)r * 96 + DR_ + s];
        const float cv  = xdbl[(size_t)r * 96 + DR_ + DS_ + s];
        const float da  = __expf(dtv * Aval);
        h = fmaf(da, h, dtv * bv * u);
        float contrib = h * cv;
        contrib += __shfl_xor(contrib, 1, 64);
        contrib += __shfl_xor(contrib, 2, 64);
        contrib += __shfl_xor(contrib, 4, 64);
        contrib += __shfl_xor(contrib, 8, 64);
        if (s == 0) {
            const float z = xz[(size_t)r * (2 * DI_) + DI_ + e];
            y[(size_t)r * DI_ + e] = bf16_rne((contrib + u * dpe) * silu_f(z));
        }
    }
}

extern "C" void kernel_launch(void* const* d_in, const int* in_sizes, int n_in,
                              void* d_out, int out_size, void* d_ws, size_t ws_size,
                              hipStream_t stream)
{
    const float* x       = (const float*)d_in[0];
    const float* pc      = (const float*)d_in[1];
    const float* pre_w1  = (const float*)d_in[2];
    const float* pre_w2  = (const float*)d_in[3];
    const float* norm_w  = (const float*)d_in[4];
    const float* ip_w    = (const float*)d_in[5];
    const float* conv_w  = (const float*)d_in[6];
    const float* conv_b  = (const float*)d_in[7];
    const float* xp_w    = (const float*)d_in[8];
    const float* dtp_w   = (const float*)d_in[9];
    const float* dtp_b   = (const float*)d_in[10];
    const float* A_log   = (const float*)d_in[11];
    const float* D_param = (const float*)d_in[12];
    const float* op_w    = (const float*)d_in[13];
    const float* fnw     = (const float*)d_in[14];
    float* out = (float*)d_out;

    float* ws = (float*)d_ws;
    float* h    = ws;  ws += (size_t)M_ * D_;            // fp32 residual
    float* xz   = ws;  ws += (size_t)M_ * 2 * DI_;       // in_proj out
    float* xi   = ws;  ws += (size_t)M_ * DI_;           // conv out fp32
    float* xdbl = ws;  ws += (size_t)M_ * 96;
    float* dtb  = ws;  ws += (size_t)M_ * DI_;
    float* Ap   = ws;  ws += (size_t)NC * B_ * DI_ * DS_;
    float* Hp   = ws;  ws += (size_t)NC * B_ * DI_ * DS_;
    float* Pbuf = ws;  ws += (size_t)XKS * M_ * 96;      // x_proj partials
    unsigned short* xn_bf  = (unsigned short*)ws;  ws += (size_t)M_ * D_ / 2;
    unsigned short* yb_bf  = (unsigned short*)ws;  ws += (size_t)M_ * DI_ / 2;
    unsigned short* xi_bf  = (unsigned short*)ws;  ws += (size_t)M_ * DI_ / 2;
    unsigned short* dtr_bf = (unsigned short*)ws;  ws += (size_t)M_ * DR_ / 2;
    unsigned short* wbuf   = (unsigned short*)ws;  ws += (size_t)2 * DI_ * D_ / 2;
    unsigned short* xpw_bf = (unsigned short*)ws;  ws += (size_t)96 * DI_ / 2;
    unsigned short* dtpw_bf= (unsigned short*)ws;  ws += (size_t)DI_ * DR_ / 2;
    // prepend temporaries alias xz (consumed before layer 0 writes xz)
    float* tmp1 = xz;
    float* tmp2 = xz + (size_t)B_ * P_ * D_;

    const dim3 blk(256);

    // prepend embed: tmp1 = silu(pc @ pre_w1); tmp2 = tmp1 @ pre_w2
    gemm_kernel<1, false><<<dim3(D_ / 64, (B_ * P_) / 64), blk, 0, stream>>>(
        pc, pre_w1, tmp1, nullptr, B_ * P_, D_, PCD_, PCD_, D_, D_);
    gemm_kernel<0, false><<<dim3(D_ / 64, (B_ * P_) / 64), blk, 0, stream>>>(
        tmp1, pre_w2, tmp2, nullptr, B_ * P_, D_, D_, D_, D_, D_);
    assemble_h_kernel<<<dim3(M_ * D_ / 4 / 256), blk, 0, stream>>>(tmp2, x, h);

    for (int l = 0; l < L_; ++l) {
        rmsnorm_bf16_kernel<<<dim3(M_), blk, 0, stream>>>(
            h, norm_w + (size_t)l * D_, xn_bf);
        // weight conversions for this layer
        cvt_bf16_kernel<<<dim3(2 * DI_ * D_ / 4 / 256), blk, 0, stream>>>(
            ip_w + (size_t)l * 2 * DI_ * D_, wbuf, 2 * DI_ * D_ / 4);
        cvt_bf16_kernel<<<dim3(96 * DI_ / 4 / 256), blk, 0, stream>>>(
            xp_w + (size_t)l * 96 * DI_, xpw_bf, 96 * DI_ / 4);
        cvt_bf16_kernel<<<dim3(DI_ * DR_ / 4 / 256), blk, 0, stream>>>(
            dtp_w + (size_t)l * DI_ * DR_, dtpw_bf, DI_ * DR_ / 4);
        // in_proj (MFMA): xz = xn @ ip_w^T   [1152, 4096, K=1024]
        gemm_mfma_kernel<0><<<dim3(2 * DI_ / 128, M_ / 128, 1), blk, 0, stream>>>(
            xn_bf, wbuf, xz, nullptr, M_, 2 * DI_, D_, D_);
        conv_silu_kernel<<<dim3(M_ * DI_ / 256), blk, 0, stream>>>(
            xz, conv_w + (size_t)l * DI_ * DC_, conv_b + (size_t)l * DI_,
            xi, xi_bf);
        // x_proj (split-K MFMA): Pbuf partials then reduce -> xdbl + dtr_bf
        xproj_mfma_kernel<<<dim3(XKS, M_ / 128), blk, 0, stream>>>(
            xi_bf, xpw_bf, Pbuf);
        xproj_reduce_kernel<<<dim3((M_ * 96 + 255) / 256), blk, 0, stream>>>(
            Pbuf, xdbl, dtr_bf);
        // dt_proj (MFMA): dtb = softplus(dtr @ dtp_w^T + dtp_b) [1152,2048,K=64]
        gemm_mfma_kernel<2><<<dim3(DI_ / 128, M_ / 128, 1), blk, 0, stream>>>(
            dtr_bf, dtpw_bf, dtb, dtp_b + (size_t)l * DI_, M_, DI_, DR_, DR_);
        // chunked scan
        scan_chunk1_kernel<<<dim3(NC * B_ * DI_ * DS_ / 256), blk, 0, stream>>>(
            dtb, xdbl, xi, A_log + (size_t)l * DI_ * DS_, Ap, Hp);
        scan_chunk2_kernel<<<dim3(B_ * DI_ * DS_ / 256), blk, 0, stream>>>(Ap, Hp);
        scan_chunk3_kernel<<<dim3(NC * B_ * DI_ * DS_ / 256), blk, 0, stream>>>(
            dtb, xdbl, xi, xz, A_log + (size_t)l * DI_ * DS_,
            D_param + (size_t)l * DI_, Hp, yb_bf);
        // out_proj weights -> bf16 (reuses wbuf; in_proj GEMM done)
        cvt_bf16_kernel<<<dim3(D_ * DI_ / 4 / 256), blk, 0, stream>>>(
            op_w + (size_t)l * D_ * DI_, wbuf, D_ * DI_ / 4);
        // out_proj + residual (split-K=2, atomicAdd): h += yb @ op_w^T
        gemm_mfma_kernel<4><<<dim3(D_ / 128, M_ / 128, 2), blk, 0, stream>>>(
            yb_bf, wbuf, h, nullptr, M_, D_, DI_, DI_ / 2);
    }

    final_rmsnorm_kernel<<<dim3(B_ * S_), blk, 0, stream>>>(h, fnw, out);
}

// Round 5
// 1149.357 us; speedup vs baseline: 3.2608x; 1.0658x over previous
//
#include <hip/hip_runtime.h>
#include <math.h>

#define B_ 2
#define S_ 512
#define P_ 64
#define T_ 576          // P_+S_
#define D_ 1024
#define L_ 4
#define DI_ 2048
#define DS_ 16
#define DC_ 4
#define DR_ 64
#define PCD_ 768
#define M_ (B_*T_)      // 1152
#define CCH 64          // scan chunk length
#define NC (T_/CCH)     // 9 chunks
#define XKS 16          // x_proj K-splits (KC = 2048/16 = 128)

typedef __attribute__((ext_vector_type(8))) short bf16x8;
typedef __attribute__((ext_vector_type(4))) float f32x4;

__device__ __forceinline__ float silu_f(float v) { return v / (1.f + __expf(-v)); }
__device__ __forceinline__ float softplus_f(float v) {
    return fmaxf(v, 0.f) + log1pf(__expf(-fabsf(v)));
}
__device__ __forceinline__ unsigned short bf16_rne(float x) {
    unsigned int b = __float_as_uint(x);
    b += 0x7fffu + ((b >> 16) & 1u);
    return (unsigned short)(b >> 16);
}

// sum over each 16-lane row via DPP row_shr (full-rate VALU, no LDS pipe).
// Result lands in lane 15 of each row of 16.
__device__ __forceinline__ float row_reduce16(float x) {
    x += __int_as_float(__builtin_amdgcn_update_dpp(
        0, __float_as_int(x), 0x111, 0xf, 0xf, true)); // row_shr:1
    x += __int_as_float(__builtin_amdgcn_update_dpp(
        0, __float_as_int(x), 0x112, 0xf, 0xf, true)); // row_shr:2
    x += __int_as_float(__builtin_amdgcn_update_dpp(
        0, __float_as_int(x), 0x114, 0xf, 0xf, true)); // row_shr:4
    x += __int_as_float(__builtin_amdgcn_update_dpp(
        0, __float_as_int(x), 0x118, 0xf, 0xf, true)); // row_shr:8
    return x;
}

typedef const void __attribute__((address_space(1)))* gas_t;
typedef void __attribute__((address_space(3)))* las_t;
__device__ __forceinline__ void async16(const void* g, void* l) {
    __builtin_amdgcn_global_load_lds((gas_t)g, (las_t)l, 16, 0, 0);
}

// ---------------------------------------------------------------------------
// bf16 MFMA GEMM (m97 structure): C[m,n] (+)= sum_k A[m,k]*W[n,k], fp32 out.
// BM=BN=128, BK=32, 256 threads = 4 waves (2x2), each wave 64x64 via 4x4
// mfma_f32_16x16x32_bf16. K-split via blockIdx.z * Kchunk.
// EPI: 0 = store, 4 = atomicAdd into C, 5 = softplus(v+bias[n]) stored
//      TRANSPOSED to C[n*M + m] (float4 per lane, m-contiguous).
// ---------------------------------------------------------------------------
template<int EPI>
__global__ __launch_bounds__(256) void gemm_mfma_kernel(
    const unsigned short* __restrict__ A, const unsigned short* __restrict__ W,
    float* __restrict__ C, const float* __restrict__ bias,
    int M, int N, int K, int Kchunk)
{
    __shared__ unsigned short As[128 * 32];
    __shared__ unsigned short Bs[128 * 32];
    const int tid = threadIdx.x;
    const int wave = tid >> 6;
    const int lane = tid & 63;
    const int m0 = blockIdx.y * 128, n0 = blockIdx.x * 128;
    const int kbase = blockIdx.z * Kchunk;
    const int wm = (wave >> 1) * 64, wn = (wave & 1) * 64;

    const int srow = (wave << 5) + (lane >> 2);
    const int selem = (lane & 3) * 8;
    const unsigned short* gA = A + (size_t)(m0 + srow) * K + kbase + selem;
    const unsigned short* gB = W + (size_t)(n0 + srow) * K + kbase + selem;
    unsigned short* lA = As + (wave << 5) * 32;
    unsigned short* lB = Bs + (wave << 5) * 32;

    f32x4 acc[4][4];
    #pragma unroll
    for (int i = 0; i < 4; ++i)
        #pragma unroll
        for (int j = 0; j < 4; ++j)
            acc[i][j] = (f32x4){0.f, 0.f, 0.f, 0.f};

    const int fr = lane & 15;
    const int fq = lane >> 4;
    const int aoff = (wm + fr) * 32 + fq * 8;
    const int boff = (wn + fr) * 32 + fq * 8;

    for (int k0 = 0; k0 < Kchunk; k0 += 32) {
        async16(gA, lA);
        async16(gA + (size_t)16 * K, lA + 16 * 32);
        async16(gB, lB);
        async16(gB + (size_t)16 * K, lB + 16 * 32);
        gA += 32; gB += 32;
        __syncthreads();
        bf16x8 af[4], bf[4];
        #pragma unroll
        for (int i = 0; i < 4; ++i) af[i] = *(const bf16x8*)&As[aoff + i * 512];
        #pragma unroll
        for (int j = 0; j < 4; ++j) bf[j] = *(const bf16x8*)&Bs[boff + j * 512];
        #pragma unroll
        for (int i = 0; i < 4; ++i)
            #pragma unroll
            for (int j = 0; j < 4; ++j)
                acc[i][j] = __builtin_amdgcn_mfma_f32_16x16x32_bf16(
                    af[i], bf[j], acc[i][j], 0, 0, 0);
        __syncthreads();
    }

    // C/D layout (m89-verified): col = lane&15, row = (lane>>4)*4 + reg
    #pragma unroll
    for (int i = 0; i < 4; ++i) {
        const int m = m0 + wm + i * 16 + fq * 4;
        #pragma unroll
        for (int j = 0; j < 4; ++j) {
            const int n = n0 + wn + j * 16 + fr;
            if (EPI == 5) {
                const float bb = bias[n];
                float4 o;
                o.x = softplus_f(acc[i][j][0] + bb);
                o.y = softplus_f(acc[i][j][1] + bb);
                o.z = softplus_f(acc[i][j][2] + bb);
                o.w = softplus_f(acc[i][j][3] + bb);
                *(float4*)(C + (size_t)n * M + m) = o;   // transposed, m%4==0
            } else {
                float* p = C + (size_t)m * N + n;
                #pragma unroll
                for (int r = 0; r < 4; ++r) {
                    const float v = acc[i][j][r];
                    if (EPI == 4) atomicAdd(p + (size_t)r * N, v);
                    else          p[(size_t)r * N] = v;
                }
            }
        }
    }
}

// ---------------------------------------------------------------------------
// x_proj split-K MFMA: P[ks][m][96] = xi_bf[m, ks*128:(ks+1)*128] @ W[96,...]^T
// ---------------------------------------------------------------------------
__global__ __launch_bounds__(256) void xproj_mfma_kernel(
    const unsigned short* __restrict__ A,   // [M, 2048] bf16
    const unsigned short* __restrict__ W,   // [96, 2048] bf16
    float* __restrict__ P)                  // [XKS, M, 96]
{
    __shared__ unsigned short As[128 * 32];
    __shared__ unsigned short Bs[96 * 32];
    const int tid = threadIdx.x;
    const int wave = tid >> 6;
    const int lane = tid & 63;
    const int m0 = blockIdx.y * 128;
    const int kbase = blockIdx.x * (DI_ / XKS);   // 128
    const int wm = (wave >> 1) * 64, wn = (wave & 1) * 48;

    const int srow = (wave << 5) + (lane >> 2);
    const int selem = (lane & 3) * 8;
    const unsigned short* gA = A + (size_t)(m0 + srow) * DI_ + kbase + selem;
    const unsigned short* gB = W + (size_t)srow * DI_ + kbase + selem;
    unsigned short* lA = As + (wave << 5) * 32;
    unsigned short* lB = Bs + (wave << 5) * 32;

    f32x4 acc[4][3];
    #pragma unroll
    for (int i = 0; i < 4; ++i)
        #pragma unroll
        for (int j = 0; j < 3; ++j)
            acc[i][j] = (f32x4){0.f, 0.f, 0.f, 0.f};

    const int fr = lane & 15;
    const int fq = lane >> 4;
    const int aoff = (wm + fr) * 32 + fq * 8;
    const int boff = (wn + fr) * 32 + fq * 8;

    #pragma unroll
    for (int kk = 0; kk < 4; ++kk) {
        async16(gA, lA);
        async16(gA + (size_t)16 * DI_, lA + 16 * 32);
        if (wave < 3) {
            async16(gB, lB);
            async16(gB + (size_t)16 * DI_, lB + 16 * 32);
        }
        gA += 32; gB += 32;
        __syncthreads();
        bf16x8 af[4], bf[3];
        #pragma unroll
        for (int i = 0; i < 4; ++i) af[i] = *(const bf16x8*)&As[aoff + i * 512];
        #pragma unroll
        for (int j = 0; j < 3; ++j) bf[j] = *(const bf16x8*)&Bs[boff + j * 512];
        #pragma unroll
        for (int i = 0; i < 4; ++i)
            #pragma unroll
            for (int j = 0; j < 3; ++j)
                acc[i][j] = __builtin_amdgcn_mfma_f32_16x16x32_bf16(
                    af[i], bf[j], acc[i][j], 0, 0, 0);
        __syncthreads();
    }

    float* Pb = P + ((size_t)blockIdx.x * M_ + m0) * 96;
    #pragma unroll
    for (int i = 0; i < 4; ++i) {
        const int m = wm + i * 16 + fq * 4;
        #pragma unroll
        for (int j = 0; j < 3; ++j) {
            const int n = wn + j * 16 + fr;
            #pragma unroll
            for (int r = 0; r < 4; ++r)
                Pb[(size_t)(m + r) * 96 + n] = acc[i][j][r];
        }
    }
}

// xdbl[m][n] = sum_ks P[ks][m][n]; also dtr_bf[m*64+n] = bf16(xdbl) for n<64
__global__ __launch_bounds__(256) void xproj_reduce_kernel(
    const float* __restrict__ P, float* __restrict__ xdbl,
    unsigned short* __restrict__ dtr_bf)
{
    const int i = blockIdx.x * 256 + threadIdx.x;
    if (i >= M_ * 96) return;
    float s = 0.f;
    #pragma unroll
    for (int ks = 0; ks < XKS; ++ks) s += P[(size_t)ks * (M_ * 96) + i];
    xdbl[i] = s;
    const int m = i / 96;
    const int n = i - m * 96;
    if (n < DR_) dtr_bf[(size_t)m * DR_ + n] = bf16_rne(s);
}

// fp32 -> bf16 (RNE), vectorized x4
__global__ __launch_bounds__(256) void cvt_bf16_kernel(
    const float* __restrict__ in, unsigned short* __restrict__ out, int n4)
{
    const int i = blockIdx.x * 256 + threadIdx.x;
    if (i >= n4) return;
    const float4 v = ((const float4*)in)[i];
    ushort4 o;
    o.x = bf16_rne(v.x); o.y = bf16_rne(v.y);
    o.z = bf16_rne(v.z); o.w = bf16_rne(v.w);
    ((ushort4*)out)[i] = o;
}

// ---------------------------------------------------------------------------
// Generic tiled fp32 GEMM (prepend path only).
// ---------------------------------------------------------------------------
template<int EPI, bool NT>
__global__ __launch_bounds__(256) void gemm_kernel(
    const float* __restrict__ A, const float* __restrict__ W,
    float* __restrict__ C, const float* __restrict__ bias,
    int M, int N, int K, int lda, int ldw, int ldc)
{
    __shared__ __align__(16) float As[16][68];
    __shared__ __align__(16) float Ws[16][68];
    const int m0 = blockIdx.y * 64;
    const int n0 = blockIdx.x * 64;
    const int tid = threadIdx.x;
    const int ty = tid >> 4;
    const int tx = tid & 15;
    float acc[4][4] = {};

    const int lr = tid >> 2;
    const int lk = (tid & 3) * 4;
    const int kk = tid >> 4;
    const int nq = (tid & 15) * 4;

    for (int k0 = 0; k0 < K; k0 += 16) {
        {
            const float4 v = *(const float4*)(A + (size_t)(m0 + lr) * lda + k0 + lk);
            As[lk + 0][lr] = v.x; As[lk + 1][lr] = v.y;
            As[lk + 2][lr] = v.z; As[lk + 3][lr] = v.w;
        }
        if (NT) {
            const int n = n0 + lr;
            float4 v = make_float4(0.f, 0.f, 0.f, 0.f);
            if (n < N) v = *(const float4*)(W + (size_t)n * ldw + k0 + lk);
            Ws[lk + 0][lr] = v.x; Ws[lk + 1][lr] = v.y;
            Ws[lk + 2][lr] = v.z; Ws[lk + 3][lr] = v.w;
        } else {
            const int n = n0 + nq;
            float4 v = make_float4(0.f, 0.f, 0.f, 0.f);
            if (n < N) v = *(const float4*)(W + (size_t)(k0 + kk) * ldw + n);
            Ws[kk][nq + 0] = v.x; Ws[kk][nq + 1] = v.y;
            Ws[kk][nq + 2] = v.z; Ws[kk][nq + 3] = v.w;
        }
        __syncthreads();
        #pragma unroll
        for (int k = 0; k < 16; ++k) {
            const float4 a = *(const float4*)&As[k][ty * 4];
            const float4 b = *(const float4*)&Ws[k][tx * 4];
            acc[0][0] = fmaf(a.x, b.x, acc[0][0]);
            acc[0][1] = fmaf(a.x, b.y, acc[0][1]);
            acc[0][2] = fmaf(a.x, b.z, acc[0][2]);
            acc[0][3] = fmaf(a.x, b.w, acc[0][3]);
            acc[1][0] = fmaf(a.y, b.x, acc[1][0]);
            acc[1][1] = fmaf(a.y, b.y, acc[1][1]);
            acc[1][2] = fmaf(a.y, b.z, acc[1][2]);
            acc[1][3] = fmaf(a.y, b.w, acc[1][3]);
            acc[2][0] = fmaf(a.z, b.x, acc[2][0]);
            acc[2][1] = fmaf(a.z, b.y, acc[2][1]);
            acc[2][2] = fmaf(a.z, b.z, acc[2][2]);
            acc[2][3] = fmaf(a.z, b.w, acc[2][3]);
            acc[3][0] = fmaf(a.w, b.x, acc[3][0]);
            acc[3][1] = fmaf(a.w, b.y, acc[3][1]);
            acc[3][2] = fmaf(a.w, b.z, acc[3][2]);
            acc[3][3] = fmaf(a.w, b.w, acc[3][3]);
        }
        __syncthreads();
    }
    #pragma unroll
    for (int i = 0; i < 4; ++i) {
        const int m = m0 + ty * 4 + i;
        #pragma unroll
        for (int j = 0; j < 4; ++j) {
            const int n = n0 + tx * 4 + j;
            if (n < N) {
                float v = acc[i][j];
                if (EPI == 1) v = silu_f(v);
                C[(size_t)m * ldc + n] = v;
            }
        }
    }
}

// h[b*T+t, :] = (t < P) ? p[b*P+t, :] : x[b*S + (t-P), :]
__global__ __launch_bounds__(256) void assemble_h_kernel(
    const float* __restrict__ p, const float* __restrict__ x, float* __restrict__ h)
{
    const int idx = blockIdx.x * 256 + threadIdx.x;
    const int r = idx >> 8;
    const int c = idx & 255;
    const int b = r / T_;
    const int t = r - b * T_;
    float4 v;
    if (t < P_) v = ((const float4*)p)[(size_t)(b * P_ + t) * 256 + c];
    else        v = ((const float4*)x)[(size_t)(b * S_ + (t - P_)) * 256 + c];
    ((float4*)h)[idx] = v;
}

// rmsnorm -> bf16 output (feeds in_proj MFMA). one block per row.
__global__ __launch_bounds__(256) void rmsnorm_bf16_kernel(
    const float* __restrict__ x, const float* __restrict__ w,
    unsigned short* __restrict__ outb)
{
    const int r = blockIdx.x;
    const float4 v = ((const float4*)(x + (size_t)r * D_))[threadIdx.x];
    float ss = v.x * v.x + v.y * v.y + v.z * v.z + v.w * v.w;
    ss += __shfl_xor(ss, 32, 64);
    ss += __shfl_xor(ss, 16, 64);
    ss += __shfl_xor(ss, 8, 64);
    ss += __shfl_xor(ss, 4, 64);
    ss += __shfl_xor(ss, 2, 64);
    ss += __shfl_xor(ss, 1, 64);
    __shared__ float red[4];
    if ((threadIdx.x & 63) == 0) red[threadIdx.x >> 6] = ss;
    __syncthreads();
    const float tot = red[0] + red[1] + red[2] + red[3];
    const float scale = rsqrtf(tot * (1.f / D_) + 1e-5f);
    const float4 wv = ((const float4*)w)[threadIdx.x];
    ushort4 o;
    o.x = bf16_rne(v.x * scale * wv.x);
    o.y = bf16_rne(v.y * scale * wv.y);
    o.z = bf16_rne(v.z * scale * wv.z);
    o.w = bf16_rne(v.w * scale * wv.w);
    ((ushort4*)(outb + (size_t)r * D_))[threadIdx.x] = o;
}

// final rmsnorm (fp32 out): rows over B*S; reads h[b*T+P+s]
__global__ __launch_bounds__(256) void final_rmsnorm_kernel(
    const float* __restrict__ h, const float* __restrict__ w, float* __restrict__ out)
{
    const int r = blockIdx.x;
    const int b = r / S_;
    const int s = r - b * S_;
    const int hr = b * T_ + P_ + s;
    const float4 v = ((const float4*)(h + (size_t)hr * D_))[threadIdx.x];
    float ss = v.x * v.x + v.y * v.y + v.z * v.z + v.w * v.w;
    ss += __shfl_xor(ss, 32, 64);
    ss += __shfl_xor(ss, 16, 64);
    ss += __shfl_xor(ss, 8, 64);
    ss += __shfl_xor(ss, 4, 64);
    ss += __shfl_xor(ss, 2, 64);
    ss += __shfl_xor(ss, 1, 64);
    __shared__ float red[4];
    if ((threadIdx.x & 63) == 0) red[threadIdx.x >> 6] = ss;
    __syncthreads();
    const float tot = red[0] + red[1] + red[2] + red[3];
    const float scale = rsqrtf(tot * (1.f / D_) + 1e-5f);
    const float4 wv = ((const float4*)w)[threadIdx.x];
    float4 o;
    o.x = v.x * scale * wv.x; o.y = v.y * scale * wv.y;
    o.z = v.z * scale * wv.z; o.w = v.w * scale * wv.w;
    ((float4*)(out + (size_t)r * D_))[threadIdx.x] = o;
}

// ---------------------------------------------------------------------------
// Fused causal depthwise conv (DC=4) + bias + silu + transpose.
// Reads xz x-half [r][e]; writes xi_bf [r][e] (x_proj operand) AND
// xi_t fp32 [e][r] (scan stream operand) via LDS tile transpose.
// Tile: 64 r x 64 e. Batch boundary is tile-aligned (576 % 64 == 0).
// ---------------------------------------------------------------------------
__global__ __launch_bounds__(256) void conv_transpose_kernel(
    const float* __restrict__ xz, const float* __restrict__ cw,
    const float* __restrict__ cb, unsigned short* __restrict__ xib,
    float* __restrict__ xit)
{
    __shared__ float xs[68][64];    // rows r0-3 .. r0+63 (67 used)
    __shared__ float tt[64][65];    // transpose staging, padded
    const int tid = threadIdx.x;
    const int tx = tid & 63;
    const int ty = tid >> 6;        // 0..3
    const int r0 = blockIdx.x * 64;
    const int e0 = blockIdx.y * 64;
    const int bt0 = (r0 / T_) * T_; // batch start row

    for (int j = ty; j < 67; j += 4) {
        const int r = r0 + j - 3;
        xs[j][tx] = (r >= bt0) ? xz[(size_t)r * (2 * DI_) + e0 + tx] : 0.f;
    }
    __syncthreads();
    const float4 w = *(const float4*)(cw + (size_t)(e0 + tx) * 4);
    const float bias = cb[e0 + tx];
    #pragma unroll
    for (int j = 0; j < 16; ++j) {
        const int rl = ty * 16 + j;
        float v = bias;
        v = fmaf(w.x, xs[rl + 0][tx], v);   // x[r-3]
        v = fmaf(w.y, xs[rl + 1][tx], v);   // x[r-2]
        v = fmaf(w.z, xs[rl + 2][tx], v);   // x[r-1]
        v = fmaf(w.w, xs[rl + 3][tx], v);   // x[r]
        const float o = silu_f(v);
        xib[(size_t)(r0 + rl) * DI_ + e0 + tx] = bf16_rne(o);
        tt[rl][tx] = o;
    }
    __syncthreads();
    #pragma unroll
    for (int j = 0; j < 16; ++j) {
        const int c = ty * 16 + j;
        xit[(size_t)(e0 + c) * M_ + r0 + tx] = tt[tx][c];
    }
}

// ---------------------------------------------------------------------------
// Chunked selective scan. dt_t / xi_t are TRANSPOSED [DI][M] streams
// (4-byte stride per step -> L1-resident lines instead of 8 KB strides).
// ---------------------------------------------------------------------------
__global__ __launch_bounds__(256) void scan_chunk1_kernel(
    const float* __restrict__ dt_t,  // [DI, M]
    const float* __restrict__ xdbl,  // [M, 96]
    const float* __restrict__ xi_t,  // [DI, M]
    const float* __restrict__ A_log,
    float* __restrict__ Ap, float* __restrict__ Hp)
{
    const int g = blockIdx.x * 256 + threadIdx.x;
    const int s = g & (DS_ - 1);
    const int e = (g >> 4) & (DI_ - 1);
    const int b = (g >> 15) & (B_ - 1);
    const int c = g >> 16;
    const float Aval = -__expf(A_log[(size_t)e * DS_ + s]);
    float ap = 1.f, hp = 0.f;
    const int r0 = b * T_ + c * CCH;
    const float* dtp = dt_t + (size_t)e * M_ + r0;
    const float* xip = xi_t + (size_t)e * M_ + r0;
    for (int t = 0; t < CCH; ++t) {
        const float dtv = dtp[t];
        const float u   = xip[t];
        const float bv  = xdbl[(size_t)(r0 + t) * 96 + DR_ + s];
        const float da  = __expf(dtv * Aval);
        ap *= da;
        hp = fmaf(da, hp, dtv * bv * u);
    }
    const size_t o = (((size_t)c * B_ + b) * DI_ + e) * DS_ + s;
    Ap[o] = ap; Hp[o] = hp;
}

__global__ __launch_bounds__(256) void scan_chunk2_kernel(
    float* __restrict__ Ap, float* __restrict__ Hp)
{
    const int g = blockIdx.x * 256 + threadIdx.x;
    float h = 0.f;
    #pragma unroll
    for (int c = 0; c < NC; ++c) {
        const size_t o = (size_t)c * (B_ * DI_ * DS_) + g;
        const float ap = Ap[o];
        const float hp = Hp[o];
        Hp[o] = h;
        h = fmaf(ap, h, hp);
    }
}

__global__ __launch_bounds__(256) void scan_chunk3_kernel(
    const float* __restrict__ dt_t,  // [DI, M]
    const float* __restrict__ xdbl,  // [M, 96]
    const float* __restrict__ xi_t,  // [DI, M]
    const float* __restrict__ xz,    // [M, 2*DI] (z half)
    const float* __restrict__ A_log, const float* __restrict__ Dp,
    const float* __restrict__ Hin, unsigned short* __restrict__ y)
{
    const int g = blockIdx.x * 256 + threadIdx.x;
    const int s = g & (DS_ - 1);
    const int e = (g >> 4) & (DI_ - 1);
    const int b = (g >> 15) & (B_ - 1);
    const int c = g >> 16;
    const float Aval = -__expf(A_log[(size_t)e * DS_ + s]);
    const float dpe = Dp[e];
    float h = Hin[(((size_t)c * B_ + b) * DI_ + e) * DS_ + s];
    const int r0 = b * T_ + c * CCH;
    const float* dtp = dt_t + (size_t)e * M_ + r0;
    const float* xip = xi_t + (size_t)e * M_ + r0;
    for (int t = 0; t < CCH; ++t) {
        const int r = r0 + t;
        const float dtv = dtp[t];
        const float u   = xip[t];
        const float bv  = xdbl[(size_t)r * 96 + DR_ + s];
        const float cv  = xdbl[(size_t)r * 96 + DR_ + DS_ + s];
        const float da  = __expf(dtv * Aval);
        h = fmaf(da, h, dtv * bv * u);
        const float contrib = row_reduce16(h * cv);   // sum -> lane s==15
        if (s == 15) {
            const float z = xz[(size_t)r * (2 * DI_) + DI_ + e];
            y[(size_t)r * DI_ + e] = bf16_rne((contrib + u * dpe) * silu_f(z));
        }
    }
}

extern "C" void kernel_launch(void* const* d_in, const int* in_sizes, int n_in,
                              void* d_out, int out_size, void* d_ws, size_t ws_size,
                              hipStream_t stream)
{
    const float* x       = (const float*)d_in[0];
    const float* pc      = (const float*)d_in[1];
    const float* pre_w1  = (const float*)d_in[2];
    const float* pre_w2  = (const float*)d_in[3];
    const float* norm_w  = (const float*)d_in[4];
    const float* ip_w    = (const float*)d_in[5];
    const float* conv_w  = (const float*)d_in[6];
    const float* conv_b  = (const float*)d_in[7];
    const float* xp_w    = (const float*)d_in[8];
    const float* dtp_w   = (const float*)d_in[9];
    const float* dtp_b   = (const float*)d_in[10];
    const float* A_log   = (const float*)d_in[11];
    const float* D_param = (const float*)d_in[12];
    const float* op_w    = (const float*)d_in[13];
    const float* fnw     = (const float*)d_in[14];
    float* out = (float*)d_out;

    float* ws = (float*)d_ws;
    float* h    = ws;  ws += (size_t)M_ * D_;            // fp32 residual
    float* xz   = ws;  ws += (size_t)M_ * 2 * DI_;       // in_proj out
    float* xi_t = ws;  ws += (size_t)M_ * DI_;           // conv out, [DI][M]
    float* xdbl = ws;  ws += (size_t)M_ * 96;
    float* dtb  = ws;  ws += (size_t)M_ * DI_;           // dt, [DI][M] transposed
    float* Ap   = ws;  ws += (size_t)NC * B_ * DI_ * DS_;
    float* Hp   = ws;  ws += (size_t)NC * B_ * DI_ * DS_;
    float* Pbuf = ws;  ws += (size_t)XKS * M_ * 96;      // x_proj partials
    unsigned short* xn_bf  = (unsigned short*)ws;  ws += (size_t)M_ * D_ / 2;
    unsigned short* yb_bf  = (unsigned short*)ws;  ws += (size_t)M_ * DI_ / 2;
    unsigned short* xi_bf  = (unsigned short*)ws;  ws += (size_t)M_ * DI_ / 2;
    unsigned short* dtr_bf = (unsigned short*)ws;  ws += (size_t)M_ * DR_ / 2;
    unsigned short* wbuf   = (unsigned short*)ws;  ws += (size_t)2 * DI_ * D_ / 2;
    unsigned short* xpw_bf = (unsigned short*)ws;  ws += (size_t)96 * DI_ / 2;
    unsigned short* dtpw_bf= (unsigned short*)ws;  ws += (size_t)DI_ * DR_ / 2;
    // prepend temporaries alias xz (consumed before layer 0 writes xz)
    float* tmp1 = xz;
    float* tmp2 = xz + (size_t)B_ * P_ * D_;

    const dim3 blk(256);

    // prepend embed: tmp1 = silu(pc @ pre_w1); tmp2 = tmp1 @ pre_w2
    gemm_kernel<1, false><<<dim3(D_ / 64, (B_ * P_) / 64), blk, 0, stream>>>(
        pc, pre_w1, tmp1, nullptr, B_ * P_, D_, PCD_, PCD_, D_, D_);
    gemm_kernel<0, false><<<dim3(D_ / 64, (B_ * P_) / 64), blk, 0, stream>>>(
        tmp1, pre_w2, tmp2, nullptr, B_ * P_, D_, D_, D_, D_, D_);
    assemble_h_kernel<<<dim3(M_ * D_ / 4 / 256), blk, 0, stream>>>(tmp2, x, h);

    for (int l = 0; l < L_; ++l) {
        rmsnorm_bf16_kernel<<<dim3(M_), blk, 0, stream>>>(
            h, norm_w + (size_t)l * D_, xn_bf);
        cvt_bf16_kernel<<<dim3(2 * DI_ * D_ / 4 / 256), blk, 0, stream>>>(
            ip_w + (size_t)l * 2 * DI_ * D_, wbuf, 2 * DI_ * D_ / 4);
        cvt_bf16_kernel<<<dim3(96 * DI_ / 4 / 256), blk, 0, stream>>>(
            xp_w + (size_t)l * 96 * DI_, xpw_bf, 96 * DI_ / 4);
        cvt_bf16_kernel<<<dim3(DI_ * DR_ / 4 / 256), blk, 0, stream>>>(
            dtp_w + (size_t)l * DI_ * DR_, dtpw_bf, DI_ * DR_ / 4);
        // in_proj (MFMA): xz = xn @ ip_w^T   [1152, 4096, K=1024]
        gemm_mfma_kernel<0><<<dim3(2 * DI_ / 128, M_ / 128, 1), blk, 0, stream>>>(
            xn_bf, wbuf, xz, nullptr, M_, 2 * DI_, D_, D_);
        // conv + silu + transpose: xi_bf [r][e] + xi_t [e][r]
        conv_transpose_kernel<<<dim3(M_ / 64, DI_ / 64), blk, 0, stream>>>(
            xz, conv_w + (size_t)l * DI_ * DC_, conv_b + (size_t)l * DI_,
            xi_bf, xi_t);
        // x_proj (split-K MFMA)
        xproj_mfma_kernel<<<dim3(XKS, M_ / 128), blk, 0, stream>>>(
            xi_bf, xpw_bf, Pbuf);
        xproj_reduce_kernel<<<dim3((M_ * 96 + 255) / 256), blk, 0, stream>>>(
            Pbuf, xdbl, dtr_bf);
        // dt_proj (MFMA, transposed softplus store): dtb[e][m]
        gemm_mfma_kernel<5><<<dim3(DI_ / 128, M_ / 128, 1), blk, 0, stream>>>(
            dtr_bf, dtpw_bf, dtb, dtp_b + (size_t)l * DI_, M_, DI_, DR_, DR_);
        // chunked scan
        scan_chunk1_kernel<<<dim3(NC * B_ * DI_ * DS_ / 256), blk, 0, stream>>>(
            dtb, xdbl, xi_t, A_log + (size_t)l * DI_ * DS_, Ap, Hp);
        scan_chunk2_kernel<<<dim3(B_ * DI_ * DS_ / 256), blk, 0, stream>>>(Ap, Hp);
        scan_chunk3_kernel<<<dim3(NC * B_ * DI_ * DS_ / 256), blk, 0, stream>>>(
            dtb, xdbl, xi_t, xz, A_log + (size_t)l * DI_ * DS_,
            D_param + (size_t)l * DI_, Hp, yb_bf);
        cvt_bf16_kernel<<<dim3(D_ * DI_ / 4 / 256), blk, 0, stream>>>(
            op_w + (size_t)l * D_ * DI_, wbuf, D_ * DI_ / 4);
        // out_proj + residual (split-K=2, atomicAdd): h += yb @ op_w^T
        gemm_mfma_kernel<4><<<dim3(D_ / 128, M_ / 128, 2), blk, 0, stream>>>(
            yb_bf, wbuf, h, nullptr, M_, D_, DI_, DI_ / 2);
    }

    final_rmsnorm_kernel<<<dim3(B_ * S_), blk, 0, stream>>>(h, fnw, out);
}

// Round 6
// 1100.148 us; speedup vs baseline: 3.4067x; 1.0447x over previous
//
#include <hip/hip_runtime.h>
#include <math.h>

#define B_ 2
#define S_ 512
#define P_ 64
#define T_ 576          // P_+S_
#define D_ 1024
#define L_ 4
#define DI_ 2048
#define DS_ 16
#define DC_ 4
#define DR_ 64
#define PCD_ 768
#define M_ (B_*T_)      // 1152
#define CCH 64          // scan chunk length
#define NC (T_/CCH)     // 9 chunks
#define XKS 16          // x_proj K-splits (KC = 2048/16 = 128)

typedef __attribute__((ext_vector_type(8))) short bf16x8;
typedef __attribute__((ext_vector_type(4))) float f32x4;

__device__ __forceinline__ float silu_f(float v) { return v / (1.f + __expf(-v)); }
__device__ __forceinline__ float softplus_f(float v) {
    return fmaxf(v, 0.f) + log1pf(__expf(-fabsf(v)));
}
__device__ __forceinline__ unsigned short bf16_rne(float x) {
    unsigned int b = __float_as_uint(x);
    b += 0x7fffu + ((b >> 16) & 1u);
    return (unsigned short)(b >> 16);
}

// sum over each 16-lane row via DPP row_shr (full-rate VALU, no LDS pipe).
// Result lands in lane 15 of each row of 16.
__device__ __forceinline__ float row_reduce16(float x) {
    x += __int_as_float(__builtin_amdgcn_update_dpp(
        0, __float_as_int(x), 0x111, 0xf, 0xf, true)); // row_shr:1
    x += __int_as_float(__builtin_amdgcn_update_dpp(
        0, __float_as_int(x), 0x112, 0xf, 0xf, true)); // row_shr:2
    x += __int_as_float(__builtin_amdgcn_update_dpp(
        0, __float_as_int(x), 0x114, 0xf, 0xf, true)); // row_shr:4
    x += __int_as_float(__builtin_amdgcn_update_dpp(
        0, __float_as_int(x), 0x118, 0xf, 0xf, true)); // row_shr:8
    return x;
}

typedef const void __attribute__((address_space(1)))* gas_t;
typedef void __attribute__((address_space(3)))* las_t;
__device__ __forceinline__ void async16(const void* g, void* l) {
    __builtin_amdgcn_global_load_lds((gas_t)g, (las_t)l, 16, 0, 0);
}

// ---------------------------------------------------------------------------
// bf16 MFMA GEMM (m97 structure): C[m,n] (+)= sum_k A[m,k]*W[n,k], fp32 out.
// EPI: 0 = store, 4 = atomicAdd into C, 5 = softplus(v+bias[n]) stored
//      TRANSPOSED to C[n*M + m] (float4 per lane, m-contiguous).
// ---------------------------------------------------------------------------
template<int EPI>
__global__ __launch_bounds__(256) void gemm_mfma_kernel(
    const unsigned short* __restrict__ A, const unsigned short* __restrict__ W,
    float* __restrict__ C, const float* __restrict__ bias,
    int M, int N, int K, int Kchunk)
{
    __shared__ unsigned short As[128 * 32];
    __shared__ unsigned short Bs[128 * 32];
    const int tid = threadIdx.x;
    const int wave = tid >> 6;
    const int lane = tid & 63;
    const int m0 = blockIdx.y * 128, n0 = blockIdx.x * 128;
    const int kbase = blockIdx.z * Kchunk;
    const int wm = (wave >> 1) * 64, wn = (wave & 1) * 64;

    const int srow = (wave << 5) + (lane >> 2);
    const int selem = (lane & 3) * 8;
    const unsigned short* gA = A + (size_t)(m0 + srow) * K + kbase + selem;
    const unsigned short* gB = W + (size_t)(n0 + srow) * K + kbase + selem;
    unsigned short* lA = As + (wave << 5) * 32;
    unsigned short* lB = Bs + (wave << 5) * 32;

    f32x4 acc[4][4];
    #pragma unroll
    for (int i = 0; i < 4; ++i)
        #pragma unroll
        for (int j = 0; j < 4; ++j)
            acc[i][j] = (f32x4){0.f, 0.f, 0.f, 0.f};

    const int fr = lane & 15;
    const int fq = lane >> 4;
    const int aoff = (wm + fr) * 32 + fq * 8;
    const int boff = (wn + fr) * 32 + fq * 8;

    for (int k0 = 0; k0 < Kchunk; k0 += 32) {
        async16(gA, lA);
        async16(gA + (size_t)16 * K, lA + 16 * 32);
        async16(gB, lB);
        async16(gB + (size_t)16 * K, lB + 16 * 32);
        gA += 32; gB += 32;
        __syncthreads();
        bf16x8 af[4], bf[4];
        #pragma unroll
        for (int i = 0; i < 4; ++i) af[i] = *(const bf16x8*)&As[aoff + i * 512];
        #pragma unroll
        for (int j = 0; j < 4; ++j) bf[j] = *(const bf16x8*)&Bs[boff + j * 512];
        #pragma unroll
        for (int i = 0; i < 4; ++i)
            #pragma unroll
            for (int j = 0; j < 4; ++j)
                acc[i][j] = __builtin_amdgcn_mfma_f32_16x16x32_bf16(
                    af[i], bf[j], acc[i][j], 0, 0, 0);
        __syncthreads();
    }

    // C/D layout (m89-verified): col = lane&15, row = (lane>>4)*4 + reg
    #pragma unroll
    for (int i = 0; i < 4; ++i) {
        const int m = m0 + wm + i * 16 + fq * 4;
        #pragma unroll
        for (int j = 0; j < 4; ++j) {
            const int n = n0 + wn + j * 16 + fr;
            if (EPI == 5) {
                const float bb = bias[n];
                float4 o;
                o.x = softplus_f(acc[i][j][0] + bb);
                o.y = softplus_f(acc[i][j][1] + bb);
                o.z = softplus_f(acc[i][j][2] + bb);
                o.w = softplus_f(acc[i][j][3] + bb);
                *(float4*)(C + (size_t)n * M + m) = o;   // transposed, m%4==0
            } else {
                float* p = C + (size_t)m * N + n;
                #pragma unroll
                for (int r = 0; r < 4; ++r) {
                    const float v = acc[i][j][r];
                    if (EPI == 4) atomicAdd(p + (size_t)r * N, v);
                    else          p[(size_t)r * N] = v;
                }
            }
        }
    }
}

// ---------------------------------------------------------------------------
// x_proj split-K MFMA: P[ks][m][96] = xi_bf[m, ks*128:(ks+1)*128] @ W[96,...]^T
// ---------------------------------------------------------------------------
__global__ __launch_bounds__(256) void xproj_mfma_kernel(
    const unsigned short* __restrict__ A,   // [M, 2048] bf16
    const unsigned short* __restrict__ W,   // [96, 2048] bf16
    float* __restrict__ P)                  // [XKS, M, 96]
{
    __shared__ unsigned short As[128 * 32];
    __shared__ unsigned short Bs[96 * 32];
    const int tid = threadIdx.x;
    const int wave = tid >> 6;
    const int lane = tid & 63;
    const int m0 = blockIdx.y * 128;
    const int kbase = blockIdx.x * (DI_ / XKS);   // 128
    const int wm = (wave >> 1) * 64, wn = (wave & 1) * 48;

    const int srow = (wave << 5) + (lane >> 2);
    const int selem = (lane & 3) * 8;
    const unsigned short* gA = A + (size_t)(m0 + srow) * DI_ + kbase + selem;
    const unsigned short* gB = W + (size_t)srow * DI_ + kbase + selem;
    unsigned short* lA = As + (wave << 5) * 32;
    unsigned short* lB = Bs + (wave << 5) * 32;

    f32x4 acc[4][3];
    #pragma unroll
    for (int i = 0; i < 4; ++i)
        #pragma unroll
        for (int j = 0; j < 3; ++j)
            acc[i][j] = (f32x4){0.f, 0.f, 0.f, 0.f};

    const int fr = lane & 15;
    const int fq = lane >> 4;
    const int aoff = (wm + fr) * 32 + fq * 8;
    const int boff = (wn + fr) * 32 + fq * 8;

    #pragma unroll
    for (int kk = 0; kk < 4; ++kk) {
        async16(gA, lA);
        async16(gA + (size_t)16 * DI_, lA + 16 * 32);
        if (wave < 3) {
            async16(gB, lB);
            async16(gB + (size_t)16 * DI_, lB + 16 * 32);
        }
        gA += 32; gB += 32;
        __syncthreads();
        bf16x8 af[4], bf[3];
        #pragma unroll
        for (int i = 0; i < 4; ++i) af[i] = *(const bf16x8*)&As[aoff + i * 512];
        #pragma unroll
        for (int j = 0; j < 3; ++j) bf[j] = *(const bf16x8*)&Bs[boff + j * 512];
        #pragma unroll
        for (int i = 0; i < 4; ++i)
            #pragma unroll
            for (int j = 0; j < 3; ++j)
                acc[i][j] = __builtin_amdgcn_mfma_f32_16x16x32_bf16(
                    af[i], bf[j], acc[i][j], 0, 0, 0);
        __syncthreads();
    }

    float* Pb = P + ((size_t)blockIdx.x * M_ + m0) * 96;
    #pragma unroll
    for (int i = 0; i < 4; ++i) {
        const int m = wm + i * 16 + fq * 4;
        #pragma unroll
        for (int j = 0; j < 3; ++j) {
            const int n = wn + j * 16 + fr;
            #pragma unroll
            for (int r = 0; r < 4; ++r)
                Pb[(size_t)(m + r) * 96 + n] = acc[i][j][r];
        }
    }
}

// reduce partials; emit dtr_bf [m][64] plus TRANSPOSED scan streams
// Bt[s][m], Ct[s][m] (s in 0..15).
__global__ __launch_bounds__(256) void xproj_reduce_kernel(
    const float* __restrict__ P, float* __restrict__ Bt, float* __restrict__ Ct,
    unsigned short* __restrict__ dtr_bf)
{
    const int i = blockIdx.x * 256 + threadIdx.x;
    if (i >= M_ * 96) return;
    float s = 0.f;
    #pragma unroll
    for (int ks = 0; ks < XKS; ++ks) s += P[(size_t)ks * (M_ * 96) + i];
    const int m = i / 96;
    const int n = i - m * 96;
    if (n < DR_)            dtr_bf[(size_t)m * DR_ + n] = bf16_rne(s);
    else if (n < DR_ + DS_) Bt[(size_t)(n - DR_) * M_ + m] = s;
    else                    Ct[(size_t)(n - DR_ - DS_) * M_ + m] = s;
}

// fp32 -> bf16 (RNE), vectorized x4
__global__ __launch_bounds__(256) void cvt_bf16_kernel(
    const float* __restrict__ in, unsigned short* __restrict__ out, int n4)
{
    const int i = blockIdx.x * 256 + threadIdx.x;
    if (i >= n4) return;
    const float4 v = ((const float4*)in)[i];
    ushort4 o;
    o.x = bf16_rne(v.x); o.y = bf16_rne(v.y);
    o.z = bf16_rne(v.z); o.w = bf16_rne(v.w);
    ((ushort4*)out)[i] = o;
}

// three conversions in one launch (in_proj + x_proj + dt_proj weights)
__global__ __launch_bounds__(256) void cvt3_kernel(
    const float* __restrict__ s0, unsigned short* __restrict__ d0, int n0,
    const float* __restrict__ s1, unsigned short* __restrict__ d1, int n1,
    const float* __restrict__ s2, unsigned short* __restrict__ d2, int n2)
{
    const int i = blockIdx.x * 256 + threadIdx.x;
    const float* s; unsigned short* d; int off;
    if (i < n0)           { s = s0; d = d0; off = i; }
    else if (i < n0 + n1) { s = s1; d = d1; off = i - n0; }
    else if (i < n0 + n1 + n2) { s = s2; d = d2; off = i - n0 - n1; }
    else return;
    const float4 v = ((const float4*)s)[off];
    ushort4 o;
    o.x = bf16_rne(v.x); o.y = bf16_rne(v.y);
    o.z = bf16_rne(v.z); o.w = bf16_rne(v.w);
    ((ushort4*)d)[off] = o;
}

// ---------------------------------------------------------------------------
// Generic tiled fp32 GEMM (prepend path only).
// ---------------------------------------------------------------------------
template<int EPI, bool NT>
__global__ __launch_bounds__(256) void gemm_kernel(
    const float* __restrict__ A, const float* __restrict__ W,
    float* __restrict__ C, const float* __restrict__ bias,
    int M, int N, int K, int lda, int ldw, int ldc)
{
    __shared__ __align__(16) float As[16][68];
    __shared__ __align__(16) float Ws[16][68];
    const int m0 = blockIdx.y * 64;
    const int n0 = blockIdx.x * 64;
    const int tid = threadIdx.x;
    const int ty = tid >> 4;
    const int tx = tid & 15;
    float acc[4][4] = {};

    const int lr = tid >> 2;
    const int lk = (tid & 3) * 4;
    const int kk = tid >> 4;
    const int nq = (tid & 15) * 4;

    for (int k0 = 0; k0 < K; k0 += 16) {
        {
            const float4 v = *(const float4*)(A + (size_t)(m0 + lr) * lda + k0 + lk);
            As[lk + 0][lr] = v.x; As[lk + 1][lr] = v.y;
            As[lk + 2][lr] = v.z; As[lk + 3][lr] = v.w;
        }
        if (NT) {
            const int n = n0 + lr;
            float4 v = make_float4(0.f, 0.f, 0.f, 0.f);
            if (n < N) v = *(const float4*)(W + (size_t)n * ldw + k0 + lk);
            Ws[lk + 0][lr] = v.x; Ws[lk + 1][lr] = v.y;
            Ws[lk + 2][lr] = v.z; Ws[lk + 3][lr] = v.w;
        } else {
            const int n = n0 + nq;
            float4 v = make_float4(0.f, 0.f, 0.f, 0.f);
            if (n < N) v = *(const float4*)(W + (size_t)(k0 + kk) * ldw + n);
            Ws[kk][nq + 0] = v.x; Ws[kk][nq + 1] = v.y;
            Ws[kk][nq + 2] = v.z; Ws[kk][nq + 3] = v.w;
        }
        __syncthreads();
        #pragma unroll
        for (int k = 0; k < 16; ++k) {
            const float4 a = *(const float4*)&As[k][ty * 4];
            const float4 b = *(const float4*)&Ws[k][tx * 4];
            acc[0][0] = fmaf(a.x, b.x, acc[0][0]);
            acc[0][1] = fmaf(a.x, b.y, acc[0][1]);
            acc[0][2] = fmaf(a.x, b.z, acc[0][2]);
            acc[0][3] = fmaf(a.x, b.w, acc[0][3]);
            acc[1][0] = fmaf(a.y, b.x, acc[1][0]);
            acc[1][1] = fmaf(a.y, b.y, acc[1][1]);
            acc[1][2] = fmaf(a.y, b.z, acc[1][2]);
            acc[1][3] = fmaf(a.y, b.w, acc[1][3]);
            acc[2][0] = fmaf(a.z, b.x, acc[2][0]);
            acc[2][1] = fmaf(a.z, b.y, acc[2][1]);
            acc[2][2] = fmaf(a.z, b.z, acc[2][2]);
            acc[2][3] = fmaf(a.z, b.w, acc[2][3]);
            acc[3][0] = fmaf(a.w, b.x, acc[3][0]);
            acc[3][1] = fmaf(a.w, b.y, acc[3][1]);
            acc[3][2] = fmaf(a.w, b.z, acc[3][2]);
            acc[3][3] = fmaf(a.w, b.w, acc[3][3]);
        }
        __syncthreads();
    }
    #pragma unroll
    for (int i = 0; i < 4; ++i) {
        const int m = m0 + ty * 4 + i;
        #pragma unroll
        for (int j = 0; j < 4; ++j) {
            const int n = n0 + tx * 4 + j;
            if (n < N) {
                float v = acc[i][j];
                if (EPI == 1) v = silu_f(v);
                C[(size_t)m * ldc + n] = v;
            }
        }
    }
}

// h[b*T+t, :] = (t < P) ? p[b*P+t, :] : x[b*S + (t-P), :]
__global__ __launch_bounds__(256) void assemble_h_kernel(
    const float* __restrict__ p, const float* __restrict__ x, float* __restrict__ h)
{
    const int idx = blockIdx.x * 256 + threadIdx.x;
    const int r = idx >> 8;
    const int c = idx & 255;
    const int b = r / T_;
    const int t = r - b * T_;
    float4 v;
    if (t < P_) v = ((const float4*)p)[(size_t)(b * P_ + t) * 256 + c];
    else        v = ((const float4*)x)[(size_t)(b * S_ + (t - P_)) * 256 + c];
    ((float4*)h)[idx] = v;
}

// rmsnorm -> bf16 output (feeds in_proj MFMA). one block per row.
__global__ __launch_bounds__(256) void rmsnorm_bf16_kernel(
    const float* __restrict__ x, const float* __restrict__ w,
    unsigned short* __restrict__ outb)
{
    const int r = blockIdx.x;
    const float4 v = ((const float4*)(x + (size_t)r * D_))[threadIdx.x];
    float ss = v.x * v.x + v.y * v.y + v.z * v.z + v.w * v.w;
    ss += __shfl_xor(ss, 32, 64);
    ss += __shfl_xor(ss, 16, 64);
    ss += __shfl_xor(ss, 8, 64);
    ss += __shfl_xor(ss, 4, 64);
    ss += __shfl_xor(ss, 2, 64);
    ss += __shfl_xor(ss, 1, 64);
    __shared__ float red[4];
    if ((threadIdx.x & 63) == 0) red[threadIdx.x >> 6] = ss;
    __syncthreads();
    const float tot = red[0] + red[1] + red[2] + red[3];
    const float scale = rsqrtf(tot * (1.f / D_) + 1e-5f);
    const float4 wv = ((const float4*)w)[threadIdx.x];
    ushort4 o;
    o.x = bf16_rne(v.x * scale * wv.x);
    o.y = bf16_rne(v.y * scale * wv.y);
    o.z = bf16_rne(v.z * scale * wv.z);
    o.w = bf16_rne(v.w * scale * wv.w);
    ((ushort4*)(outb + (size_t)r * D_))[threadIdx.x] = o;
}

// final rmsnorm (fp32 out): rows over B*S; reads h[b*T+P+s]
__global__ __launch_bounds__(256) void final_rmsnorm_kernel(
    const float* __restrict__ h, const float* __restrict__ w, float* __restrict__ out)
{
    const int r = blockIdx.x;
    const int b = r / S_;
    const int s = r - b * S_;
    const int hr = b * T_ + P_ + s;
    const float4 v = ((const float4*)(h + (size_t)hr * D_))[threadIdx.x];
    float ss = v.x * v.x + v.y * v.y + v.z * v.z + v.w * v.w;
    ss += __shfl_xor(ss, 32, 64);
    ss += __shfl_xor(ss, 16, 64);
    ss += __shfl_xor(ss, 8, 64);
    ss += __shfl_xor(ss, 4, 64);
    ss += __shfl_xor(ss, 2, 64);
    ss += __shfl_xor(ss, 1, 64);
    __shared__ float red[4];
    if ((threadIdx.x & 63) == 0) red[threadIdx.x >> 6] = ss;
    __syncthreads();
    const float tot = red[0] + red[1] + red[2] + red[3];
    const float scale = rsqrtf(tot * (1.f / D_) + 1e-5f);
    const float4 wv = ((const float4*)w)[threadIdx.x];
    float4 o;
    o.x = v.x * scale * wv.x; o.y = v.y * scale * wv.y;
    o.z = v.z * scale * wv.z; o.w = v.w * scale * wv.w;
    ((float4*)(out + (size_t)r * D_))[threadIdx.x] = o;
}

// ---------------------------------------------------------------------------
// Fused causal depthwise conv (DC=4) + bias + silu + transpose, PLUS
// silu(z) transposed stream. Outputs:
//   xib  [r][e] bf16  (x_proj MFMA operand)
//   xit  [e][r] fp32  (scan u stream)
//   szt  [e][r] fp32  (scan gate stream = silu(z))
// Tile: 64 r x 64 e. Batch boundary is tile-aligned (576 % 64 == 0).
// ---------------------------------------------------------------------------
__global__ __launch_bounds__(256) void conv_transpose_kernel(
    const float* __restrict__ xz, const float* __restrict__ cw,
    const float* __restrict__ cb, unsigned short* __restrict__ xib,
    float* __restrict__ xit, float* __restrict__ szt)
{
    __shared__ float xs[68][64];    // rows r0-3 .. r0+63 (67 used)
    __shared__ float tt[64][65];    // transpose staging, padded
    const int tid = threadIdx.x;
    const int tx = tid & 63;
    const int ty = tid >> 6;        // 0..3
    const int r0 = blockIdx.x * 64;
    const int e0 = blockIdx.y * 64;
    const int bt0 = (r0 / T_) * T_; // batch start row

    for (int j = ty; j < 67; j += 4) {
        const int r = r0 + j - 3;
        xs[j][tx] = (r >= bt0) ? xz[(size_t)r * (2 * DI_) + e0 + tx] : 0.f;
    }
    __syncthreads();
    const float4 w = *(const float4*)(cw + (size_t)(e0 + tx) * 4);
    const float bias = cb[e0 + tx];
    #pragma unroll
    for (int j = 0; j < 16; ++j) {
        const int rl = ty * 16 + j;
        float v = bias;
        v = fmaf(w.x, xs[rl + 0][tx], v);   // x[r-3]
        v = fmaf(w.y, xs[rl + 1][tx], v);   // x[r-2]
        v = fmaf(w.z, xs[rl + 2][tx], v);   // x[r-1]
        v = fmaf(w.w, xs[rl + 3][tx], v);   // x[r]
        const float o = silu_f(v);
        xib[(size_t)(r0 + rl) * DI_ + e0 + tx] = bf16_rne(o);
        tt[rl][tx] = o;
    }
    __syncthreads();
    #pragma unroll
    for (int j = 0; j < 16; ++j) {
        const int c = ty * 16 + j;
        xit[(size_t)(e0 + c) * M_ + r0 + tx] = tt[tx][c];
    }
    __syncthreads();
    // z half -> silu -> transpose
    #pragma unroll
    for (int j = 0; j < 16; ++j) {
        const int rl = ty * 16 + j;
        tt[rl][tx] = silu_f(xz[(size_t)(r0 + rl) * (2 * DI_) + DI_ + e0 + tx]);
    }
    __syncthreads();
    #pragma unroll
    for (int j = 0; j < 16; ++j) {
        const int c = ty * 16 + j;
        szt[(size_t)(e0 + c) * M_ + r0 + tx] = tt[tx][c];
    }
}

// ---------------------------------------------------------------------------
// Chunked selective scan, float4 x4 time-unroll. All operand streams are
// contiguous in t: dt_t/xi_t/szt [e][m], Bt/Ct [s][m]. 5 vector loads per
// 4 steps instead of ~20 scalar loads (R5 was issue/latency-bound, VGPR=12).
// ---------------------------------------------------------------------------
__global__ __launch_bounds__(256) void scan_chunk1_kernel(
    const float* __restrict__ dt_t,  // [DI, M]
    const float* __restrict__ Bt,    // [16, M]
    const float* __restrict__ xi_t,  // [DI, M]
    const float* __restrict__ A_log,
    float* __restrict__ Ap, float* __restrict__ Hp)
{
    const int g = blockIdx.x * 256 + threadIdx.x;
    const int s = g & (DS_ - 1);
    const int e = (g >> 4) & (DI_ - 1);
    const int b = (g >> 15) & (B_ - 1);
    const int c = g >> 16;
    const float Aval = -__expf(A_log[(size_t)e * DS_ + s]);
    float ap = 1.f, hp = 0.f;
    const int r0 = b * T_ + c * CCH;
    const float4* dtp = (const float4*)(dt_t + (size_t)e * M_ + r0);
    const float4* xip = (const float4*)(xi_t + (size_t)e * M_ + r0);
    const float4* bp  = (const float4*)(Bt   + (size_t)s * M_ + r0);
    #pragma unroll 4
    for (int q = 0; q < CCH / 4; ++q) {
        const float4 dtq = dtp[q];
        const float4 uq  = xip[q];
        const float4 bq  = bp[q];
        const float* dta = &dtq.x;
        const float* ua  = &uq.x;
        const float* ba  = &bq.x;
        #pragma unroll
        for (int j = 0; j < 4; ++j) {
            const float dtv = dta[j];
            const float da  = __expf(dtv * Aval);
            ap *= da;
            hp = fmaf(da, hp, dtv * ba[j] * ua[j]);
        }
    }
    const size_t o = (((size_t)c * B_ + b) * DI_ + e) * DS_ + s;
    Ap[o] = ap; Hp[o] = hp;
}

__global__ __launch_bounds__(256) void scan_chunk2_kernel(
    float* __restrict__ Ap, float* __restrict__ Hp)
{
    const int g = blockIdx.x * 256 + threadIdx.x;
    float h = 0.f;
    #pragma unroll
    for (int c = 0; c < NC; ++c) {
        const size_t o = (size_t)c * (B_ * DI_ * DS_) + g;
        const float ap = Ap[o];
        const float hp = Hp[o];
        Hp[o] = h;
        h = fmaf(ap, h, hp);
    }
}

__global__ __launch_bounds__(256) void scan_chunk3_kernel(
    const float* __restrict__ dt_t,  // [DI, M]
    const float* __restrict__ Bt,    // [16, M]
    const float* __restrict__ Ct,    // [16, M]
    const float* __restrict__ xi_t,  // [DI, M]
    const float* __restrict__ szt,   // [DI, M] silu(z)
    const float* __restrict__ A_log, const float* __restrict__ Dp,
    const float* __restrict__ Hin, unsigned short* __restrict__ y)
{
    const int g = blockIdx.x * 256 + threadIdx.x;
    const int s = g & (DS_ - 1);
    const int e = (g >> 4) & (DI_ - 1);
    const int b = (g >> 15) & (B_ - 1);
    const int c = g >> 16;
    const float Aval = -__expf(A_log[(size_t)e * DS_ + s]);
    const float dpe = Dp[e];
    float h = Hin[(((size_t)c * B_ + b) * DI_ + e) * DS_ + s];
    const int r0 = b * T_ + c * CCH;
    const float4* dtp = (const float4*)(dt_t + (size_t)e * M_ + r0);
    const float4* xip = (const float4*)(xi_t + (size_t)e * M_ + r0);
    const float4* szp = (const float4*)(szt  + (size_t)e * M_ + r0);
    const float4* bp  = (const float4*)(Bt   + (size_t)s * M_ + r0);
    const float4* cp  = (const float4*)(Ct   + (size_t)s * M_ + r0);
    unsigned short* yp = y + (size_t)r0 * DI_ + e;
    #pragma unroll 4
    for (int q = 0; q < CCH / 4; ++q) {
        const float4 dtq = dtp[q];
        const float4 uq  = xip[q];
        const float4 bq  = bp[q];
        const float4 cq  = cp[q];
        const float4 szq = szp[q];
        const float* dta = &dtq.x;
        const float* ua  = &uq.x;
        const float* ba  = &bq.x;
        const float* ca  = &cq.x;
        const float* sza = &szq.x;
        #pragma unroll
        for (int j = 0; j < 4; ++j) {
            const float dtv = dta[j];
            const float u   = ua[j];
            const float da  = __expf(dtv * Aval);
            h = fmaf(da, h, dtv * ba[j] * u);
            const float contrib = row_reduce16(h * ca[j]);  // sum -> lane 15
            const float yv = fmaf(u, dpe, contrib) * sza[j];
            if (s == 15)
                yp[(size_t)(q * 4 + j) * DI_] = bf16_rne(yv);
        }
    }
}

extern "C" void kernel_launch(void* const* d_in, const int* in_sizes, int n_in,
                              void* d_out, int out_size, void* d_ws, size_t ws_size,
                              hipStream_t stream)
{
    const float* x       = (const float*)d_in[0];
    const float* pc      = (const float*)d_in[1];
    const float* pre_w1  = (const float*)d_in[2];
    const float* pre_w2  = (const float*)d_in[3];
    const float* norm_w  = (const float*)d_in[4];
    const float* ip_w    = (const float*)d_in[5];
    const float* conv_w  = (const float*)d_in[6];
    const float* conv_b  = (const float*)d_in[7];
    const float* xp_w    = (const float*)d_in[8];
    const float* dtp_w   = (const float*)d_in[9];
    const float* dtp_b   = (const float*)d_in[10];
    const float* A_log   = (const float*)d_in[11];
    const float* D_param = (const float*)d_in[12];
    const float* op_w    = (const float*)d_in[13];
    const float* fnw     = (const float*)d_in[14];
    float* out = (float*)d_out;

    float* ws = (float*)d_ws;
    float* h    = ws;  ws += (size_t)M_ * D_;            // fp32 residual
    float* xz   = ws;  ws += (size_t)M_ * 2 * DI_;       // in_proj out
    float* xi_t = ws;  ws += (size_t)M_ * DI_;           // conv out, [DI][M]
    float* szt  = ws;  ws += (size_t)M_ * DI_;           // silu(z), [DI][M]
    float* dtb  = ws;  ws += (size_t)M_ * DI_;           // dt, [DI][M]
    float* Ap   = ws;  ws += (size_t)NC * B_ * DI_ * DS_;
    float* Hp   = ws;  ws += (size_t)NC * B_ * DI_ * DS_;
    float* Pbuf = ws;  ws += (size_t)XKS * M_ * 96;      // x_proj partials
    float* Bt   = ws;  ws += (size_t)DS_ * M_;           // B stream [s][m]
    float* Ct   = ws;  ws += (size_t)DS_ * M_;           // C stream [s][m]
    unsigned short* xn_bf  = (unsigned short*)ws;  ws += (size_t)M_ * D_ / 2;
    unsigned short* yb_bf  = (unsigned short*)ws;  ws += (size_t)M_ * DI_ / 2;
    unsigned short* xi_bf  = (unsigned short*)ws;  ws += (size_t)M_ * DI_ / 2;
    unsigned short* dtr_bf = (unsigned short*)ws;  ws += (size_t)M_ * DR_ / 2;
    unsigned short* wbuf   = (unsigned short*)ws;  ws += (size_t)2 * DI_ * D_ / 2;
    unsigned short* xpw_bf = (unsigned short*)ws;  ws += (size_t)96 * DI_ / 2;
    unsigned short* dtpw_bf= (unsigned short*)ws;  ws += (size_t)DI_ * DR_ / 2;
    // prepend temporaries alias xz (consumed before layer 0 writes xz)
    float* tmp1 = xz;
    float* tmp2 = xz + (size_t)B_ * P_ * D_;

    const dim3 blk(256);

    // prepend embed: tmp1 = silu(pc @ pre_w1); tmp2 = tmp1 @ pre_w2
    gemm_kernel<1, false><<<dim3(D_ / 64, (B_ * P_) / 64), blk, 0, stream>>>(
        pc, pre_w1, tmp1, nullptr, B_ * P_, D_, PCD_, PCD_, D_, D_);
    gemm_kernel<0, false><<<dim3(D_ / 64, (B_ * P_) / 64), blk, 0, stream>>>(
        tmp1, pre_w2, tmp2, nullptr, B_ * P_, D_, D_, D_, D_, D_);
    assemble_h_kernel<<<dim3(M_ * D_ / 4 / 256), blk, 0, stream>>>(tmp2, x, h);

    const int n_ip  = 2 * DI_ * D_ / 4;
    const int n_xp  = 96 * DI_ / 4;
    const int n_dtp = DI_ * DR_ / 4;

    for (int l = 0; l < L_; ++l) {
        rmsnorm_bf16_kernel<<<dim3(M_), blk, 0, stream>>>(
            h, norm_w + (size_t)l * D_, xn_bf);
        cvt3_kernel<<<dim3((n_ip + n_xp + n_dtp + 255) / 256), blk, 0, stream>>>(
            ip_w + (size_t)l * 2 * DI_ * D_, wbuf, n_ip,
            xp_w + (size_t)l * 96 * DI_, xpw_bf, n_xp,
            dtp_w + (size_t)l * DI_ * DR_, dtpw_bf, n_dtp);
        // in_proj (MFMA): xz = xn @ ip_w^T   [1152, 4096, K=1024]
        gemm_mfma_kernel<0><<<dim3(2 * DI_ / 128, M_ / 128, 1), blk, 0, stream>>>(
            xn_bf, wbuf, xz, nullptr, M_, 2 * DI_, D_, D_);
        // conv + silu + transposes: xi_bf [r][e], xi_t [e][r], szt [e][r]
        conv_transpose_kernel<<<dim3(M_ / 64, DI_ / 64), blk, 0, stream>>>(
            xz, conv_w + (size_t)l * DI_ * DC_, conv_b + (size_t)l * DI_,
            xi_bf, xi_t, szt);
        // x_proj (split-K MFMA) + reduce -> dtr_bf, Bt, Ct
        xproj_mfma_kernel<<<dim3(XKS, M_ / 128), blk, 0, stream>>>(
            xi_bf, xpw_bf, Pbuf);
        xproj_reduce_kernel<<<dim3((M_ * 96 + 255) / 256), blk, 0, stream>>>(
            Pbuf, Bt, Ct, dtr_bf);
        // dt_proj (MFMA, transposed softplus store): dtb[e][m]
        gemm_mfma_kernel<5><<<dim3(DI_ / 128, M_ / 128, 1), blk, 0, stream>>>(
            dtr_bf, dtpw_bf, dtb, dtp_b + (size_t)l * DI_, M_, DI_, DR_, DR_);
        // chunked scan
        scan_chunk1_kernel<<<dim3(NC * B_ * DI_ * DS_ / 256), blk, 0, stream>>>(
            dtb, Bt, xi_t, A_log + (size_t)l * DI_ * DS_, Ap, Hp);
        scan_chunk2_kernel<<<dim3(B_ * DI_ * DS_ / 256), blk, 0, stream>>>(Ap, Hp);
        scan_chunk3_kernel<<<dim3(NC * B_ * DI_ * DS_ / 256), blk, 0, stream>>>(
            dtb, Bt, Ct, xi_t, szt, A_log + (size_t)l * DI_ * DS_,
            D_param + (size_t)l * DI_, Hp, yb_bf);
        // out_proj weights -> bf16 (reuses wbuf; in_proj GEMM done)
        cvt_bf16_kernel<<<dim3(D_ * DI_ / 4 / 256), blk, 0, stream>>>(
            op_w + (size_t)l * D_ * DI_, wbuf, D_ * DI_ / 4);
        // out_proj + residual (split-K=2, atomicAdd): h += yb @ op_w^T
        gemm_mfma_kernel<4><<<dim3(D_ / 128, M_ / 128, 2), blk, 0, stream>>>(
            yb_bf, wbuf, h, nullptr, M_, D_, DI_, DI_ / 2);
    }

    final_rmsnorm_kernel<<<dim3(B_ * S_), blk, 0, stream>>>(h, fnw, out);
}

// Round 7
// 1074.380 us; speedup vs baseline: 3.4884x; 1.0240x over previous
//
#include <hip/hip_runtime.h>
#include <math.h>

#define B_ 2
#define S_ 512
#define P_ 64
#define T_ 576          // P_+S_
#define D_ 1024
#define L_ 4
#define DI_ 2048
#define DS_ 16
#define DC_ 4
#define DR_ 64
#define PCD_ 768
#define M_ (B_*T_)      // 1152
#define CCH 64          // scan chunk length
#define NC (T_/CCH)     // 9 chunks
#define XKS 16          // x_proj K-splits (KC = 2048/16 = 128)

typedef __attribute__((ext_vector_type(8))) short bf16x8;
typedef __attribute__((ext_vector_type(4))) float f32x4;

__device__ __forceinline__ float silu_f(float v) { return v / (1.f + __expf(-v)); }
__device__ __forceinline__ float softplus_f(float v) {
    return fmaxf(v, 0.f) + log1pf(__expf(-fabsf(v)));
}
__device__ __forceinline__ unsigned short bf16_rne(float x) {
    unsigned int b = __float_as_uint(x);
    b += 0x7fffu + ((b >> 16) & 1u);
    return (unsigned short)(b >> 16);
}

// sum over each 16-lane row via DPP row_shr (full-rate VALU, no LDS pipe).
// Result lands in lane 15 of each row of 16.
__device__ __forceinline__ float row_reduce16(float x) {
    x += __int_as_float(__builtin_amdgcn_update_dpp(
        0, __float_as_int(x), 0x111, 0xf, 0xf, true)); // row_shr:1
    x += __int_as_float(__builtin_amdgcn_update_dpp(
        0, __float_as_int(x), 0x112, 0xf, 0xf, true)); // row_shr:2
    x += __int_as_float(__builtin_amdgcn_update_dpp(
        0, __float_as_int(x), 0x114, 0xf, 0xf, true)); // row_shr:4
    x += __int_as_float(__builtin_amdgcn_update_dpp(
        0, __float_as_int(x), 0x118, 0xf, 0xf, true)); // row_shr:8
    return x;
}

typedef const void __attribute__((address_space(1)))* gas_t;
typedef void __attribute__((address_space(3)))* las_t;
__device__ __forceinline__ void async16(const void* g, void* l) {
    __builtin_amdgcn_global_load_lds((gas_t)g, (las_t)l, 16, 0, 0);
}

// ---------------------------------------------------------------------------
// bf16 MFMA GEMM (m97 structure): C[m,n] (+)= sum_k A[m,k]*W[n,k], fp32 out.
// EPI: 0 = store, 4 = atomicAdd into C, 5 = softplus(v+bias[n]) stored
//      TRANSPOSED to C[n*M + m], 6 = split-K partial store to
//      C[(z*M + m)*N + n] (no atomics; deterministic reduce follows).
// ---------------------------------------------------------------------------
template<int EPI>
__global__ __launch_bounds__(256) void gemm_mfma_kernel(
    const unsigned short* __restrict__ A, const unsigned short* __restrict__ W,
    float* __restrict__ C, const float* __restrict__ bias,
    int M, int N, int K, int Kchunk)
{
    __shared__ unsigned short As[128 * 32];
    __shared__ unsigned short Bs[128 * 32];
    const int tid = threadIdx.x;
    const int wave = tid >> 6;
    const int lane = tid & 63;
    const int m0 = blockIdx.y * 128, n0 = blockIdx.x * 128;
    const int kbase = blockIdx.z * Kchunk;
    const int wm = (wave >> 1) * 64, wn = (wave & 1) * 64;

    const int srow = (wave << 5) + (lane >> 2);
    const int selem = (lane & 3) * 8;
    const unsigned short* gA = A + (size_t)(m0 + srow) * K + kbase + selem;
    const unsigned short* gB = W + (size_t)(n0 + srow) * K + kbase + selem;
    unsigned short* lA = As + (wave << 5) * 32;
    unsigned short* lB = Bs + (wave << 5) * 32;

    f32x4 acc[4][4];
    #pragma unroll
    for (int i = 0; i < 4; ++i)
        #pragma unroll
        for (int j = 0; j < 4; ++j)
            acc[i][j] = (f32x4){0.f, 0.f, 0.f, 0.f};

    const int fr = lane & 15;
    const int fq = lane >> 4;
    const int aoff = (wm + fr) * 32 + fq * 8;
    const int boff = (wn + fr) * 32 + fq * 8;

    for (int k0 = 0; k0 < Kchunk; k0 += 32) {
        async16(gA, lA);
        async16(gA + (size_t)16 * K, lA + 16 * 32);
        async16(gB, lB);
        async16(gB + (size_t)16 * K, lB + 16 * 32);
        gA += 32; gB += 32;
        __syncthreads();
        bf16x8 af[4], bf[4];
        #pragma unroll
        for (int i = 0; i < 4; ++i) af[i] = *(const bf16x8*)&As[aoff + i * 512];
        #pragma unroll
        for (int j = 0; j < 4; ++j) bf[j] = *(const bf16x8*)&Bs[boff + j * 512];
        #pragma unroll
        for (int i = 0; i < 4; ++i)
            #pragma unroll
            for (int j = 0; j < 4; ++j)
                acc[i][j] = __builtin_amdgcn_mfma_f32_16x16x32_bf16(
                    af[i], bf[j], acc[i][j], 0, 0, 0);
        __syncthreads();
    }

    // C/D layout (m89-verified): col = lane&15, row = (lane>>4)*4 + reg
    #pragma unroll
    for (int i = 0; i < 4; ++i) {
        const int m = m0 + wm + i * 16 + fq * 4;
        #pragma unroll
        for (int j = 0; j < 4; ++j) {
            const int n = n0 + wn + j * 16 + fr;
            if (EPI == 5) {
                const float bb = bias[n];
                float4 o;
                o.x = softplus_f(acc[i][j][0] + bb);
                o.y = softplus_f(acc[i][j][1] + bb);
                o.z = softplus_f(acc[i][j][2] + bb);
                o.w = softplus_f(acc[i][j][3] + bb);
                *(float4*)(C + (size_t)n * M + m) = o;   // transposed, m%4==0
            } else if (EPI == 6) {
                float* p = C + ((size_t)blockIdx.z * M + m) * N + n;
                #pragma unroll
                for (int r = 0; r < 4; ++r)
                    p[(size_t)r * N] = acc[i][j][r];
            } else {
                float* p = C + (size_t)m * N + n;
                #pragma unroll
                for (int r = 0; r < 4; ++r) {
                    const float v = acc[i][j][r];
                    if (EPI == 4) atomicAdd(p + (size_t)r * N, v);
                    else          p[(size_t)r * N] = v;
                }
            }
        }
    }
}

// ---------------------------------------------------------------------------
// x_proj split-K MFMA: P[ks][m][96] = xi_bf[m, ks*128:(ks+1)*128] @ W[96,...]^T
// ---------------------------------------------------------------------------
__global__ __launch_bounds__(256) void xproj_mfma_kernel(
    const unsigned short* __restrict__ A,   // [M, 2048] bf16
    const unsigned short* __restrict__ W,   // [96, 2048] bf16
    float* __restrict__ P)                  // [XKS, M, 96]
{
    __shared__ unsigned short As[128 * 32];
    __shared__ unsigned short Bs[96 * 32];
    const int tid = threadIdx.x;
    const int wave = tid >> 6;
    const int lane = tid & 63;
    const int m0 = blockIdx.y * 128;
    const int kbase = blockIdx.x * (DI_ / XKS);   // 128
    const int wm = (wave >> 1) * 64, wn = (wave & 1) * 48;

    const int srow = (wave << 5) + (lane >> 2);
    const int selem = (lane & 3) * 8;
    const unsigned short* gA = A + (size_t)(m0 + srow) * DI_ + kbase + selem;
    const unsigned short* gB = W + (size_t)srow * DI_ + kbase + selem;
    unsigned short* lA = As + (wave << 5) * 32;
    unsigned short* lB = Bs + (wave << 5) * 32;

    f32x4 acc[4][3];
    #pragma unroll
    for (int i = 0; i < 4; ++i)
        #pragma unroll
        for (int j = 0; j < 3; ++j)
            acc[i][j] = (f32x4){0.f, 0.f, 0.f, 0.f};

    const int fr = lane & 15;
    const int fq = lane >> 4;
    const int aoff = (wm + fr) * 32 + fq * 8;
    const int boff = (wn + fr) * 32 + fq * 8;

    #pragma unroll
    for (int kk = 0; kk < 4; ++kk) {
        async16(gA, lA);
        async16(gA + (size_t)16 * DI_, lA + 16 * 32);
        if (wave < 3) {
            async16(gB, lB);
            async16(gB + (size_t)16 * DI_, lB + 16 * 32);
        }
        gA += 32; gB += 32;
        __syncthreads();
        bf16x8 af[4], bf[3];
        #pragma unroll
        for (int i = 0; i < 4; ++i) af[i] = *(const bf16x8*)&As[aoff + i * 512];
        #pragma unroll
        for (int j = 0; j < 3; ++j) bf[j] = *(const bf16x8*)&Bs[boff + j * 512];
        #pragma unroll
        for (int i = 0; i < 4; ++i)
            #pragma unroll
            for (int j = 0; j < 3; ++j)
                acc[i][j] = __builtin_amdgcn_mfma_f32_16x16x32_bf16(
                    af[i], bf[j], acc[i][j], 0, 0, 0);
        __syncthreads();
    }

    float* Pb = P + ((size_t)blockIdx.x * M_ + m0) * 96;
    #pragma unroll
    for (int i = 0; i < 4; ++i) {
        const int m = wm + i * 16 + fq * 4;
        #pragma unroll
        for (int j = 0; j < 3; ++j) {
            const int n = wn + j * 16 + fr;
            #pragma unroll
            for (int r = 0; r < 4; ++r)
                Pb[(size_t)(m + r) * 96 + n] = acc[i][j][r];
        }
    }
}

// reduce partials; emit dtr_bf [m][64] plus TRANSPOSED scan streams
// Bt[s][m], Ct[s][m] (s in 0..15).
__global__ __launch_bounds__(256) void xproj_reduce_kernel(
    const float* __restrict__ P, float* __restrict__ Bt, float* __restrict__ Ct,
    unsigned short* __restrict__ dtr_bf)
{
    const int i = blockIdx.x * 256 + threadIdx.x;
    if (i >= M_ * 96) return;
    float s = 0.f;
    #pragma unroll
    for (int ks = 0; ks < XKS; ++ks) s += P[(size_t)ks * (M_ * 96) + i];
    const int m = i / 96;
    const int n = i - m * 96;
    if (n < DR_)            dtr_bf[(size_t)m * DR_ + n] = bf16_rne(s);
    else if (n < DR_ + DS_) Bt[(size_t)(n - DR_) * M_ + m] = s;
    else                    Ct[(size_t)(n - DR_ - DS_) * M_ + m] = s;
}

// fp32 -> bf16 (RNE), vectorized x4
__global__ __launch_bounds__(256) void cvt_bf16_kernel(
    const float* __restrict__ in, unsigned short* __restrict__ out, int n4)
{
    const int i = blockIdx.x * 256 + threadIdx.x;
    if (i >= n4) return;
    const float4 v = ((const float4*)in)[i];
    ushort4 o;
    o.x = bf16_rne(v.x); o.y = bf16_rne(v.y);
    o.z = bf16_rne(v.z); o.w = bf16_rne(v.w);
    ((ushort4*)out)[i] = o;
}

// three conversions in one launch (in_proj + x_proj + dt_proj weights)
__global__ __launch_bounds__(256) void cvt3_kernel(
    const float* __restrict__ s0, unsigned short* __restrict__ d0, int n0,
    const float* __restrict__ s1, unsigned short* __restrict__ d1, int n1,
    const float* __restrict__ s2, unsigned short* __restrict__ d2, int n2)
{
    const int i = blockIdx.x * 256 + threadIdx.x;
    const float* s; unsigned short* d; int off;
    if (i < n0)           { s = s0; d = d0; off = i; }
    else if (i < n0 + n1) { s = s1; d = d1; off = i - n0; }
    else if (i < n0 + n1 + n2) { s = s2; d = d2; off = i - n0 - n1; }
    else return;
    const float4 v = ((const float4*)s)[off];
    ushort4 o;
    o.x = bf16_rne(v.x); o.y = bf16_rne(v.y);
    o.z = bf16_rne(v.z); o.w = bf16_rne(v.w);
    ((ushort4*)d)[off] = o;
}

// fp32 [K][N] (k-major) -> bf16 [N][K] (n-major) transpose+convert, 64x64 tile
__global__ __launch_bounds__(256) void cvt_transpose_kernel(
    const float* __restrict__ in, unsigned short* __restrict__ out, int K, int N)
{
    __shared__ float t[64][65];
    const int k0 = blockIdx.x * 64;
    const int n0 = blockIdx.y * 64;
    const int tx = threadIdx.x & 63;
    const int ty = threadIdx.x >> 6;
    #pragma unroll
    for (int j = 0; j < 16; ++j) {
        const int kk = ty * 16 + j;
        t[kk][tx] = in[(size_t)(k0 + kk) * N + n0 + tx];
    }
    __syncthreads();
    #pragma unroll
    for (int j = 0; j < 16; ++j) {
        const int nn = ty * 16 + j;
        out[(size_t)(n0 + nn) * K + k0 + tx] = bf16_rne(t[tx][nn]);
    }
}

// prepend split-K reduces (MN = 128*1024 = 131072)
__global__ __launch_bounds__(256) void reduce3_silu_bf16_kernel(
    const float* __restrict__ P, unsigned short* __restrict__ o)
{
    const int i = blockIdx.x * 256 + threadIdx.x;
    const float s = P[i] + P[131072 + i] + P[262144 + i];
    o[i] = bf16_rne(silu_f(s));
}
__global__ __launch_bounds__(256) void reduce4_fp32_kernel(
    const float* __restrict__ P, float* __restrict__ o)
{
    const int i = blockIdx.x * 256 + threadIdx.x;
    o[i] = P[i] + P[131072 + i] + P[262144 + i] + P[393216 + i];
}

// h[b*T+t, :] = (t < P) ? p[b*P+t, :] : x[b*S + (t-P), :]
__global__ __launch_bounds__(256) void assemble_h_kernel(
    const float* __restrict__ p, const float* __restrict__ x, float* __restrict__ h)
{
    const int idx = blockIdx.x * 256 + threadIdx.x;
    const int r = idx >> 8;
    const int c = idx & 255;
    const int b = r / T_;
    const int t = r - b * T_;
    float4 v;
    if (t < P_) v = ((const float4*)p)[(size_t)(b * P_ + t) * 256 + c];
    else        v = ((const float4*)x)[(size_t)(b * S_ + (t - P_)) * 256 + c];
    ((float4*)h)[idx] = v;
}

// rmsnorm -> bf16 output (feeds in_proj MFMA). one block per row.
__global__ __launch_bounds__(256) void rmsnorm_bf16_kernel(
    const float* __restrict__ x, const float* __restrict__ w,
    unsigned short* __restrict__ outb)
{
    const int r = blockIdx.x;
    const float4 v = ((const float4*)(x + (size_t)r * D_))[threadIdx.x];
    float ss = v.x * v.x + v.y * v.y + v.z * v.z + v.w * v.w;
    ss += __shfl_xor(ss, 32, 64);
    ss += __shfl_xor(ss, 16, 64);
    ss += __shfl_xor(ss, 8, 64);
    ss += __shfl_xor(ss, 4, 64);
    ss += __shfl_xor(ss, 2, 64);
    ss += __shfl_xor(ss, 1, 64);
    __shared__ float red[4];
    if ((threadIdx.x & 63) == 0) red[threadIdx.x >> 6] = ss;
    __syncthreads();
    const float tot = red[0] + red[1] + red[2] + red[3];
    const float scale = rsqrtf(tot * (1.f / D_) + 1e-5f);
    const float4 wv = ((const float4*)w)[threadIdx.x];
    ushort4 o;
    o.x = bf16_rne(v.x * scale * wv.x);
    o.y = bf16_rne(v.y * scale * wv.y);
    o.z = bf16_rne(v.z * scale * wv.z);
    o.w = bf16_rne(v.w * scale * wv.w);
    ((ushort4*)(outb + (size_t)r * D_))[threadIdx.x] = o;
}

// final rmsnorm (fp32 out): rows over B*S; reads h[b*T+P+s]
__global__ __launch_bounds__(256) void final_rmsnorm_kernel(
    const float* __restrict__ h, const float* __restrict__ w, float* __restrict__ out)
{
    const int r = blockIdx.x;
    const int b = r / S_;
    const int s = r - b * S_;
    const int hr = b * T_ + P_ + s;
    const float4 v = ((const float4*)(h + (size_t)hr * D_))[threadIdx.x];
    float ss = v.x * v.x + v.y * v.y + v.z * v.z + v.w * v.w;
    ss += __shfl_xor(ss, 32, 64);
    ss += __shfl_xor(ss, 16, 64);
    ss += __shfl_xor(ss, 8, 64);
    ss += __shfl_xor(ss, 4, 64);
    ss += __shfl_xor(ss, 2, 64);
    ss += __shfl_xor(ss, 1, 64);
    __shared__ float red[4];
    if ((threadIdx.x & 63) == 0) red[threadIdx.x >> 6] = ss;
    __syncthreads();
    const float tot = red[0] + red[1] + red[2] + red[3];
    const float scale = rsqrtf(tot * (1.f / D_) + 1e-5f);
    const float4 wv = ((const float4*)w)[threadIdx.x];
    float4 o;
    o.x = v.x * scale * wv.x; o.y = v.y * scale * wv.y;
    o.z = v.z * scale * wv.z; o.w = v.w * scale * wv.w;
    ((float4*)(out + (size_t)r * D_))[threadIdx.x] = o;
}

// ---------------------------------------------------------------------------
// Fused causal depthwise conv (DC=4) + bias + silu + transpose, PLUS
// silu(z) transposed stream. Outputs:
//   xib  [r][e] bf16  (x_proj MFMA operand)
//   xit  [e][r] fp32  (scan u stream)
//   szt  [e][r] fp32  (scan gate stream = silu(z))
// Tile: 64 r x 64 e. Batch boundary is tile-aligned (576 % 64 == 0).
// ---------------------------------------------------------------------------
__global__ __launch_bounds__(256) void conv_transpose_kernel(
    const float* __restrict__ xz, const float* __restrict__ cw,
    const float* __restrict__ cb, unsigned short* __restrict__ xib,
    float* __restrict__ xit, float* __restrict__ szt)
{
    __shared__ float xs[68][64];    // rows r0-3 .. r0+63 (67 used)
    __shared__ float tt[64][65];    // transpose staging, padded
    const int tid = threadIdx.x;
    const int tx = tid & 63;
    const int ty = tid >> 6;        // 0..3
    const int r0 = blockIdx.x * 64;
    const int e0 = blockIdx.y * 64;
    const int bt0 = (r0 / T_) * T_; // batch start row

    for (int j = ty; j < 67; j += 4) {
        const int r = r0 + j - 3;
        xs[j][tx] = (r >= bt0) ? xz[(size_t)r * (2 * DI_) + e0 + tx] : 0.f;
    }
    __syncthreads();
    const float4 w = *(const float4*)(cw + (size_t)(e0 + tx) * 4);
    const float bias = cb[e0 + tx];
    #pragma unroll
    for (int j = 0; j < 16; ++j) {
        const int rl = ty * 16 + j;
        float v = bias;
        v = fmaf(w.x, xs[rl + 0][tx], v);   // x[r-3]
        v = fmaf(w.y, xs[rl + 1][tx], v);   // x[r-2]
        v = fmaf(w.z, xs[rl + 2][tx], v);   // x[r-1]
        v = fmaf(w.w, xs[rl + 3][tx], v);   // x[r]
        const float o = silu_f(v);
        xib[(size_t)(r0 + rl) * DI_ + e0 + tx] = bf16_rne(o);
        tt[rl][tx] = o;
    }
    __syncthreads();
    #pragma unroll
    for (int j = 0; j < 16; ++j) {
        const int c = ty * 16 + j;
        xit[(size_t)(e0 + c) * M_ + r0 + tx] = tt[tx][c];
    }
    __syncthreads();
    // z half -> silu -> transpose
    #pragma unroll
    for (int j = 0; j < 16; ++j) {
        const int rl = ty * 16 + j;
        tt[rl][tx] = silu_f(xz[(size_t)(r0 + rl) * (2 * DI_) + DI_ + e0 + tx]);
    }
    __syncthreads();
    #pragma unroll
    for (int j = 0; j < 16; ++j) {
        const int c = ty * 16 + j;
        szt[(size_t)(e0 + c) * M_ + r0 + tx] = tt[tx][c];
    }
}

// ---------------------------------------------------------------------------
// Chunked selective scan, float4 x4 time-unroll. All operand streams are
// contiguous in t: dt_t/xi_t/szt [e][m], Bt/Ct [s][m].
// ---------------------------------------------------------------------------
__global__ __launch_bounds__(256) void scan_chunk1_kernel(
    const float* __restrict__ dt_t,  // [DI, M]
    const float* __restrict__ Bt,    // [16, M]
    const float* __restrict__ xi_t,  // [DI, M]
    const float* __restrict__ A_log,
    float* __restrict__ Ap, float* __restrict__ Hp)
{
    const int g = blockIdx.x * 256 + threadIdx.x;
    const int s = g & (DS_ - 1);
    const int e = (g >> 4) & (DI_ - 1);
    const int b = (g >> 15) & (B_ - 1);
    const int c = g >> 16;
    const float Aval = -__expf(A_log[(size_t)e * DS_ + s]);
    float ap = 1.f, hp = 0.f;
    const int r0 = b * T_ + c * CCH;
    const float4* dtp = (const float4*)(dt_t + (size_t)e * M_ + r0);
    const float4* xip = (const float4*)(xi_t + (size_t)e * M_ + r0);
    const float4* bp  = (const float4*)(Bt   + (size_t)s * M_ + r0);
    #pragma unroll 4
    for (int q = 0; q < CCH / 4; ++q) {
        const float4 dtq = dtp[q];
        const float4 uq  = xip[q];
        const float4 bq  = bp[q];
        const float* dta = &dtq.x;
        const float* ua  = &uq.x;
        const float* ba  = &bq.x;
        #pragma unroll
        for (int j = 0; j < 4; ++j) {
            const float dtv = dta[j];
            const float da  = __expf(dtv * Aval);
            ap *= da;
            hp = fmaf(da, hp, dtv * ba[j] * ua[j]);
        }
    }
    const size_t o = (((size_t)c * B_ + b) * DI_ + e) * DS_ + s;
    Ap[o] = ap; Hp[o] = hp;
}

__global__ __launch_bounds__(256) void scan_chunk2_kernel(
    float* __restrict__ Ap, float* __restrict__ Hp)
{
    const int g = blockIdx.x * 256 + threadIdx.x;
    float h = 0.f;
    #pragma unroll
    for (int c = 0; c < NC; ++c) {
        const size_t o = (size_t)c * (B_ * DI_ * DS_) + g;
        const float ap = Ap[o];
        const float hp = Hp[o];
        Hp[o] = h;
        h = fmaf(ap, h, hp);
    }
}

__global__ __launch_bounds__(256) void scan_chunk3_kernel(
    const float* __restrict__ dt_t,  // [DI, M]
    const float* __restrict__ Bt,    // [16, M]
    const float* __restrict__ Ct,    // [16, M]
    const float* __restrict__ xi_t,  // [DI, M]
    const float* __restrict__ szt,   // [DI, M] silu(z)
    const float* __restrict__ A_log, const float* __restrict__ Dp,
    const float* __restrict__ Hin, unsigned short* __restrict__ y)
{
    const int g = blockIdx.x * 256 + threadIdx.x;
    const int s = g & (DS_ - 1);
    const int e = (g >> 4) & (DI_ - 1);
    const int b = (g >> 15) & (B_ - 1);
    const int c = g >> 16;
    const float Aval = -__expf(A_log[(size_t)e * DS_ + s]);
    const float dpe = Dp[e];
    float h = Hin[(((size_t)c * B_ + b) * DI_ + e) * DS_ + s];
    const int r0 = b * T_ + c * CCH;
    const float4* dtp = (const float4*)(dt_t + (size_t)e * M_ + r0);
    const float4* xip = (const float4*)(xi_t + (size_t)e * M_ + r0);
    const float4* szp = (const float4*)(szt  + (size_t)e * M_ + r0);
    const float4* bp  = (const float4*)(Bt   + (size_t)s * M_ + r0);
    const float4* cp  = (const float4*)(Ct   + (size_t)s * M_ + r0);
    unsigned short* yp = y + (size_t)r0 * DI_ + e;
    #pragma unroll 4
    for (int q = 0; q < CCH / 4; ++q) {
        const float4 dtq = dtp[q];
        const float4 uq  = xip[q];
        const float4 bq  = bp[q];
        const float4 cq  = cp[q];
        const float4 szq = szp[q];
        const float* dta = &dtq.x;
        const float* ua  = &uq.x;
        const float* ba  = &bq.x;
        const float* ca  = &cq.x;
        const float* sza = &szq.x;
        #pragma unroll
        for (int j = 0; j < 4; ++j) {
            const float dtv = dta[j];
            const float u   = ua[j];
            const float da  = __expf(dtv * Aval);
            h = fmaf(da, h, dtv * ba[j] * u);
            const float contrib = row_reduce16(h * ca[j]);  // sum -> lane 15
            const float yv = fmaf(u, dpe, contrib) * sza[j];
            if (s == 15)
                yp[(size_t)(q * 4 + j) * DI_] = bf16_rne(yv);
        }
    }
}

extern "C" void kernel_launch(void* const* d_in, const int* in_sizes, int n_in,
                              void* d_out, int out_size, void* d_ws, size_t ws_size,
                              hipStream_t stream)
{
    const float* x       = (const float*)d_in[0];
    const float* pc      = (const float*)d_in[1];
    const float* pre_w1  = (const float*)d_in[2];
    const float* pre_w2  = (const float*)d_in[3];
    const float* norm_w  = (const float*)d_in[4];
    const float* ip_w    = (const float*)d_in[5];
    const float* conv_w  = (const float*)d_in[6];
    const float* conv_b  = (const float*)d_in[7];
    const float* xp_w    = (const float*)d_in[8];
    const float* dtp_w   = (const float*)d_in[9];
    const float* dtp_b   = (const float*)d_in[10];
    const float* A_log   = (const float*)d_in[11];
    const float* D_param = (const float*)d_in[12];
    const float* op_w    = (const float*)d_in[13];
    const float* fnw     = (const float*)d_in[14];
    float* out = (float*)d_out;

    float* ws = (float*)d_ws;
    float* h    = ws;  ws += (size_t)M_ * D_;            // fp32 residual
    float* xz   = ws;  ws += (size_t)M_ * 2 * DI_;       // in_proj out
    float* xi_t = ws;  ws += (size_t)M_ * DI_;           // conv out, [DI][M]
    float* szt  = ws;  ws += (size_t)M_ * DI_;           // silu(z), [DI][M]
    float* dtb  = ws;  ws += (size_t)M_ * DI_;           // dt, [DI][M]
    float* Ap   = ws;  ws += (size_t)NC * B_ * DI_ * DS_;
    float* Hp   = ws;  ws += (size_t)NC * B_ * DI_ * DS_;
    float* Pbuf = ws;  ws += (size_t)XKS * M_ * 96;      // x_proj / prepend partials
    float* Bt   = ws;  ws += (size_t)DS_ * M_;           // B stream [s][m]
    float* Ct   = ws;  ws += (size_t)DS_ * M_;           // C stream [s][m]
    unsigned short* xn_bf  = (unsigned short*)ws;  ws += (size_t)M_ * D_ / 2;
    unsigned short* yb_bf  = (unsigned short*)ws;  ws += (size_t)M_ * DI_ / 2;
    unsigned short* xi_bf  = (unsigned short*)ws;  ws += (size_t)M_ * DI_ / 2;
    unsigned short* dtr_bf = (unsigned short*)ws;  ws += (size_t)M_ * DR_ / 2;
    unsigned short* wbuf   = (unsigned short*)ws;  ws += (size_t)2 * DI_ * D_ / 2;
    unsigned short* xpw_bf = (unsigned short*)ws;  ws += (size_t)96 * DI_ / 2;
    unsigned short* dtpw_bf= (unsigned short*)ws;  ws += (size_t)DI_ * DR_ / 2;

    // prepend-phase aliases (all dead once the layer loop starts):
    unsigned short* pc_bf   = xi_bf;                    // 128*768 shorts
    unsigned short* w1t_bf  = wbuf;                     // [1024][768]
    unsigned short* w2t_bf  = wbuf + (size_t)D_ * PCD_; // [1024][1024]
    unsigned short* tmp1_bf = xn_bf;                    // [128][1024]
    float*          tmp2    = xz;                       // [128][1024] fp32

    const dim3 blk(256);

    // ---- prepend embed (MFMA path): silu(pc @ w1) @ w2 ----
    cvt_bf16_kernel<<<dim3(B_ * P_ * PCD_ / 4 / 256), blk, 0, stream>>>(
        pc, pc_bf, B_ * P_ * PCD_ / 4);
    cvt_transpose_kernel<<<dim3(PCD_ / 64, D_ / 64), blk, 0, stream>>>(
        pre_w1, w1t_bf, PCD_, D_);
    cvt_transpose_kernel<<<dim3(D_ / 64, D_ / 64), blk, 0, stream>>>(
        pre_w2, w2t_bf, D_, D_);
    // GEMM1: [128, 1024, K=768], split-K 3 -> partials, silu-reduce -> bf16
    gemm_mfma_kernel<6><<<dim3(D_ / 128, 1, 3), blk, 0, stream>>>(
        pc_bf, w1t_bf, Pbuf, nullptr, B_ * P_, D_, PCD_, PCD_ / 3);
    reduce3_silu_bf16_kernel<<<dim3(B_ * P_ * D_ / 256), blk, 0, stream>>>(
        Pbuf, tmp1_bf);
    // GEMM2: [128, 1024, K=1024], split-K 4 -> partials, reduce -> fp32
    gemm_mfma_kernel<6><<<dim3(D_ / 128, 1, 4), blk, 0, stream>>>(
        tmp1_bf, w2t_bf, Pbuf, nullptr, B_ * P_, D_, D_, D_ / 4);
    reduce4_fp32_kernel<<<dim3(B_ * P_ * D_ / 256), blk, 0, stream>>>(Pbuf, tmp2);
    assemble_h_kernel<<<dim3(M_ * D_ / 4 / 256), blk, 0, stream>>>(tmp2, x, h);

    const int n_ip  = 2 * DI_ * D_ / 4;
    const int n_xp  = 96 * DI_ / 4;
    const int n_dtp = DI_ * DR_ / 4;

    for (int l = 0; l < L_; ++l) {
        rmsnorm_bf16_kernel<<<dim3(M_), blk, 0, stream>>>(
            h, norm_w + (size_t)l * D_, xn_bf);
        cvt3_kernel<<<dim3((n_ip + n_xp + n_dtp + 255) / 256), blk, 0, stream>>>(
            ip_w + (size_t)l * 2 * DI_ * D_, wbuf, n_ip,
            xp_w + (size_t)l * 96 * DI_, xpw_bf, n_xp,
            dtp_w + (size_t)l * DI_ * DR_, dtpw_bf, n_dtp);
        // in_proj (MFMA): xz = xn @ ip_w^T   [1152, 4096, K=1024]
        gemm_mfma_kernel<0><<<dim3(2 * DI_ / 128, M_ / 128, 1), blk, 0, stream>>>(
            xn_bf, wbuf, xz, nullptr, M_, 2 * DI_, D_, D_);
        // conv + silu + transposes: xi_bf [r][e], xi_t [e][r], szt [e][r]
        conv_transpose_kernel<<<dim3(M_ / 64, DI_ / 64), blk, 0, stream>>>(
            xz, conv_w + (size_t)l * DI_ * DC_, conv_b + (size_t)l * DI_,
            xi_bf, xi_t, szt);
        // x_proj (split-K MFMA) + reduce -> dtr_bf, Bt, Ct
        xproj_mfma_kernel<<<dim3(XKS, M_ / 128), blk, 0, stream>>>(
            xi_bf, xpw_bf, Pbuf);
        xproj_reduce_kernel<<<dim3((M_ * 96 + 255) / 256), blk, 0, stream>>>(
            Pbuf, Bt, Ct, dtr_bf);
        // dt_proj (MFMA, transposed softplus store): dtb[e][m]
        gemm_mfma_kernel<5><<<dim3(DI_ / 128, M_ / 128, 1), blk, 0, stream>>>(
            dtr_bf, dtpw_bf, dtb, dtp_b + (size_t)l * DI_, M_, DI_, DR_, DR_);
        // chunked scan
        scan_chunk1_kernel<<<dim3(NC * B_ * DI_ * DS_ / 256), blk, 0, stream>>>(
            dtb, Bt, xi_t, A_log + (size_t)l * DI_ * DS_, Ap, Hp);
        scan_chunk2_kernel<<<dim3(B_ * DI_ * DS_ / 256), blk, 0, stream>>>(Ap, Hp);
        scan_chunk3_kernel<<<dim3(NC * B_ * DI_ * DS_ / 256), blk, 0, stream>>>(
            dtb, Bt, Ct, xi_t, szt, A_log + (size_t)l * DI_ * DS_,
            D_param + (size_t)l * DI_, Hp, yb_bf);
        // out_proj weights -> bf16 (reuses wbuf; in_proj GEMM done)
        cvt_bf16_kernel<<<dim3(D_ * DI_ / 4 / 256), blk, 0, stream>>>(
            op_w + (size_t)l * D_ * DI_, wbuf, D_ * DI_ / 4);
        // out_proj + residual (split-K=2, atomicAdd): h += yb @ op_w^T
        gemm_mfma_kernel<4><<<dim3(D_ / 128, M_ / 128, 2), blk, 0, stream>>>(
            yb_bf, wbuf, h, nullptr, M_, D_, DI_, DI_ / 2);
    }

    final_rmsnorm_kernel<<<dim3(B_ * S_), blk, 0, stream>>>(h, fnw, out);
}

// Round 8
// 991.575 us; speedup vs baseline: 3.7797x; 1.0835x over previous
//
#include <hip/hip_runtime.h>
#include <math.h>

#define B_ 2
#define S_ 512
#define P_ 64
#define T_ 576          // P_+S_
#define D_ 1024
#define L_ 4
#define DI_ 2048
#define DS_ 16
#define DC_ 4
#define DR_ 64
#define PCD_ 768
#define M_ (B_*T_)      // 1152
#define CCH 64          // scan chunk length
#define NC (T_/CCH)     // 9 chunks
#define XKS 16          // x_proj K-splits (KC = 2048/16 = 128)

typedef __attribute__((ext_vector_type(8))) short bf16x8;
typedef __attribute__((ext_vector_type(4))) float f32x4;

__device__ __forceinline__ float silu_f(float v) { return v / (1.f + __expf(-v)); }
__device__ __forceinline__ float softplus_f(float v) {
    return fmaxf(v, 0.f) + log1pf(__expf(-fabsf(v)));
}
__device__ __forceinline__ unsigned short bf16_rne(float x) {
    unsigned int b = __float_as_uint(x);
    b += 0x7fffu + ((b >> 16) & 1u);
    return (unsigned short)(b >> 16);
}

// sum over each 16-lane row via DPP row_shr (full-rate VALU, no LDS pipe).
// Result lands in lane 15 of each row of 16.
__device__ __forceinline__ float row_reduce16(float x) {
    x += __int_as_float(__builtin_amdgcn_update_dpp(
        0, __float_as_int(x), 0x111, 0xf, 0xf, true)); // row_shr:1
    x += __int_as_float(__builtin_amdgcn_update_dpp(
        0, __float_as_int(x), 0x112, 0xf, 0xf, true)); // row_shr:2
    x += __int_as_float(__builtin_amdgcn_update_dpp(
        0, __float_as_int(x), 0x114, 0xf, 0xf, true)); // row_shr:4
    x += __int_as_float(__builtin_amdgcn_update_dpp(
        0, __float_as_int(x), 0x118, 0xf, 0xf, true)); // row_shr:8
    return x;
}

typedef const void __attribute__((address_space(1)))* gas_t;
typedef void __attribute__((address_space(3)))* las_t;
__device__ __forceinline__ void async16(const void* g, void* l) {
    __builtin_amdgcn_global_load_lds((gas_t)g, (las_t)l, 16, 0, 0);
}

// ---------------------------------------------------------------------------
// bf16 MFMA GEMM (m97 structure): C[m,n] (+)= sum_k A[m,k]*W[n,k], fp32 out.
// EPI: 0 = store, 5 = softplus(v+bias[n]) stored TRANSPOSED to C[n*M + m],
//      6 = split-K partial store to C[(z*M + m)*N + n] (deterministic
//      reduce kernel follows; NO atomics — device-scope atomicAdd with
//      colliding z-splits ping-pongs L2 lines across XCDs).
// ---------------------------------------------------------------------------
template<int EPI>
__global__ __launch_bounds__(256) void gemm_mfma_kernel(
    const unsigned short* __restrict__ A, const unsigned short* __restrict__ W,
    float* __restrict__ C, const float* __restrict__ bias,
    int M, int N, int K, int Kchunk)
{
    __shared__ unsigned short As[128 * 32];
    __shared__ unsigned short Bs[128 * 32];
    const int tid = threadIdx.x;
    const int wave = tid >> 6;
    const int lane = tid & 63;
    const int m0 = blockIdx.y * 128, n0 = blockIdx.x * 128;
    const int kbase = blockIdx.z * Kchunk;
    const int wm = (wave >> 1) * 64, wn = (wave & 1) * 64;

    const int srow = (wave << 5) + (lane >> 2);
    const int selem = (lane & 3) * 8;
    const unsigned short* gA = A + (size_t)(m0 + srow) * K + kbase + selem;
    const unsigned short* gB = W + (size_t)(n0 + srow) * K + kbase + selem;
    unsigned short* lA = As + (wave << 5) * 32;
    unsigned short* lB = Bs + (wave << 5) * 32;

    f32x4 acc[4][4];
    #pragma unroll
    for (int i = 0; i < 4; ++i)
        #pragma unroll
        for (int j = 0; j < 4; ++j)
            acc[i][j] = (f32x4){0.f, 0.f, 0.f, 0.f};

    const int fr = lane & 15;
    const int fq = lane >> 4;
    const int aoff = (wm + fr) * 32 + fq * 8;
    const int boff = (wn + fr) * 32 + fq * 8;

    for (int k0 = 0; k0 < Kchunk; k0 += 32) {
        async16(gA, lA);
        async16(gA + (size_t)16 * K, lA + 16 * 32);
        async16(gB, lB);
        async16(gB + (size_t)16 * K, lB + 16 * 32);
        gA += 32; gB += 32;
        __syncthreads();
        bf16x8 af[4], bf[4];
        #pragma unroll
        for (int i = 0; i < 4; ++i) af[i] = *(const bf16x8*)&As[aoff + i * 512];
        #pragma unroll
        for (int j = 0; j < 4; ++j) bf[j] = *(const bf16x8*)&Bs[boff + j * 512];
        #pragma unroll
        for (int i = 0; i < 4; ++i)
            #pragma unroll
            for (int j = 0; j < 4; ++j)
                acc[i][j] = __builtin_amdgcn_mfma_f32_16x16x32_bf16(
                    af[i], bf[j], acc[i][j], 0, 0, 0);
        __syncthreads();
    }

    // C/D layout (m89-verified): col = lane&15, row = (lane>>4)*4 + reg
    #pragma unroll
    for (int i = 0; i < 4; ++i) {
        const int m = m0 + wm + i * 16 + fq * 4;
        #pragma unroll
        for (int j = 0; j < 4; ++j) {
            const int n = n0 + wn + j * 16 + fr;
            if (EPI == 5) {
                const float bb = bias[n];
                float4 o;
                o.x = softplus_f(acc[i][j][0] + bb);
                o.y = softplus_f(acc[i][j][1] + bb);
                o.z = softplus_f(acc[i][j][2] + bb);
                o.w = softplus_f(acc[i][j][3] + bb);
                *(float4*)(C + (size_t)n * M + m) = o;   // transposed, m%4==0
            } else if (EPI == 6) {
                float* p = C + ((size_t)blockIdx.z * M + m) * N + n;
                #pragma unroll
                for (int r = 0; r < 4; ++r)
                    p[(size_t)r * N] = acc[i][j][r];
            } else {
                float* p = C + (size_t)m * N + n;
                #pragma unroll
                for (int r = 0; r < 4; ++r)
                    p[(size_t)r * N] = acc[i][j][r];
            }
        }
    }
}

// ---------------------------------------------------------------------------
// x_proj split-K MFMA: P[ks][m][96] = xi_bf[m, ks*128:(ks+1)*128] @ W[96,...]^T
// ---------------------------------------------------------------------------
__global__ __launch_bounds__(256) void xproj_mfma_kernel(
    const unsigned short* __restrict__ A,   // [M, 2048] bf16
    const unsigned short* __restrict__ W,   // [96, 2048] bf16
    float* __restrict__ P)                  // [XKS, M, 96]
{
    __shared__ unsigned short As[128 * 32];
    __shared__ unsigned short Bs[96 * 32];
    const int tid = threadIdx.x;
    const int wave = tid >> 6;
    const int lane = tid & 63;
    const int m0 = blockIdx.y * 128;
    const int kbase = blockIdx.x * (DI_ / XKS);   // 128
    const int wm = (wave >> 1) * 64, wn = (wave & 1) * 48;

    const int srow = (wave << 5) + (lane >> 2);
    const int selem = (lane & 3) * 8;
    const unsigned short* gA = A + (size_t)(m0 + srow) * DI_ + kbase + selem;
    const unsigned short* gB = W + (size_t)srow * DI_ + kbase + selem;
    unsigned short* lA = As + (wave << 5) * 32;
    unsigned short* lB = Bs + (wave << 5) * 32;

    f32x4 acc[4][3];
    #pragma unroll
    for (int i = 0; i < 4; ++i)
        #pragma unroll
        for (int j = 0; j < 3; ++j)
            acc[i][j] = (f32x4){0.f, 0.f, 0.f, 0.f};

    const int fr = lane & 15;
    const int fq = lane >> 4;
    const int aoff = (wm + fr) * 32 + fq * 8;
    const int boff = (wn + fr) * 32 + fq * 8;

    #pragma unroll
    for (int kk = 0; kk < 4; ++kk) {
        async16(gA, lA);
        async16(gA + (size_t)16 * DI_, lA + 16 * 32);
        if (wave < 3) {
            async16(gB, lB);
            async16(gB + (size_t)16 * DI_, lB + 16 * 32);
        }
        gA += 32; gB += 32;
        __syncthreads();
        bf16x8 af[4], bf[3];
        #pragma unroll
        for (int i = 0; i < 4; ++i) af[i] = *(const bf16x8*)&As[aoff + i * 512];
        #pragma unroll
        for (int j = 0; j < 3; ++j) bf[j] = *(const bf16x8*)&Bs[boff + j * 512];
        #pragma unroll
        for (int i = 0; i < 4; ++i)
            #pragma unroll
            for (int j = 0; j < 3; ++j)
                acc[i][j] = __builtin_amdgcn_mfma_f32_16x16x32_bf16(
                    af[i], bf[j], acc[i][j], 0, 0, 0);
        __syncthreads();
    }

    float* Pb = P + ((size_t)blockIdx.x * M_ + m0) * 96;
    #pragma unroll
    for (int i = 0; i < 4; ++i) {
        const int m = wm + i * 16 + fq * 4;
        #pragma unroll
        for (int j = 0; j < 3; ++j) {
            const int n = wn + j * 16 + fr;
            #pragma unroll
            for (int r = 0; r < 4; ++r)
                Pb[(size_t)(m + r) * 96 + n] = acc[i][j][r];
        }
    }
}

// reduce partials; emit dtr_bf [m][64] plus TRANSPOSED scan streams
// Bt[s][m], Ct[s][m] (s in 0..15).
__global__ __launch_bounds__(256) void xproj_reduce_kernel(
    const float* __restrict__ P, float* __restrict__ Bt, float* __restrict__ Ct,
    unsigned short* __restrict__ dtr_bf)
{
    const int i = blockIdx.x * 256 + threadIdx.x;
    if (i >= M_ * 96) return;
    float s = 0.f;
    #pragma unroll
    for (int ks = 0; ks < XKS; ++ks) s += P[(size_t)ks * (M_ * 96) + i];
    const int m = i / 96;
    const int n = i - m * 96;
    if (n < DR_)            dtr_bf[(size_t)m * DR_ + n] = bf16_rne(s);
    else if (n < DR_ + DS_) Bt[(size_t)(n - DR_) * M_ + m] = s;
    else                    Ct[(size_t)(n - DR_ - DS_) * M_ + m] = s;
}

// fp32 -> bf16 (RNE), vectorized x4
__global__ __launch_bounds__(256) void cvt_bf16_kernel(
    const float* __restrict__ in, unsigned short* __restrict__ out, int n4)
{
    const int i = blockIdx.x * 256 + threadIdx.x;
    if (i >= n4) return;
    const float4 v = ((const float4*)in)[i];
    ushort4 o;
    o.x = bf16_rne(v.x); o.y = bf16_rne(v.y);
    o.z = bf16_rne(v.z); o.w = bf16_rne(v.w);
    ((ushort4*)out)[i] = o;
}

// three conversions in one launch (in_proj + x_proj + dt_proj weights)
__global__ __launch_bounds__(256) void cvt3_kernel(
    const float* __restrict__ s0, unsigned short* __restrict__ d0, int n0,
    const float* __restrict__ s1, unsigned short* __restrict__ d1, int n1,
    const float* __restrict__ s2, unsigned short* __restrict__ d2, int n2)
{
    const int i = blockIdx.x * 256 + threadIdx.x;
    const float* s; unsigned short* d; int off;
    if (i < n0)           { s = s0; d = d0; off = i; }
    else if (i < n0 + n1) { s = s1; d = d1; off = i - n0; }
    else if (i < n0 + n1 + n2) { s = s2; d = d2; off = i - n0 - n1; }
    else return;
    const float4 v = ((const float4*)s)[off];
    ushort4 o;
    o.x = bf16_rne(v.x); o.y = bf16_rne(v.y);
    o.z = bf16_rne(v.z); o.w = bf16_rne(v.w);
    ((ushort4*)d)[off] = o;
}

// fp32 [K][N] (k-major) -> bf16 [N][K] (n-major) transpose+convert, 64x64 tile
__global__ __launch_bounds__(256) void cvt_transpose_kernel(
    const float* __restrict__ in, unsigned short* __restrict__ out, int K, int N)
{
    __shared__ float t[64][65];
    const int k0 = blockIdx.x * 64;
    const int n0 = blockIdx.y * 64;
    const int tx = threadIdx.x & 63;
    const int ty = threadIdx.x >> 6;
    #pragma unroll
    for (int j = 0; j < 16; ++j) {
        const int kk = ty * 16 + j;
        t[kk][tx] = in[(size_t)(k0 + kk) * N + n0 + tx];
    }
    __syncthreads();
    #pragma unroll
    for (int j = 0; j < 16; ++j) {
        const int nn = ty * 16 + j;
        out[(size_t)(n0 + nn) * K + k0 + tx] = bf16_rne(t[tx][nn]);
    }
}

// generalized split-K reduces (stride MN between partials)
__global__ __launch_bounds__(256) void reduce_silu_bf16_kernel(
    const float* __restrict__ P, unsigned short* __restrict__ o, int MN, int ns)
{
    const int i = blockIdx.x * 256 + threadIdx.x;
    if (i >= MN) return;
    float s = 0.f;
    for (int k = 0; k < ns; ++k) s += P[(size_t)k * MN + i];
    o[i] = bf16_rne(silu_f(s));
}
__global__ __launch_bounds__(256) void reduce_fp32_kernel(
    const float* __restrict__ P, float* __restrict__ o, int MN, int ns)
{
    const int i = blockIdx.x * 256 + threadIdx.x;
    if (i >= MN) return;
    float s = 0.f;
    for (int k = 0; k < ns; ++k) s += P[(size_t)k * MN + i];
    o[i] = s;
}

// out_proj split-K=2 reduce + residual add into h, float4 vectorized
__global__ __launch_bounds__(256) void outproj_reduce_kernel(
    const float* __restrict__ P, float* __restrict__ h)
{
    const int i = blockIdx.x * 256 + threadIdx.x;   // over M_*D_/4
    const float4 a = ((const float4*)P)[i];
    const float4 b = ((const float4*)P)[i + M_ * D_ / 4];
    float4 hv = ((float4*)h)[i];
    hv.x += a.x + b.x; hv.y += a.y + b.y;
    hv.z += a.z + b.z; hv.w += a.w + b.w;
    ((float4*)h)[i] = hv;
}

// h[b*T+t, :] = (t < P) ? p[b*P+t, :] : x[b*S + (t-P), :]
__global__ __launch_bounds__(256) void assemble_h_kernel(
    const float* __restrict__ p, const float* __restrict__ x, float* __restrict__ h)
{
    const int idx = blockIdx.x * 256 + threadIdx.x;
    const int r = idx >> 8;
    const int c = idx & 255;
    const int b = r / T_;
    const int t = r - b * T_;
    float4 v;
    if (t < P_) v = ((const float4*)p)[(size_t)(b * P_ + t) * 256 + c];
    else        v = ((const float4*)x)[(size_t)(b * S_ + (t - P_)) * 256 + c];
    ((float4*)h)[idx] = v;
}

// rmsnorm -> bf16 output (feeds in_proj MFMA). one block per row.
__global__ __launch_bounds__(256) void rmsnorm_bf16_kernel(
    const float* __restrict__ x, const float* __restrict__ w,
    unsigned short* __restrict__ outb)
{
    const int r = blockIdx.x;
    const float4 v = ((const float4*)(x + (size_t)r * D_))[threadIdx.x];
    float ss = v.x * v.x + v.y * v.y + v.z * v.z + v.w * v.w;
    ss += __shfl_xor(ss, 32, 64);
    ss += __shfl_xor(ss, 16, 64);
    ss += __shfl_xor(ss, 8, 64);
    ss += __shfl_xor(ss, 4, 64);
    ss += __shfl_xor(ss, 2, 64);
    ss += __shfl_xor(ss, 1, 64);
    __shared__ float red[4];
    if ((threadIdx.x & 63) == 0) red[threadIdx.x >> 6] = ss;
    __syncthreads();
    const float tot = red[0] + red[1] + red[2] + red[3];
    const float scale = rsqrtf(tot * (1.f / D_) + 1e-5f);
    const float4 wv = ((const float4*)w)[threadIdx.x];
    ushort4 o;
    o.x = bf16_rne(v.x * scale * wv.x);
    o.y = bf16_rne(v.y * scale * wv.y);
    o.z = bf16_rne(v.z * scale * wv.z);
    o.w = bf16_rne(v.w * scale * wv.w);
    ((ushort4*)(outb + (size_t)r * D_))[threadIdx.x] = o;
}

// final rmsnorm (fp32 out): rows over B*S; reads h[b*T+P+s]
__global__ __launch_bounds__(256) void final_rmsnorm_kernel(
    const float* __restrict__ h, const float* __restrict__ w, float* __restrict__ out)
{
    const int r = blockIdx.x;
    const int b = r / S_;
    const int s = r - b * S_;
    const int hr = b * T_ + P_ + s;
    const float4 v = ((const float4*)(h + (size_t)hr * D_))[threadIdx.x];
    float ss = v.x * v.x + v.y * v.y + v.z * v.z + v.w * v.w;
    ss += __shfl_xor(ss, 32, 64);
    ss += __shfl_xor(ss, 16, 64);
    ss += __shfl_xor(ss, 8, 64);
    ss += __shfl_xor(ss, 4, 64);
    ss += __shfl_xor(ss, 2, 64);
    ss += __shfl_xor(ss, 1, 64);
    __shared__ float red[4];
    if ((threadIdx.x & 63) == 0) red[threadIdx.x >> 6] = ss;
    __syncthreads();
    const float tot = red[0] + red[1] + red[2] + red[3];
    const float scale = rsqrtf(tot * (1.f / D_) + 1e-5f);
    const float4 wv = ((const float4*)w)[threadIdx.x];
    float4 o;
    o.x = v.x * scale * wv.x; o.y = v.y * scale * wv.y;
    o.z = v.z * scale * wv.z; o.w = v.w * scale * wv.w;
    ((float4*)(out + (size_t)r * D_))[threadIdx.x] = o;
}

// ---------------------------------------------------------------------------
// Fused causal depthwise conv (DC=4) + bias + silu + transpose, PLUS
// silu(z) transposed stream. Outputs:
//   xib  [r][e] bf16  (x_proj MFMA operand)
//   xit  [e][r] fp32  (scan u stream)
//   szt  [e][r] fp32  (scan gate stream = silu(z))
// Tile: 64 r x 64 e. Batch boundary is tile-aligned (576 % 64 == 0).
// ---------------------------------------------------------------------------
__global__ __launch_bounds__(256) void conv_transpose_kernel(
    const float* __restrict__ xz, const float* __restrict__ cw,
    const float* __restrict__ cb, unsigned short* __restrict__ xib,
    float* __restrict__ xit, float* __restrict__ szt)
{
    __shared__ float xs[68][64];    // rows r0-3 .. r0+63 (67 used)
    __shared__ float tt[64][65];    // transpose staging, padded
    const int tid = threadIdx.x;
    const int tx = tid & 63;
    const int ty = tid >> 6;        // 0..3
    const int r0 = blockIdx.x * 64;
    const int e0 = blockIdx.y * 64;
    const int bt0 = (r0 / T_) * T_; // batch start row

    for (int j = ty; j < 67; j += 4) {
        const int r = r0 + j - 3;
        xs[j][tx] = (r >= bt0) ? xz[(size_t)r * (2 * DI_) + e0 + tx] : 0.f;
    }
    __syncthreads();
    const float4 w = *(const float4*)(cw + (size_t)(e0 + tx) * 4);
    const float bias = cb[e0 + tx];
    #pragma unroll
    for (int j = 0; j < 16; ++j) {
        const int rl = ty * 16 + j;
        float v = bias;
        v = fmaf(w.x, xs[rl + 0][tx], v);   // x[r-3]
        v = fmaf(w.y, xs[rl + 1][tx], v);   // x[r-2]
        v = fmaf(w.z, xs[rl + 2][tx], v);   // x[r-1]
        v = fmaf(w.w, xs[rl + 3][tx], v);   // x[r]
        const float o = silu_f(v);
        xib[(size_t)(r0 + rl) * DI_ + e0 + tx] = bf16_rne(o);
        tt[rl][tx] = o;
    }
    __syncthreads();
    #pragma unroll
    for (int j = 0; j < 16; ++j) {
        const int c = ty * 16 + j;
        xit[(size_t)(e0 + c) * M_ + r0 + tx] = tt[tx][c];
    }
    __syncthreads();
    // z half -> silu -> transpose
    #pragma unroll
    for (int j = 0; j < 16; ++j) {
        const int rl = ty * 16 + j;
        tt[rl][tx] = silu_f(xz[(size_t)(r0 + rl) * (2 * DI_) + DI_ + e0 + tx]);
    }
    __syncthreads();
    #pragma unroll
    for (int j = 0; j < 16; ++j) {
        const int c = ty * 16 + j;
        szt[(size_t)(e0 + c) * M_ + r0 + tx] = tt[tx][c];
    }
}

// ---------------------------------------------------------------------------
// Chunked selective scan, float4 x4 time-unroll. All operand streams are
// contiguous in t: dt_t/xi_t/szt [e][m], Bt/Ct [s][m].
// ---------------------------------------------------------------------------
__global__ __launch_bounds__(256) void scan_chunk1_kernel(
    const float* __restrict__ dt_t,  // [DI, M]
    const float* __restrict__ Bt,    // [16, M]
    const float* __restrict__ xi_t,  // [DI, M]
    const float* __restrict__ A_log,
    float* __restrict__ Ap, float* __restrict__ Hp)
{
    const int g = blockIdx.x * 256 + threadIdx.x;
    const int s = g & (DS_ - 1);
    const int e = (g >> 4) & (DI_ - 1);
    const int b = (g >> 15) & (B_ - 1);
    const int c = g >> 16;
    const float Aval = -__expf(A_log[(size_t)e * DS_ + s]);
    float ap = 1.f, hp = 0.f;
    const int r0 = b * T_ + c * CCH;
    const float4* dtp = (const float4*)(dt_t + (size_t)e * M_ + r0);
    const float4* xip = (const float4*)(xi_t + (size_t)e * M_ + r0);
    const float4* bp  = (const float4*)(Bt   + (size_t)s * M_ + r0);
    #pragma unroll 4
    for (int q = 0; q < CCH / 4; ++q) {
        const float4 dtq = dtp[q];
        const float4 uq  = xip[q];
        const float4 bq  = bp[q];
        const float* dta = &dtq.x;
        const float* ua  = &uq.x;
        const float* ba  = &bq.x;
        #pragma unroll
        for (int j = 0; j < 4; ++j) {
            const float dtv = dta[j];
            const float da  = __expf(dtv * Aval);
            ap *= da;
            hp = fmaf(da, hp, dtv * ba[j] * ua[j]);
        }
    }
    const size_t o = (((size_t)c * B_ + b) * DI_ + e) * DS_ + s;
    Ap[o] = ap; Hp[o] = hp;
}

__global__ __launch_bounds__(256) void scan_chunk2_kernel(
    float* __restrict__ Ap, float* __restrict__ Hp)
{
    const int g = blockIdx.x * 256 + threadIdx.x;
    float h = 0.f;
    #pragma unroll
    for (int c = 0; c < NC; ++c) {
        const size_t o = (size_t)c * (B_ * DI_ * DS_) + g;
        const float ap = Ap[o];
        const float hp = Hp[o];
        Hp[o] = h;
        h = fmaf(ap, h, hp);
    }
}

__global__ __launch_bounds__(256) void scan_chunk3_kernel(
    const float* __restrict__ dt_t,  // [DI, M]
    const float* __restrict__ Bt,    // [16, M]
    const float* __restrict__ Ct,    // [16, M]
    const float* __restrict__ xi_t,  // [DI, M]
    const float* __restrict__ szt,   // [DI, M] silu(z)
    const float* __restrict__ A_log, const float* __restrict__ Dp,
    const float* __restrict__ Hin, unsigned short* __restrict__ y)
{
    const int g = blockIdx.x * 256 + threadIdx.x;
    const int s = g & (DS_ - 1);
    const int e = (g >> 4) & (DI_ - 1);
    const int b = (g >> 15) & (B_ - 1);
    const int c = g >> 16;
    const float Aval = -__expf(A_log[(size_t)e * DS_ + s]);
    const float dpe = Dp[e];
    float h = Hin[(((size_t)c * B_ + b) * DI_ + e) * DS_ + s];
    const int r0 = b * T_ + c * CCH;
    const float4* dtp = (const float4*)(dt_t + (size_t)e * M_ + r0);
    const float4* xip = (const float4*)(xi_t + (size_t)e * M_ + r0);
    const float4* szp = (const float4*)(szt  + (size_t)e * M_ + r0);
    const float4* bp  = (const float4*)(Bt   + (size_t)s * M_ + r0);
    const float4* cp  = (const float4*)(Ct   + (size_t)s * M_ + r0);
    unsigned short* yp = y + (size_t)r0 * DI_ + e;
    #pragma unroll 4
    for (int q = 0; q < CCH / 4; ++q) {
        const float4 dtq = dtp[q];
        const float4 uq  = xip[q];
        const float4 bq  = bp[q];
        const float4 cq  = cp[q];
        const float4 szq = szp[q];
        const float* dta = &dtq.x;
        const float* ua  = &uq.x;
        const float* ba  = &bq.x;
        const float* ca  = &cq.x;
        const float* sza = &szq.x;
        #pragma unroll
        for (int j = 0; j < 4; ++j) {
            const float dtv = dta[j];
            const float u   = ua[j];
            const float da  = __expf(dtv * Aval);
            h = fmaf(da, h, dtv * ba[j] * u);
            const float contrib = row_reduce16(h * ca[j]);  // sum -> lane 15
            const float yv = fmaf(u, dpe, contrib) * sza[j];
            if (s == 15)
                yp[(size_t)(q * 4 + j) * DI_] = bf16_rne(yv);
        }
    }
}

extern "C" void kernel_launch(void* const* d_in, const int* in_sizes, int n_in,
                              void* d_out, int out_size, void* d_ws, size_t ws_size,
                              hipStream_t stream)
{
    const float* x       = (const float*)d_in[0];
    const float* pc      = (const float*)d_in[1];
    const float* pre_w1  = (const float*)d_in[2];
    const float* pre_w2  = (const float*)d_in[3];
    const float* norm_w  = (const float*)d_in[4];
    const float* ip_w    = (const float*)d_in[5];
    const float* conv_w  = (const float*)d_in[6];
    const float* conv_b  = (const float*)d_in[7];
    const float* xp_w    = (const float*)d_in[8];
    const float* dtp_w   = (const float*)d_in[9];
    const float* dtp_b   = (const float*)d_in[10];
    const float* A_log   = (const float*)d_in[11];
    const float* D_param = (const float*)d_in[12];
    const float* op_w    = (const float*)d_in[13];
    const float* fnw     = (const float*)d_in[14];
    float* out = (float*)d_out;

    float* ws = (float*)d_ws;
    float* h    = ws;  ws += (size_t)M_ * D_;            // fp32 residual
    float* xz   = ws;  ws += (size_t)M_ * 2 * DI_;       // in_proj out
    float* xi_t = ws;  ws += (size_t)M_ * DI_;           // conv out, [DI][M]
    float* szt  = ws;  ws += (size_t)M_ * DI_;           // silu(z), [DI][M]
    float* dtb  = ws;  ws += (size_t)M_ * DI_;           // dt, [DI][M]
    float* Ap   = ws;  ws += (size_t)NC * B_ * DI_ * DS_;
    float* Hp   = ws;  ws += (size_t)NC * B_ * DI_ * DS_;
    float* Pbuf = ws;  ws += (size_t)XKS * M_ * 96;      // x_proj / prepend partials
    float* Bt   = ws;  ws += (size_t)DS_ * M_;           // B stream [s][m]
    float* Ct   = ws;  ws += (size_t)DS_ * M_;           // C stream [s][m]
    unsigned short* xn_bf  = (unsigned short*)ws;  ws += (size_t)M_ * D_ / 2;
    unsigned short* yb_bf  = (unsigned short*)ws;  ws += (size_t)M_ * DI_ / 2;
    unsigned short* xi_bf  = (unsigned short*)ws;  ws += (size_t)M_ * DI_ / 2;
    unsigned short* dtr_bf = (unsigned short*)ws;  ws += (size_t)M_ * DR_ / 2;
    unsigned short* wbuf   = (unsigned short*)ws;  ws += (size_t)2 * DI_ * D_ / 2;
    unsigned short* xpw_bf = (unsigned short*)ws;  ws += (size_t)96 * DI_ / 2;
    unsigned short* dtpw_bf= (unsigned short*)ws;  ws += (size_t)DI_ * DR_ / 2;

    // prepend-phase aliases (all dead once the layer loop starts):
    unsigned short* pc_bf   = xi_bf;                    // 128*768 shorts
    unsigned short* w1t_bf  = wbuf;                     // [1024][768]
    unsigned short* w2t_bf  = wbuf + (size_t)D_ * PCD_; // [1024][1024]
    unsigned short* tmp1_bf = xn_bf;                    // [128][1024]
    float*          tmp2    = szt;                      // [128][1024] fp32
    // out_proj split-K partials alias xz (dead after conv_transpose)
    float*          Pop     = xz;                       // [2][M_][D_]

    const dim3 blk(256);

    // ---- prepend embed (MFMA path): silu(pc @ w1) @ w2 ----
    cvt_bf16_kernel<<<dim3(B_ * P_ * PCD_ / 4 / 256), blk, 0, stream>>>(
        pc, pc_bf, B_ * P_ * PCD_ / 4);
    cvt_transpose_kernel<<<dim3(PCD_ / 64, D_ / 64), blk, 0, stream>>>(
        pre_w1, w1t_bf, PCD_, D_);
    cvt_transpose_kernel<<<dim3(D_ / 64, D_ / 64), blk, 0, stream>>>(
        pre_w2, w2t_bf, D_, D_);
    // GEMM1: [128, 1024, K=768], split-K 6 (48 blocks), silu-reduce -> bf16
    gemm_mfma_kernel<6><<<dim3(D_ / 128, 1, 6), blk, 0, stream>>>(
        pc_bf, w1t_bf, Pbuf, nullptr, B_ * P_, D_, PCD_, PCD_ / 6);
    reduce_silu_bf16_kernel<<<dim3(B_ * P_ * D_ / 256), blk, 0, stream>>>(
        Pbuf, tmp1_bf, B_ * P_ * D_, 6);
    // GEMM2: [128, 1024, K=1024], split-K 8 (64 blocks), reduce -> fp32
    gemm_mfma_kernel<6><<<dim3(D_ / 128, 1, 8), blk, 0, stream>>>(
        tmp1_bf, w2t_bf, Pbuf, nullptr, B_ * P_, D_, D_, D_ / 8);
    reduce_fp32_kernel<<<dim3(B_ * P_ * D_ / 256), blk, 0, stream>>>(
        Pbuf, tmp2, B_ * P_ * D_, 8);
    assemble_h_kernel<<<dim3(M_ * D_ / 4 / 256), blk, 0, stream>>>(tmp2, x, h);

    const int n_ip  = 2 * DI_ * D_ / 4;
    const int n_xp  = 96 * DI_ / 4;
    const int n_dtp = DI_ * DR_ / 4;

    for (int l = 0; l < L_; ++l) {
        rmsnorm_bf16_kernel<<<dim3(M_), blk, 0, stream>>>(
            h, norm_w + (size_t)l * D_, xn_bf);
        cvt3_kernel<<<dim3((n_ip + n_xp + n_dtp + 255) / 256), blk, 0, stream>>>(
            ip_w + (size_t)l * 2 * DI_ * D_, wbuf, n_ip,
            xp_w + (size_t)l * 96 * DI_, xpw_bf, n_xp,
            dtp_w + (size_t)l * DI_ * DR_, dtpw_bf, n_dtp);
        // in_proj (MFMA): xz = xn @ ip_w^T   [1152, 4096, K=1024]
        gemm_mfma_kernel<0><<<dim3(2 * DI_ / 128, M_ / 128, 1), blk, 0, stream>>>(
            xn_bf, wbuf, xz, nullptr, M_, 2 * DI_, D_, D_);
        // conv + silu + transposes: xi_bf [r][e], xi_t [e][r], szt [e][r]
        conv_transpose_kernel<<<dim3(M_ / 64, DI_ / 64), blk, 0, stream>>>(
            xz, conv_w + (size_t)l * DI_ * DC_, conv_b + (size_t)l * DI_,
            xi_bf, xi_t, szt);
        // x_proj (split-K MFMA) + reduce -> dtr_bf, Bt, Ct
        xproj_mfma_kernel<<<dim3(XKS, M_ / 128), blk, 0, stream>>>(
            xi_bf, xpw_bf, Pbuf);
        xproj_reduce_kernel<<<dim3((M_ * 96 + 255) / 256), blk, 0, stream>>>(
            Pbuf, Bt, Ct, dtr_bf);
        // dt_proj (MFMA, transposed softplus store): dtb[e][m]
        gemm_mfma_kernel<5><<<dim3(DI_ / 128, M_ / 128, 1), blk, 0, stream>>>(
            dtr_bf, dtpw_bf, dtb, dtp_b + (size_t)l * DI_, M_, DI_, DR_, DR_);
        // chunked scan
        scan_chunk1_kernel<<<dim3(NC * B_ * DI_ * DS_ / 256), blk, 0, stream>>>(
            dtb, Bt, xi_t, A_log + (size_t)l * DI_ * DS_, Ap, Hp);
        scan_chunk2_kernel<<<dim3(B_ * DI_ * DS_ / 256), blk, 0, stream>>>(Ap, Hp);
        scan_chunk3_kernel<<<dim3(NC * B_ * DI_ * DS_ / 256), blk, 0, stream>>>(
            dtb, Bt, Ct, xi_t, szt, A_log + (size_t)l * DI_ * DS_,
            D_param + (size_t)l * DI_, Hp, yb_bf);
        // out_proj weights -> bf16 (reuses wbuf; in_proj GEMM done)
        cvt_bf16_kernel<<<dim3(D_ * DI_ / 4 / 256), blk, 0, stream>>>(
            op_w + (size_t)l * D_ * DI_, wbuf, D_ * DI_ / 4);
        // out_proj (split-K=2, partial stores into dead xz; NO atomics)
        gemm_mfma_kernel<6><<<dim3(D_ / 128, M_ / 128, 2), blk, 0, stream>>>(
            yb_bf, wbuf, Pop, nullptr, M_, D_, DI_, DI_ / 2);
        outproj_reduce_kernel<<<dim3(M_ * D_ / 4 / 256), blk, 0, stream>>>(Pop, h);
    }

    final_rmsnorm_kernel<<<dim3(B_ * S_), blk, 0, stream>>>(h, fnw, out);
}

// Round 9
// 939.927 us; speedup vs baseline: 3.9874x; 1.0549x over previous
//
#include <hip/hip_runtime.h>
#include <math.h>

#define B_ 2
#define S_ 512
#define P_ 64
#define T_ 576          // P_+S_
#define D_ 1024
#define L_ 4
#define DI_ 2048
#define DS_ 16
#define DC_ 4
#define DR_ 64
#define PCD_ 768
#define M_ (B_*T_)      // 1152
#define CCH 72          // scan chunk length: NC*B*DI*DS/64 = 8192 waves = EXACT
#define NC (T_/CCH)     // 8 chunks -> 2048 blocks = 8 blocks/CU, single round
#define NQ (CCH/4)      // 18 float4 quads per chunk
#define XKS 16          // x_proj K-splits (KC = 2048/16 = 128)

typedef __attribute__((ext_vector_type(8))) short bf16x8;
typedef __attribute__((ext_vector_type(4))) float f32x4;

__device__ __forceinline__ float silu_f(float v) { return v / (1.f + __expf(-v)); }
__device__ __forceinline__ float softplus_f(float v) {
    return fmaxf(v, 0.f) + log1pf(__expf(-fabsf(v)));
}
__device__ __forceinline__ unsigned short bf16_rne(float x) {
    unsigned int b = __float_as_uint(x);
    b += 0x7fffu + ((b >> 16) & 1u);
    return (unsigned short)(b >> 16);
}

// sum over each 16-lane row via DPP row_shr (full-rate VALU, no LDS pipe).
// Result lands in lane 15 of each row of 16.
__device__ __forceinline__ float row_reduce16(float x) {
    x += __int_as_float(__builtin_amdgcn_update_dpp(
        0, __float_as_int(x), 0x111, 0xf, 0xf, true)); // row_shr:1
    x += __int_as_float(__builtin_amdgcn_update_dpp(
        0, __float_as_int(x), 0x112, 0xf, 0xf, true)); // row_shr:2
    x += __int_as_float(__builtin_amdgcn_update_dpp(
        0, __float_as_int(x), 0x114, 0xf, 0xf, true)); // row_shr:4
    x += __int_as_float(__builtin_amdgcn_update_dpp(
        0, __float_as_int(x), 0x118, 0xf, 0xf, true)); // row_shr:8
    return x;
}

typedef const void __attribute__((address_space(1)))* gas_t;
typedef void __attribute__((address_space(3)))* las_t;
__device__ __forceinline__ void async16(const void* g, void* l) {
    __builtin_amdgcn_global_load_lds((gas_t)g, (las_t)l, 16, 0, 0);
}

// ---------------------------------------------------------------------------
// bf16 MFMA GEMM (m97 structure): C[m,n] (+)= sum_k A[m,k]*W[n,k], fp32 out.
// EPI: 0 = store, 5 = softplus(v+bias[n]) stored TRANSPOSED to C[n*M + m],
//      6 = split-K partial store to C[(z*M + m)*N + n] (deterministic
//      reduce kernel follows; NO atomics).
// ---------------------------------------------------------------------------
template<int EPI>
__global__ __launch_bounds__(256) void gemm_mfma_kernel(
    const unsigned short* __restrict__ A, const unsigned short* __restrict__ W,
    float* __restrict__ C, const float* __restrict__ bias,
    int M, int N, int K, int Kchunk)
{
    __shared__ unsigned short As[128 * 32];
    __shared__ unsigned short Bs[128 * 32];
    const int tid = threadIdx.x;
    const int wave = tid >> 6;
    const int lane = tid & 63;
    const int m0 = blockIdx.y * 128, n0 = blockIdx.x * 128;
    const int kbase = blockIdx.z * Kchunk;
    const int wm = (wave >> 1) * 64, wn = (wave & 1) * 64;

    const int srow = (wave << 5) + (lane >> 2);
    const int selem = (lane & 3) * 8;
    const unsigned short* gA = A + (size_t)(m0 + srow) * K + kbase + selem;
    const unsigned short* gB = W + (size_t)(n0 + srow) * K + kbase + selem;
    unsigned short* lA = As + (wave << 5) * 32;
    unsigned short* lB = Bs + (wave << 5) * 32;

    f32x4 acc[4][4];
    #pragma unroll
    for (int i = 0; i < 4; ++i)
        #pragma unroll
        for (int j = 0; j < 4; ++j)
            acc[i][j] = (f32x4){0.f, 0.f, 0.f, 0.f};

    const int fr = lane & 15;
    const int fq = lane >> 4;
    const int aoff = (wm + fr) * 32 + fq * 8;
    const int boff = (wn + fr) * 32 + fq * 8;

    for (int k0 = 0; k0 < Kchunk; k0 += 32) {
        async16(gA, lA);
        async16(gA + (size_t)16 * K, lA + 16 * 32);
        async16(gB, lB);
        async16(gB + (size_t)16 * K, lB + 16 * 32);
        gA += 32; gB += 32;
        __syncthreads();
        bf16x8 af[4], bf[4];
        #pragma unroll
        for (int i = 0; i < 4; ++i) af[i] = *(const bf16x8*)&As[aoff + i * 512];
        #pragma unroll
        for (int j = 0; j < 4; ++j) bf[j] = *(const bf16x8*)&Bs[boff + j * 512];
        #pragma unroll
        for (int i = 0; i < 4; ++i)
            #pragma unroll
            for (int j = 0; j < 4; ++j)
                acc[i][j] = __builtin_amdgcn_mfma_f32_16x16x32_bf16(
                    af[i], bf[j], acc[i][j], 0, 0, 0);
        __syncthreads();
    }

    // C/D layout (m89-verified): col = lane&15, row = (lane>>4)*4 + reg
    #pragma unroll
    for (int i = 0; i < 4; ++i) {
        const int m = m0 + wm + i * 16 + fq * 4;
        #pragma unroll
        for (int j = 0; j < 4; ++j) {
            const int n = n0 + wn + j * 16 + fr;
            if (EPI == 5) {
                const float bb = bias[n];
                float4 o;
                o.x = softplus_f(acc[i][j][0] + bb);
                o.y = softplus_f(acc[i][j][1] + bb);
                o.z = softplus_f(acc[i][j][2] + bb);
                o.w = softplus_f(acc[i][j][3] + bb);
                *(float4*)(C + (size_t)n * M + m) = o;   // transposed, m%4==0
            } else if (EPI == 6) {
                float* p = C + ((size_t)blockIdx.z * M + m) * N + n;
                #pragma unroll
                for (int r = 0; r < 4; ++r)
                    p[(size_t)r * N] = acc[i][j][r];
            } else {
                float* p = C + (size_t)m * N + n;
                #pragma unroll
                for (int r = 0; r < 4; ++r)
                    p[(size_t)r * N] = acc[i][j][r];
            }
        }
    }
}

// ---------------------------------------------------------------------------
// x_proj split-K MFMA: P[ks][m][96] = xi_bf[m, ks*128:(ks+1)*128] @ W[96,...]^T
// ---------------------------------------------------------------------------
__global__ __launch_bounds__(256) void xproj_mfma_kernel(
    const unsigned short* __restrict__ A,   // [M, 2048] bf16
    const unsigned short* __restrict__ W,   // [96, 2048] bf16
    float* __restrict__ P)                  // [XKS, M, 96]
{
    __shared__ unsigned short As[128 * 32];
    __shared__ unsigned short Bs[96 * 32];
    const int tid = threadIdx.x;
    const int wave = tid >> 6;
    const int lane = tid & 63;
    const int m0 = blockIdx.y * 128;
    const int kbase = blockIdx.x * (DI_ / XKS);   // 128
    const int wm = (wave >> 1) * 64, wn = (wave & 1) * 48;

    const int srow = (wave << 5) + (lane >> 2);
    const int selem = (lane & 3) * 8;
    const unsigned short* gA = A + (size_t)(m0 + srow) * DI_ + kbase + selem;
    const unsigned short* gB = W + (size_t)srow * DI_ + kbase + selem;
    unsigned short* lA = As + (wave << 5) * 32;
    unsigned short* lB = Bs + (wave << 5) * 32;

    f32x4 acc[4][3];
    #pragma unroll
    for (int i = 0; i < 4; ++i)
        #pragma unroll
        for (int j = 0; j < 3; ++j)
            acc[i][j] = (f32x4){0.f, 0.f, 0.f, 0.f};

    const int fr = lane & 15;
    const int fq = lane >> 4;
    const int aoff = (wm + fr) * 32 + fq * 8;
    const int boff = (wn + fr) * 32 + fq * 8;

    #pragma unroll
    for (int kk = 0; kk < 4; ++kk) {
        async16(gA, lA);
        async16(gA + (size_t)16 * DI_, lA + 16 * 32);
        if (wave < 3) {
            async16(gB, lB);
            async16(gB + (size_t)16 * DI_, lB + 16 * 32);
        }
        gA += 32; gB += 32;
        __syncthreads();
        bf16x8 af[4], bf[3];
        #pragma unroll
        for (int i = 0; i < 4; ++i) af[i] = *(const bf16x8*)&As[aoff + i * 512];
        #pragma unroll
        for (int j = 0; j < 3; ++j) bf[j] = *(const bf16x8*)&Bs[boff + j * 512];
        #pragma unroll
        for (int i = 0; i < 4; ++i)
            #pragma unroll
            for (int j = 0; j < 3; ++j)
                acc[i][j] = __builtin_amdgcn_mfma_f32_16x16x32_bf16(
                    af[i], bf[j], acc[i][j], 0, 0, 0);
        __syncthreads();
    }

    float* Pb = P + ((size_t)blockIdx.x * M_ + m0) * 96;
    #pragma unroll
    for (int i = 0; i < 4; ++i) {
        const int m = wm + i * 16 + fq * 4;
        #pragma unroll
        for (int j = 0; j < 3; ++j) {
            const int n = wn + j * 16 + fr;
            #pragma unroll
            for (int r = 0; r < 4; ++r)
                Pb[(size_t)(m + r) * 96 + n] = acc[i][j][r];
        }
    }
}

// reduce partials; emit dtr_bf [m][64] plus TRANSPOSED scan streams
// Bt[s][m], Ct[s][m] (s in 0..15).
__global__ __launch_bounds__(256) void xproj_reduce_kernel(
    const float* __restrict__ P, float* __restrict__ Bt, float* __restrict__ Ct,
    unsigned short* __restrict__ dtr_bf)
{
    const int i = blockIdx.x * 256 + threadIdx.x;
    if (i >= M_ * 96) return;
    float s = 0.f;
    #pragma unroll
    for (int ks = 0; ks < XKS; ++ks) s += P[(size_t)ks * (M_ * 96) + i];
    const int m = i / 96;
    const int n = i - m * 96;
    if (n < DR_)            dtr_bf[(size_t)m * DR_ + n] = bf16_rne(s);
    else if (n < DR_ + DS_) Bt[(size_t)(n - DR_) * M_ + m] = s;
    else                    Ct[(size_t)(n - DR_ - DS_) * M_ + m] = s;
}

// fp32 -> bf16 (RNE), vectorized x4
__global__ __launch_bounds__(256) void cvt_bf16_kernel(
    const float* __restrict__ in, unsigned short* __restrict__ out, int n4)
{
    const int i = blockIdx.x * 256 + threadIdx.x;
    if (i >= n4) return;
    const float4 v = ((const float4*)in)[i];
    ushort4 o;
    o.x = bf16_rne(v.x); o.y = bf16_rne(v.y);
    o.z = bf16_rne(v.z); o.w = bf16_rne(v.w);
    ((ushort4*)out)[i] = o;
}

// three conversions in one launch (in_proj + x_proj + dt_proj weights)
__global__ __launch_bounds__(256) void cvt3_kernel(
    const float* __restrict__ s0, unsigned short* __restrict__ d0, int n0,
    const float* __restrict__ s1, unsigned short* __restrict__ d1, int n1,
    const float* __restrict__ s2, unsigned short* __restrict__ d2, int n2)
{
    const int i = blockIdx.x * 256 + threadIdx.x;
    const float* s; unsigned short* d; int off;
    if (i < n0)           { s = s0; d = d0; off = i; }
    else if (i < n0 + n1) { s = s1; d = d1; off = i - n0; }
    else if (i < n0 + n1 + n2) { s = s2; d = d2; off = i - n0 - n1; }
    else return;
    const float4 v = ((const float4*)s)[off];
    ushort4 o;
    o.x = bf16_rne(v.x); o.y = bf16_rne(v.y);
    o.z = bf16_rne(v.z); o.w = bf16_rne(v.w);
    ((ushort4*)d)[off] = o;
}

// fp32 [K][N] (k-major) -> bf16 [N][K] (n-major) transpose+convert, 64x64 tile
__global__ __launch_bounds__(256) void cvt_transpose_kernel(
    const float* __restrict__ in, unsigned short* __restrict__ out, int K, int N)
{
    __shared__ float t[64][65];
    const int k0 = blockIdx.x * 64;
    const int n0 = blockIdx.y * 64;
    const int tx = threadIdx.x & 63;
    const int ty = threadIdx.x >> 6;
    #pragma unroll
    for (int j = 0; j < 16; ++j) {
        const int kk = ty * 16 + j;
        t[kk][tx] = in[(size_t)(k0 + kk) * N + n0 + tx];
    }
    __syncthreads();
    #pragma unroll
    for (int j = 0; j < 16; ++j) {
        const int nn = ty * 16 + j;
        out[(size_t)(n0 + nn) * K + k0 + tx] = bf16_rne(t[tx][nn]);
    }
}

// generalized split-K reduces (stride MN between partials)
__global__ __launch_bounds__(256) void reduce_silu_bf16_kernel(
    const float* __restrict__ P, unsigned short* __restrict__ o, int MN, int ns)
{
    const int i = blockIdx.x * 256 + threadIdx.x;
    if (i >= MN) return;
    float s = 0.f;
    for (int k = 0; k < ns; ++k) s += P[(size_t)k * MN + i];
    o[i] = bf16_rne(silu_f(s));
}
__global__ __launch_bounds__(256) void reduce_fp32_kernel(
    const float* __restrict__ P, float* __restrict__ o, int MN, int ns)
{
    const int i = blockIdx.x * 256 + threadIdx.x;
    if (i >= MN) return;
    float s = 0.f;
    for (int k = 0; k < ns; ++k) s += P[(size_t)k * MN + i];
    o[i] = s;
}

// out_proj split-K=2 reduce + residual add into h, float4 vectorized
__global__ __launch_bounds__(256) void outproj_reduce_kernel(
    const float* __restrict__ P, float* __restrict__ h)
{
    const int i = blockIdx.x * 256 + threadIdx.x;   // over M_*D_/4
    const float4 a = ((const float4*)P)[i];
    const float4 b = ((const float4*)P)[i + M_ * D_ / 4];
    float4 hv = ((float4*)h)[i];
    hv.x += a.x + b.x; hv.y += a.y + b.y;
    hv.z += a.z + b.z; hv.w += a.w + b.w;
    ((float4*)h)[i] = hv;
}

// h[b*T+t, :] = (t < P) ? p[b*P+t, :] : x[b*S + (t-P), :]
__global__ __launch_bounds__(256) void assemble_h_kernel(
    const float* __restrict__ p, const float* __restrict__ x, float* __restrict__ h)
{
    const int idx = blockIdx.x * 256 + threadIdx.x;
    const int r = idx >> 8;
    const int c = idx & 255;
    const int b = r / T_;
    const int t = r - b * T_;
    float4 v;
    if (t < P_) v = ((const float4*)p)[(size_t)(b * P_ + t) * 256 + c];
    else        v = ((const float4*)x)[(size_t)(b * S_ + (t - P_)) * 256 + c];
    ((float4*)h)[idx] = v;
}

// rmsnorm -> bf16 output (feeds in_proj MFMA). one block per row.
__global__ __launch_bounds__(256) void rmsnorm_bf16_kernel(
    const float* __restrict__ x, const float* __restrict__ w,
    unsigned short* __restrict__ outb)
{
    const int r = blockIdx.x;
    const float4 v = ((const float4*)(x + (size_t)r * D_))[threadIdx.x];
    float ss = v.x * v.x + v.y * v.y + v.z * v.z + v.w * v.w;
    ss += __shfl_xor(ss, 32, 64);
    ss += __shfl_xor(ss, 16, 64);
    ss += __shfl_xor(ss, 8, 64);
    ss += __shfl_xor(ss, 4, 64);
    ss += __shfl_xor(ss, 2, 64);
    ss += __shfl_xor(ss, 1, 64);
    __shared__ float red[4];
    if ((threadIdx.x & 63) == 0) red[threadIdx.x >> 6] = ss;
    __syncthreads();
    const float tot = red[0] + red[1] + red[2] + red[3];
    const float scale = rsqrtf(tot * (1.f / D_) + 1e-5f);
    const float4 wv = ((const float4*)w)[threadIdx.x];
    ushort4 o;
    o.x = bf16_rne(v.x * scale * wv.x);
    o.y = bf16_rne(v.y * scale * wv.y);
    o.z = bf16_rne(v.z * scale * wv.z);
    o.w = bf16_rne(v.w * scale * wv.w);
    ((ushort4*)(outb + (size_t)r * D_))[threadIdx.x] = o;
}

// final rmsnorm (fp32 out): rows over B*S; reads h[b*T+P+s]
__global__ __launch_bounds__(256) void final_rmsnorm_kernel(
    const float* __restrict__ h, const float* __restrict__ w, float* __restrict__ out)
{
    const int r = blockIdx.x;
    const int b = r / S_;
    const int s = r - b * S_;
    const int hr = b * T_ + P_ + s;
    const float4 v = ((const float4*)(h + (size_t)hr * D_))[threadIdx.x];
    float ss = v.x * v.x + v.y * v.y + v.z * v.z + v.w * v.w;
    ss += __shfl_xor(ss, 32, 64);
    ss += __shfl_xor(ss, 16, 64);
    ss += __shfl_xor(ss, 8, 64);
    ss += __shfl_xor(ss, 4, 64);
    ss += __shfl_xor(ss, 2, 64);
    ss += __shfl_xor(ss, 1, 64);
    __shared__ float red[4];
    if ((threadIdx.x & 63) == 0) red[threadIdx.x >> 6] = ss;
    __syncthreads();
    const float tot = red[0] + red[1] + red[2] + red[3];
    const float scale = rsqrtf(tot * (1.f / D_) + 1e-5f);
    const float4 wv = ((const float4*)w)[threadIdx.x];
    float4 o;
    o.x = v.x * scale * wv.x; o.y = v.y * scale * wv.y;
    o.z = v.z * scale * wv.z; o.w = v.w * scale * wv.w;
    ((float4*)(out + (size_t)r * D_))[threadIdx.x] = o;
}

// ---------------------------------------------------------------------------
// Fused causal depthwise conv (DC=4) + bias + silu + transpose, PLUS
// silu(z) transposed stream.
// ---------------------------------------------------------------------------
__global__ __launch_bounds__(256) void conv_transpose_kernel(
    const float* __restrict__ xz, const float* __restrict__ cw,
    const float* __restrict__ cb, unsigned short* __restrict__ xib,
    float* __restrict__ xit, float* __restrict__ szt)
{
    __shared__ float xs[68][64];    // rows r0-3 .. r0+63 (67 used)
    __shared__ float tt[64][65];    // transpose staging, padded
    const int tid = threadIdx.x;
    const int tx = tid & 63;
    const int ty = tid >> 6;        // 0..3
    const int r0 = blockIdx.x * 64;
    const int e0 = blockIdx.y * 64;
    const int bt0 = (r0 / T_) * T_; // batch start row

    for (int j = ty; j < 67; j += 4) {
        const int r = r0 + j - 3;
        xs[j][tx] = (r >= bt0) ? xz[(size_t)r * (2 * DI_) + e0 + tx] : 0.f;
    }
    __syncthreads();
    const float4 w = *(const float4*)(cw + (size_t)(e0 + tx) * 4);
    const float bias = cb[e0 + tx];
    #pragma unroll
    for (int j = 0; j < 16; ++j) {
        const int rl = ty * 16 + j;
        float v = bias;
        v = fmaf(w.x, xs[rl + 0][tx], v);   // x[r-3]
        v = fmaf(w.y, xs[rl + 1][tx], v);   // x[r-2]
        v = fmaf(w.z, xs[rl + 2][tx], v);   // x[r-1]
        v = fmaf(w.w, xs[rl + 3][tx], v);   // x[r]
        const float o = silu_f(v);
        xib[(size_t)(r0 + rl) * DI_ + e0 + tx] = bf16_rne(o);
        tt[rl][tx] = o;
    }
    __syncthreads();
    #pragma unroll
    for (int j = 0; j < 16; ++j) {
        const int c = ty * 16 + j;
        xit[(size_t)(e0 + c) * M_ + r0 + tx] = tt[tx][c];
    }
    __syncthreads();
    // z half -> silu -> transpose
    #pragma unroll
    for (int j = 0; j < 16; ++j) {
        const int rl = ty * 16 + j;
        tt[rl][tx] = silu_f(xz[(size_t)(r0 + rl) * (2 * DI_) + DI_ + e0 + tx]);
    }
    __syncthreads();
    #pragma unroll
    for (int j = 0; j < 16; ++j) {
        const int c = ty * 16 + j;
        szt[(size_t)(e0 + c) * M_ + r0 + tx] = tt[tx][c];
    }
}

// ---------------------------------------------------------------------------
// Chunked selective scan, float4 time-unroll + EXPLICIT one-quad prefetch
// (R8 had VGPR=24: compiler kept no lookahead, paying full vmcnt latency per
// quad). Grid: NC*B*DI*DS/64 = 8192 waves = exactly one round (8 blk/CU).
// ---------------------------------------------------------------------------
__global__ __launch_bounds__(256) void scan_chunk1_kernel(
    const float* __restrict__ dt_t,  // [DI, M]
    const float* __restrict__ Bt,    // [16, M]
    const float* __restrict__ xi_t,  // [DI, M]
    const float* __restrict__ A_log,
    float* __restrict__ Ap, float* __restrict__ Hp)
{
    const int g = blockIdx.x * 256 + threadIdx.x;
    const int s = g & (DS_ - 1);
    const int e = (g >> 4) & (DI_ - 1);
    const int b = (g >> 15) & (B_ - 1);
    const int c = g >> 16;
    const float Aval = -__expf(A_log[(size_t)e * DS_ + s]);
    float ap = 1.f, hp = 0.f;
    const int r0 = b * T_ + c * CCH;
    const float4* dtp = (const float4*)(dt_t + (size_t)e * M_ + r0);
    const float4* xip = (const float4*)(xi_t + (size_t)e * M_ + r0);
    const float4* bp  = (const float4*)(Bt   + (size_t)s * M_ + r0);
    float4 dq = dtp[0], uq = xip[0], bq = bp[0];
    #pragma unroll
    for (int q = 0; q < NQ; ++q) {
        float4 dn, un, bn;
        if (q < NQ - 1) { dn = dtp[q + 1]; un = xip[q + 1]; bn = bp[q + 1]; }
        const float* dta = &dq.x;
        const float* ua  = &uq.x;
        const float* ba  = &bq.x;
        #pragma unroll
        for (int j = 0; j < 4; ++j) {
            const float dtv = dta[j];
            const float da  = __expf(dtv * Aval);
            ap *= da;
            hp = fmaf(da, hp, dtv * ba[j] * ua[j]);
        }
        dq = dn; uq = un; bq = bn;
    }
    const size_t o = (((size_t)c * B_ + b) * DI_ + e) * DS_ + s;
    Ap[o] = ap; Hp[o] = hp;
}

__global__ __launch_bounds__(256) void scan_chunk2_kernel(
    float* __restrict__ Ap, float* __restrict__ Hp)
{
    const int g = blockIdx.x * 256 + threadIdx.x;
    float h = 0.f;
    #pragma unroll
    for (int c = 0; c < NC; ++c) {
        const size_t o = (size_t)c * (B_ * DI_ * DS_) + g;
        const float ap = Ap[o];
        const float hp = Hp[o];
        Hp[o] = h;
        h = fmaf(ap, h, hp);
    }
}

__global__ __launch_bounds__(256) void scan_chunk3_kernel(
    const float* __restrict__ dt_t,  // [DI, M]
    const float* __restrict__ Bt,    // [16, M]
    const float* __restrict__ Ct,    // [16, M]
    const float* __restrict__ xi_t,  // [DI, M]
    const float* __restrict__ szt,   // [DI, M] silu(z)
    const float* __restrict__ A_log, const float* __restrict__ Dp,
    const float* __restrict__ Hin, unsigned short* __restrict__ y)
{
    const int g = blockIdx.x * 256 + threadIdx.x;
    const int s = g & (DS_ - 1);
    const int e = (g >> 4) & (DI_ - 1);
    const int b = (g >> 15) & (B_ - 1);
    const int c = g >> 16;
    const float Aval = -__expf(A_log[(size_t)e * DS_ + s]);
    const float dpe = Dp[e];
    float h = Hin[(((size_t)c * B_ + b) * DI_ + e) * DS_ + s];
    const int r0 = b * T_ + c * CCH;
    const float4* dtp = (const float4*)(dt_t + (size_t)e * M_ + r0);
    const float4* xip = (const float4*)(xi_t + (size_t)e * M_ + r0);
    const float4* szp = (const float4*)(szt  + (size_t)e * M_ + r0);
    const float4* bp  = (const float4*)(Bt   + (size_t)s * M_ + r0);
    const float4* cp  = (const float4*)(Ct   + (size_t)s * M_ + r0);
    unsigned short* yp = y + (size_t)r0 * DI_ + e;
    float4 dq = dtp[0], uq = xip[0], bq = bp[0], cq = cp[0], sq = szp[0];
    #pragma unroll
    for (int q = 0; q < NQ; ++q) {
        float4 dn, un, bn, cn, sn;
        if (q < NQ - 1) {
            dn = dtp[q + 1]; un = xip[q + 1]; bn = bp[q + 1];
            cn = cp[q + 1];  sn = szp[q + 1];
        }
        const float* dta = &dq.x;
        const float* ua  = &uq.x;
        const float* ba  = &bq.x;
        const float* ca  = &cq.x;
        const float* sza = &sq.x;
        #pragma unroll
        for (int j = 0; j < 4; ++j) {
            const float dtv = dta[j];
            const float u   = ua[j];
            const float da  = __expf(dtv * Aval);
            h = fmaf(da, h, dtv * ba[j] * u);
            const float contrib = row_reduce16(h * ca[j]);  // sum -> lane 15
            const float yv = fmaf(u, dpe, contrib) * sza[j];
            if (s == 15)
                yp[(size_t)(q * 4 + j) * DI_] = bf16_rne(yv);
        }
        dq = dn; uq = un; bq = bn; cq = cn; sq = sn;
    }
}

extern "C" void kernel_launch(void* const* d_in, const int* in_sizes, int n_in,
                              void* d_out, int out_size, void* d_ws, size_t ws_size,
                              hipStream_t stream)
{
    const float* x       = (const float*)d_in[0];
    const float* pc      = (const float*)d_in[1];
    const float* pre_w1  = (const float*)d_in[2];
    const float* pre_w2  = (const float*)d_in[3];
    const float* norm_w  = (const float*)d_in[4];
    const float* ip_w    = (const float*)d_in[5];
    const float* conv_w  = (const float*)d_in[6];
    const float* conv_b  = (const float*)d_in[7];
    const float* xp_w    = (const float*)d_in[8];
    const float* dtp_w   = (const float*)d_in[9];
    const float* dtp_b   = (const float*)d_in[10];
    const float* A_log   = (const float*)d_in[11];
    const float* D_param = (const float*)d_in[12];
    const float* op_w    = (const float*)d_in[13];
    const float* fnw     = (const float*)d_in[14];
    float* out = (float*)d_out;

    float* ws = (float*)d_ws;
    float* h    = ws;  ws += (size_t)M_ * D_;            // fp32 residual
    float* xz   = ws;  ws += (size_t)M_ * 2 * DI_;       // in_proj out
    float* xi_t = ws;  ws += (size_t)M_ * DI_;           // conv out, [DI][M]
    float* szt  = ws;  ws += (size_t)M_ * DI_;           // silu(z), [DI][M]
    float* dtb  = ws;  ws += (size_t)M_ * DI_;           // dt, [DI][M]
    float* Ap   = ws;  ws += (size_t)NC * B_ * DI_ * DS_;
    float* Hp   = ws;  ws += (size_t)NC * B_ * DI_ * DS_;
    float* Pbuf = ws;  ws += (size_t)XKS * M_ * 96;      // x_proj / prepend partials
    float* Bt   = ws;  ws += (size_t)DS_ * M_;           // B stream [s][m]
    float* Ct   = ws;  ws += (size_t)DS_ * M_;           // C stream [s][m]
    unsigned short* xn_bf  = (unsigned short*)ws;  ws += (size_t)M_ * D_ / 2;
    unsigned short* yb_bf  = (unsigned short*)ws;  ws += (size_t)M_ * DI_ / 2;
    unsigned short* xi_bf  = (unsigned short*)ws;  ws += (size_t)M_ * DI_ / 2;
    unsigned short* dtr_bf = (unsigned short*)ws;  ws += (size_t)M_ * DR_ / 2;
    unsigned short* wbuf   = (unsigned short*)ws;  ws += (size_t)2 * DI_ * D_ / 2;
    unsigned short* xpw_bf = (unsigned short*)ws;  ws += (size_t)96 * DI_ / 2;
    unsigned short* dtpw_bf= (unsigned short*)ws;  ws += (size_t)DI_ * DR_ / 2;

    // prepend-phase aliases (all dead once the layer loop starts):
    unsigned short* pc_bf   = xi_bf;                    // 128*768 shorts
    unsigned short* w1t_bf  = wbuf;                     // [1024][768]
    unsigned short* w2t_bf  = wbuf + (size_t)D_ * PCD_; // [1024][1024]
    unsigned short* tmp1_bf = xn_bf;                    // [128][1024]
    float*          tmp2    = szt;                      // [128][1024] fp32
    // out_proj split-K partials alias xz (dead after conv_transpose)
    float*          Pop     = xz;                       // [2][M_][D_]

    const dim3 blk(256);

    // ---- prepend embed (MFMA path): silu(pc @ w1) @ w2 ----
    cvt_bf16_kernel<<<dim3(B_ * P_ * PCD_ / 4 / 256), blk, 0, stream>>>(
        pc, pc_bf, B_ * P_ * PCD_ / 4);
    cvt_transpose_kernel<<<dim3(PCD_ / 64, D_ / 64), blk, 0, stream>>>(
        pre_w1, w1t_bf, PCD_, D_);
    cvt_transpose_kernel<<<dim3(D_ / 64, D_ / 64), blk, 0, stream>>>(
        pre_w2, w2t_bf, D_, D_);
    // GEMM1: [128, 1024, K=768], split-K 6 (48 blocks), silu-reduce -> bf16
    gemm_mfma_kernel<6><<<dim3(D_ / 128, 1, 6), blk, 0, stream>>>(
        pc_bf, w1t_bf, Pbuf, nullptr, B_ * P_, D_, PCD_, PCD_ / 6);
    reduce_silu_bf16_kernel<<<dim3(B_ * P_ * D_ / 256), blk, 0, stream>>>(
        Pbuf, tmp1_bf, B_ * P_ * D_, 6);
    // GEMM2: [128, 1024, K=1024], split-K 8 (64 blocks), reduce -> fp32
    gemm_mfma_kernel<6><<<dim3(D_ / 128, 1, 8), blk, 0, stream>>>(
        tmp1_bf, w2t_bf, Pbuf, nullptr, B_ * P_, D_, D_, D_ / 8);
    reduce_fp32_kernel<<<dim3(B_ * P_ * D_ / 256), blk, 0, stream>>>(
        Pbuf, tmp2, B_ * P_ * D_, 8);
    assemble_h_kernel<<<dim3(M_ * D_ / 4 / 256), blk, 0, stream>>>(tmp2, x, h);

    const int n_ip  = 2 * DI_ * D_ / 4;
    const int n_xp  = 96 * DI_ / 4;
    const int n_dtp = DI_ * DR_ / 4;

    for (int l = 0; l < L_; ++l) {
        rmsnorm_bf16_kernel<<<dim3(M_), blk, 0, stream>>>(
            h, norm_w + (size_t)l * D_, xn_bf);
        cvt3_kernel<<<dim3((n_ip + n_xp + n_dtp + 255) / 256), blk, 0, stream>>>(
            ip_w + (size_t)l * 2 * DI_ * D_, wbuf, n_ip,
            xp_w + (size_t)l * 96 * DI_, xpw_bf, n_xp,
            dtp_w + (size_t)l * DI_ * DR_, dtpw_bf, n_dtp);
        // in_proj (MFMA): xz = xn @ ip_w^T   [1152, 4096, K=1024]
        gemm_mfma_kernel<0><<<dim3(2 * DI_ / 128, M_ / 128, 1), blk, 0, stream>>>(
            xn_bf, wbuf, xz, nullptr, M_, 2 * DI_, D_, D_);
        // conv + silu + transposes: xi_bf [r][e], xi_t [e][r], szt [e][r]
        conv_transpose_kernel<<<dim3(M_ / 64, DI_ / 64), blk, 0, stream>>>(
            xz, conv_w + (size_t)l * DI_ * DC_, conv_b + (size_t)l * DI_,
            xi_bf, xi_t, szt);
        // x_proj (split-K MFMA) + reduce -> dtr_bf, Bt, Ct
        xproj_mfma_kernel<<<dim3(XKS, M_ / 128), blk, 0, stream>>>(
            xi_bf, xpw_bf, Pbuf);
        xproj_reduce_kernel<<<dim3((M_ * 96 + 255) / 256), blk, 0, stream>>>(
            Pbuf, Bt, Ct, dtr_bf);
        // dt_proj (MFMA, transposed softplus store): dtb[e][m]
        gemm_mfma_kernel<5><<<dim3(DI_ / 128, M_ / 128, 1), blk, 0, stream>>>(
            dtr_bf, dtpw_bf, dtb, dtp_b + (size_t)l * DI_, M_, DI_, DR_, DR_);
        // chunked scan (2048 blocks = 8/CU exact single round)
        scan_chunk1_kernel<<<dim3(NC * B_ * DI_ * DS_ / 256), blk, 0, stream>>>(
            dtb, Bt, xi_t, A_log + (size_t)l * DI_ * DS_, Ap, Hp);
        scan_chunk2_kernel<<<dim3(B_ * DI_ * DS_ / 256), blk, 0, stream>>>(Ap, Hp);
        scan_chunk3_kernel<<<dim3(NC * B_ * DI_ * DS_ / 256), blk, 0, stream>>>(
            dtb, Bt, Ct, xi_t, szt, A_log + (size_t)l * DI_ * DS_,
            D_param + (size_t)l * DI_, Hp, yb_bf);
        // out_proj weights -> bf16 (reuses wbuf; in_proj GEMM done)
        cvt_bf16_kernel<<<dim3(D_ * DI_ / 4 / 256), blk, 0, stream>>>(
            op_w + (size_t)l * D_ * DI_, wbuf, D_ * DI_ / 4);
        // out_proj (split-K=2, partial stores into dead xz; NO atomics)
        gemm_mfma_kernel<6><<<dim3(D_ / 128, M_ / 128, 2), blk, 0, stream>>>(
            yb_bf, wbuf, Pop, nullptr, M_, D_, DI_, DI_ / 2);
        outproj_reduce_kernel<<<dim3(M_ * D_ / 4 / 256), blk, 0, stream>>>(Pop, h);
    }

    final_rmsnorm_kernel<<<dim3(B_ * S_), blk, 0, stream>>>(h, fnw, out);
}